// Round 2
// baseline (2596.121 us; speedup 1.0000x reference)
//
#include <hip/hip_runtime.h>

#define T_LEN 2048
#define C_DIM 1024
// chunked-scan tile layout (floats per (head,chunk) tile)
#define TSTRIDE 6208
// offsets: R~ 0, A~ 1024, B^ 2048, K^ 3072, Zl[v][t] 4096, Vt[v][s] 5120, pL 6144

static __device__ __forceinline__ float sigf(float x) {
    return 1.f / (1.f + __expf(-x));
}

// ---------------------------------------------------------------------------
// NT GEMM: out[t,i] = sum_c A(t,c) * W[i,c];  A = mixv ? x + (shift-x)*mix : X
// ---------------------------------------------------------------------------
__global__ __launch_bounds__(256) void gemm_nt(
    const float* __restrict__ X, const float* __restrict__ xprev,
    const float* __restrict__ mixv, const float* __restrict__ W,
    float* __restrict__ out)
{
    __shared__ __align__(16) float As[16][68];
    __shared__ __align__(16) float Ws[16][68];
    const int tid = threadIdx.x;
    const int t0 = blockIdx.y * 64;
    const int n0 = blockIdx.x * 64;
    const int lr = tid >> 2;
    const int lk = (tid & 3) << 2;
    const int ty = tid >> 4;
    const int tx = tid & 15;
    float acc[4][4] = {{0.f}};

    const int trow = t0 + lr;
    const float* xrow  = X + (size_t)trow * C_DIM;
    const float* xprow = (trow == 0) ? xprev : (X + (size_t)(trow - 1) * C_DIM);
    const float* wrow  = W + (size_t)(n0 + lr) * C_DIM;

    for (int k0 = 0; k0 < C_DIM; k0 += 16) {
        float4 xv = *(const float4*)(xrow + k0 + lk);
        if (mixv) {
            float4 pv = *(const float4*)(xprow + k0 + lk);
            float4 mv = *(const float4*)(mixv + k0 + lk);
            xv.x += (pv.x - xv.x) * mv.x;
            xv.y += (pv.y - xv.y) * mv.y;
            xv.z += (pv.z - xv.z) * mv.z;
            xv.w += (pv.w - xv.w) * mv.w;
        }
        As[lk + 0][lr] = xv.x; As[lk + 1][lr] = xv.y;
        As[lk + 2][lr] = xv.z; As[lk + 3][lr] = xv.w;
        float4 wv = *(const float4*)(wrow + k0 + lk);
        Ws[lk + 0][lr] = wv.x; Ws[lk + 1][lr] = wv.y;
        Ws[lk + 2][lr] = wv.z; Ws[lk + 3][lr] = wv.w;
        __syncthreads();
#pragma unroll
        for (int kk = 0; kk < 16; ++kk) {
            float4 av = *(const float4*)&As[kk][ty << 2];
            float4 bv = *(const float4*)&Ws[kk][tx << 2];
            float a_[4] = {av.x, av.y, av.z, av.w};
            float b_[4] = {bv.x, bv.y, bv.z, bv.w};
#pragma unroll
            for (int i = 0; i < 4; ++i)
#pragma unroll
                for (int j = 0; j < 4; ++j)
                    acc[i][j] = fmaf(a_[i], b_[j], acc[i][j]);
        }
        __syncthreads();
    }
#pragma unroll
    for (int i = 0; i < 4; ++i) {
        float4 o4 = {acc[i][0], acc[i][1], acc[i][2], acc[i][3]};
        *(float4*)(out + (size_t)(t0 + (ty << 2) + i) * C_DIM + n0 + (tx << 2)) = o4;
    }
}

// ---------------------------------------------------------------------------
// LoRA stage 1
// ---------------------------------------------------------------------------
__global__ __launch_bounds__(256) void lora1(
    const float* __restrict__ X, const float* __restrict__ xprev,
    const float* __restrict__ mixv, const float* __restrict__ W1,
    float* __restrict__ hbuf, int Kh, int act)
{
    __shared__ __align__(16) float As[8192];
    const int tid = threadIdx.x;
    const int tpb = 256 / Kh;
    const int t0 = blockIdx.x * tpb;
    for (int idx = tid; idx < (tpb << 10); idx += 256) {
        int l = idx >> 10, cc = idx & 1023;
        int t = t0 + l;
        float xv = X[(size_t)t * C_DIM + cc];
        float pv = (t == 0) ? xprev[cc] : X[(size_t)(t - 1) * C_DIM + cc];
        As[idx] = xv + (pv - xv) * mixv[cc];
    }
    __syncthreads();
    const int l = tid / Kh;
    const int j = tid % Kh;
    const float* arow = As + (l << 10);
    float acc = 0.f;
#pragma unroll 4
    for (int cc = 0; cc < 1024; ++cc)
        acc = fmaf(arow[cc], W1[(size_t)cc * Kh + j], acc);
    if (act == 1) acc = tanhf(acc);
    else if (act == 2) acc = sigf(acc);
    hbuf[(size_t)(t0 + l) * Kh + j] = acc;
}

// ---------------------------------------------------------------------------
// LoRA stage 2
// ---------------------------------------------------------------------------
__global__ __launch_bounds__(256) void lora2(
    const float* __restrict__ hbuf, const float* __restrict__ W2,
    const float* __restrict__ bias, float* __restrict__ outp,
    const float* __restrict__ vfirst, int Kh, int mode)
{
    __shared__ __align__(16) float hs[128];
    const int t = blockIdx.y;
    const int i = blockIdx.x * 256 + threadIdx.x;
    if (threadIdx.x < Kh) hs[threadIdx.x] = hbuf[(size_t)t * Kh + threadIdx.x];
    __syncthreads();
    float acc = bias ? bias[i] : 0.f;
#pragma unroll 8
    for (int j = 0; j < Kh; ++j)
        acc = fmaf(hs[j], W2[(size_t)j * C_DIM + i], acc);
    const size_t idx = (size_t)t * C_DIM + i;
    if (mode == 0) {
        outp[idx] = __expf(-0.6065306597126334f * sigf(acc));
    } else if (mode == 1) {
        outp[idx] = sigf(acc);
    } else if (mode == 2) {
        float s = sigf(acc);
        float vr = outp[idx];
        outp[idx] = vr + (vfirst[idx] - vr) * s;
    } else {
        outp[idx] = acc;
    }
}

// ---------------------------------------------------------------------------
// k post-process
// ---------------------------------------------------------------------------
__global__ __launch_bounds__(256) void kpost(
    float* __restrict__ kbuf, float* __restrict__ abuf, float* __restrict__ kkbuf,
    const float* __restrict__ k_k, const float* __restrict__ k_a)
{
    const int t = blockIdx.x, tid = threadIdx.x;
    const int c0 = tid << 2;
    const size_t base = (size_t)t * C_DIM + c0;
    float4 kr  = *(float4*)(kbuf + base);
    float4 kkw = *(const float4*)(k_k + c0);
    float4 kav = *(const float4*)(k_a + c0);
    float4 av  = *(float4*)(abuf + base);
    float4 kn = {kr.x * kkw.x, kr.y * kkw.y, kr.z * kkw.z, kr.w * kkw.w};
    float ss = kn.x * kn.x + kn.y * kn.y + kn.z * kn.z + kn.w * kn.w;
#pragma unroll
    for (int m = 1; m <= 8; m <<= 1) ss += __shfl_xor(ss, m);
    const float scale = 1.f / fmaxf(sqrtf(ss), 1e-12f);
    float4 kkv = {kn.x * scale, kn.y * scale, kn.z * scale, kn.w * scale};
    *(float4*)(kkbuf + base) = kkv;
    float4 bb = {kkv.x * av.x, kkv.y * av.y, kkv.z * av.z, kkv.w * av.w};
    *(float4*)(abuf + base) = bb;
    float4 kf = {kr.x * (1.f + (av.x - 1.f) * kav.x),
                 kr.y * (1.f + (av.y - 1.f) * kav.y),
                 kr.z * (1.f + (av.z - 1.f) * kav.z),
                 kr.w * (1.f + (av.w - 1.f) * kav.w)};
    *(float4*)(kbuf + base) = kf;
}

// ---------------------------------------------------------------------------
// Chunked scan phase A (parallel over head x chunk, L=16).
// Produces per-(h,c) tiles: R~, A~, B^, K^, Zl (transposed [v][t]),
// Vt (transposed [v][s]), pL; and writes O_loc into yB.
// ---------------------------------------------------------------------------
__global__ __launch_bounds__(256) void chunk_prep(
    const float* __restrict__ rb, const float* __restrict__ ewb,
    const float* __restrict__ kb, const float* __restrict__ vb,
    const float* __restrict__ kkb, const float* __restrict__ bbb,
    float* __restrict__ tiles, float* __restrict__ yB)
{
    const int c = blockIdx.x;   // chunk 0..127
    const int h = blockIdx.y;   // head 0..15
    const int tid = threadIdx.x;
    __shared__ float sQ[16][64];           // exclusive cumprod
    __shared__ float sP[16][64];           // ew then inclusive cumprod
    __shared__ float sA[16][68], sB[16][68], sK[16][68], sR[16][68], sV[16][68];
    __shared__ float sY[16][68], sZ[16][68], sAt[16][68];
    __shared__ float mG[16][17], mGk[16][17], mRB[16][17], mRK[16][17], mM[16][17];

    const size_t gbase = (size_t)(c * 16) * C_DIM + h * 64;
    const size_t tb = (size_t)(h * 128 + c) * TSTRIDE;

    // 1. load exp(w) tile
    for (int e = tid; e < 1024; e += 256) {
        const int i = e >> 6, j = e & 63;
        sP[i][j] = ewb[gbase + (size_t)i * C_DIM + j];
    }
    __syncthreads();
    // 2. cumprods (64 columns in parallel, serial over 16 steps)
    if (tid < 64) {
        const int j = tid;
        float q = 1.f;
#pragma unroll
        for (int i = 0; i < 16; ++i) {
            const float e = sP[i][j];
            sQ[i][j] = q;
            q *= e;
            sP[i][j] = q;
        }
        tiles[tb + 6144 + j] = q;   // p_L
    }
    __syncthreads();
    // 3. hat quantities
    for (int e = tid; e < 1024; e += 256) {
        const int i = e >> 6, j = e & 63;
        const size_t g = gbase + (size_t)i * C_DIM + j;
        const float q = sQ[i][j], p = sP[i][j];
        const float rp = 1.f / p;
        const float ah = -kkb[g] * q;   // a = -kk
        const float bh = bbb[g] * rp;
        const float kh = kb[g] * rp;
        const float rh = rb[g] * p;
        const float vv = vb[g];
        sA[i][j] = ah; sB[i][j] = bh; sK[i][j] = kh; sR[i][j] = rh; sV[i][j] = vv;
        tiles[tb + 2048 + i * 64 + j] = bh;
        tiles[tb + 3072 + i * 64 + j] = kh;
        tiles[tb + 5120 + j * 16 + i] = vv;       // Vt[v][s]
    }
    __syncthreads();
    // 4. 16x16 gram matrices
    {
        const int t = tid >> 4, s = tid & 15;
        float gab = 0.f, gak = 0.f, grb = 0.f, grk = 0.f;
#pragma unroll 8
        for (int j = 0; j < 64; ++j) {
            const float at = sA[t][j], rt = sR[t][j];
            const float bs = sB[s][j], ks = sK[s][j];
            gab = fmaf(at, bs, gab);
            gak = fmaf(at, ks, gak);
            grb = fmaf(rt, bs, grb);
            grk = fmaf(rt, ks, grk);
        }
        mG[t][s]  = (s < t)  ? gab : 0.f;
        mGk[t][s] = (s < t)  ? gak : 0.f;
        mRB[t][s] = (s <= t) ? grb : 0.f;
        mRK[t][s] = (s <= t) ? grk : 0.f;
    }
    __syncthreads();
    // 5. M = (I - mG)^{-1} by forward substitution (16 columns)
    if (tid < 16) {
        const int col = tid;
        float m[16];
        for (int t = 0; t < 16; ++t) {
            float acc = (t == col) ? 1.f : 0.f;
            for (int s = col; s < t; ++s)
                acc = fmaf(mG[t][s], m[s], acc);
            m[t] = acc;
        }
        for (int t = 0; t < 16; ++t) mM[t][col] = m[t];
    }
    __syncthreads();
    // 6. Y = Gak*V ; A~ = M*A
    {
        const int t = tid >> 4, j0 = (tid & 15) * 4;
        float y[4] = {0,0,0,0}, a[4] = {0,0,0,0};
#pragma unroll
        for (int s = 0; s < 16; ++s) {
            const float gk = mGk[t][s], mm = mM[t][s];
#pragma unroll
            for (int u = 0; u < 4; ++u) {
                y[u] = fmaf(gk, sV[s][j0 + u], y[u]);
                a[u] = fmaf(mm, sA[s][j0 + u], a[u]);
            }
        }
#pragma unroll
        for (int u = 0; u < 4; ++u) {
            sY[t][j0 + u] = y[u];
            sAt[t][j0 + u] = a[u];
            tiles[tb + 1024 + t * 64 + j0 + u] = a[u];
        }
    }
    __syncthreads();
    // 7. Zl = M*Y ; R~ = R^ + RB*A~
    {
        const int t = tid >> 4, j0 = (tid & 15) * 4;
        float z[4] = {0,0,0,0};
        float rt[4];
#pragma unroll
        for (int u = 0; u < 4; ++u) rt[u] = sR[t][j0 + u];
#pragma unroll
        for (int s = 0; s < 16; ++s) {
            const float mm = mM[t][s], rb_ = mRB[t][s];
#pragma unroll
            for (int u = 0; u < 4; ++u) {
                z[u] = fmaf(mm, sY[s][j0 + u], z[u]);
                rt[u] = fmaf(rb_, sAt[s][j0 + u], rt[u]);
            }
        }
#pragma unroll
        for (int u = 0; u < 4; ++u) {
            sZ[t][j0 + u] = z[u];
            tiles[tb + 4096 + (j0 + u) * 16 + t] = z[u];   // Zl[v][t]
            tiles[tb + 0 + t * 64 + j0 + u] = rt[u];
        }
    }
    __syncthreads();
    // 8. O_loc = RB*Zl + RK*V  -> yB
    {
        const int t = tid >> 4, j0 = (tid & 15) * 4;
        float o[4] = {0,0,0,0};
#pragma unroll
        for (int s = 0; s < 16; ++s) {
            const float rb_ = mRB[t][s], rk_ = mRK[t][s];
#pragma unroll
            for (int u = 0; u < 4; ++u)
                o[u] = fmaf(rb_, sZ[s][j0 + u], fmaf(rk_, sV[s][j0 + u], o[u]));
        }
#pragma unroll
        for (int u = 0; u < 4; ++u)
            yB[(size_t)(c * 16 + t) * C_DIM + h * 64 + j0 + u] = o[u];
    }
}

// ---------------------------------------------------------------------------
// Chunked scan phase B (sequential over 128 chunks, one block per head).
// Wave w owns key-slice j in [16w,16w+16); lane l = value row v.
// Per chunk: O += R~ S0^T ; Z = Zl + A~ S0^T ; S = (S0 + Z^T B^ + V^T K^) diag(pL)
// Tile reads are wave-uniform (SGPR-friendly via readfirstlane wave id).
// ---------------------------------------------------------------------------
__global__ __launch_bounds__(256) void chunk_scan(
    const float* __restrict__ tiles, const float* __restrict__ init_state,
    float* __restrict__ yB)
{
    const int h = blockIdx.x;
    const int tid = threadIdx.x;
    const int l = tid & 63;
    const int w = __builtin_amdgcn_readfirstlane(tid >> 6);
    const int jb = w << 4;
    __shared__ float redO[4][64][16];
    __shared__ float redZ[4][64][16];
    float S[16];
    {
        const float* is = init_state + h * 4096 + l * 64 + jb;
#pragma unroll
        for (int u = 0; u < 4; ++u) {
            float4 t4 = *(const float4*)(is + u * 4);
            S[u * 4 + 0] = t4.x; S[u * 4 + 1] = t4.y;
            S[u * 4 + 2] = t4.z; S[u * 4 + 3] = t4.w;
        }
    }
    for (int c = 0; c < 128; ++c) {
        const float* tp = tiles + (size_t)(h * 128 + c) * TSTRIDE;
        // per-lane vector loads: Z_loc and V for row v=l
        float Zr[16], Vr[16];
#pragma unroll
        for (int u = 0; u < 4; ++u) {
            float4 z4 = *(const float4*)(tp + 4096 + l * 16 + u * 4);
            float4 v4 = *(const float4*)(tp + 5120 + l * 16 + u * 4);
            Zr[u * 4 + 0] = z4.x; Zr[u * 4 + 1] = z4.y;
            Zr[u * 4 + 2] = z4.z; Zr[u * 4 + 3] = z4.w;
            Vr[u * 4 + 0] = v4.x; Vr[u * 4 + 1] = v4.y;
            Vr[u * 4 + 2] = v4.z; Vr[u * 4 + 3] = v4.w;
        }
        // partial O/Z over this wave's j-slice (tile operands wave-uniform)
        float po[16], pz[16];
#pragma unroll
        for (int t = 0; t < 16; ++t) {
            const float* rt = tp + t * 64 + jb;
            const float* at = tp + 1024 + t * 64 + jb;
            float o = 0.f, z = 0.f;
#pragma unroll
            for (int i = 0; i < 16; ++i) {
                o = fmaf(rt[i], S[i], o);
                z = fmaf(at[i], S[i], z);
            }
            po[t] = o; pz[t] = z;
        }
#pragma unroll
        for (int u = 0; u < 4; ++u) {
            *(float4*)&redO[w][l][u * 4] =
                make_float4(po[u * 4], po[u * 4 + 1], po[u * 4 + 2], po[u * 4 + 3]);
            *(float4*)&redZ[w][l][u * 4] =
                make_float4(pz[u * 4], pz[u * 4 + 1], pz[u * 4 + 2], pz[u * 4 + 3]);
        }
        __syncthreads();
        // full Z for v = l  (Zr holds Z_loc)
#pragma unroll
        for (int w2 = 0; w2 < 4; ++w2) {
#pragma unroll
            for (int u = 0; u < 4; ++u) {
                float4 z4 = *(const float4*)&redZ[w2][l][u * 4];
                Zr[u * 4 + 0] += z4.x; Zr[u * 4 + 1] += z4.y;
                Zr[u * 4 + 2] += z4.z; Zr[u * 4 + 3] += z4.w;
            }
        }
        // O for this wave's t-range [4w, 4w+4), accumulate onto O_loc in yB
        float of[4] = {0.f, 0.f, 0.f, 0.f};
#pragma unroll
        for (int w2 = 0; w2 < 4; ++w2) {
            float4 o4 = *(const float4*)&redO[w2][l][4 * w];
            of[0] += o4.x; of[1] += o4.y; of[2] += o4.z; of[3] += o4.w;
        }
#pragma unroll
        for (int u = 0; u < 4; ++u) {
            const size_t oidx = (size_t)(c * 16 + 4 * w + u) * C_DIM + h * 64 + l;
            yB[oidx] += of[u];
        }
        // state update
#pragma unroll
        for (int s = 0; s < 16; ++s) {
            const float* bh = tp + 2048 + s * 64 + jb;
            const float* kh = tp + 3072 + s * 64 + jb;
            const float zs = Zr[s], vs = Vr[s];
#pragma unroll
            for (int i = 0; i < 16; ++i)
                S[i] = fmaf(zs, bh[i], fmaf(vs, kh[i], S[i]));
        }
        const float* pl = tp + 6144 + jb;
#pragma unroll
        for (int i = 0; i < 16; ++i) S[i] *= pl[i];
        __syncthreads();   // protect red buffers for next chunk
    }
}

// ---------------------------------------------------------------------------
// Fallback sequential scan (used only if workspace too small for tiles)
// ---------------------------------------------------------------------------
__global__ __launch_bounds__(256) void scan_kernel(
    const float* __restrict__ rb, const float* __restrict__ ewb,
    const float* __restrict__ kb, const float* __restrict__ vb,
    const float* __restrict__ kkb, const float* __restrict__ bbb,
    const float* __restrict__ init_state, float* __restrict__ y)
{
    const int h = blockIdx.x;
    const int tid = threadIdx.x;
    const int vrow = tid >> 2;
    const int q = tid & 3;
    const int jb = q << 4;
    __shared__ __align__(16) float rs[2][64], ews[2][64], ks[2][64],
                                   vs[2][64], aas[2][64], bbs[2][64];
    float S[16];
    const float* is = init_state + h * 4096 + vrow * 64 + jb;
#pragma unroll
    for (int i = 0; i < 16; ++i) S[i] = is[i];

    const int cb = h * 64;
    const int role = tid >> 6;
    const int lane = tid & 63;

    float p0 = 0.f, p1 = 0.f;
    {
        const int base = cb + lane;
        if (role == 0)      { p0 = rb[base];  p1 = ewb[base]; }
        else if (role == 1) { p0 = kb[base];  p1 = vb[base]; }
        else if (role == 2) { p0 = -kkb[base]; p1 = bbb[base]; }
    }
    if (role == 0)      { rs[0][lane] = p0;  ews[0][lane] = p1; }
    else if (role == 1) { ks[0][lane] = p0;  vs[0][lane]  = p1; }
    else if (role == 2) { aas[0][lane] = p0; bbs[0][lane] = p1; }
    __syncthreads();

    for (int t = 0; t < T_LEN; ++t) {
        const int cur = t & 1, nxt = cur ^ 1;
        if (t + 1 < T_LEN) {
            const int base = (t + 1) * C_DIM + cb + lane;
            if (role == 0)      { p0 = rb[base];  p1 = ewb[base]; }
            else if (role == 1) { p0 = kb[base];  p1 = vb[base]; }
            else if (role == 2) { p0 = -kkb[base]; p1 = bbb[base]; }
        }
        float sa = 0.f;
#pragma unroll
        for (int i = 0; i < 16; ++i) sa = fmaf(S[i], aas[cur][jb + i], sa);
        sa += __shfl_xor(sa, 1);
        sa += __shfl_xor(sa, 2);
        const float vv = vs[cur][vrow];
#pragma unroll
        for (int i = 0; i < 16; ++i)
            S[i] = fmaf(vv, ks[cur][jb + i],
                        fmaf(sa, bbs[cur][jb + i], S[i] * ews[cur][jb + i]));
        float o = 0.f;
#pragma unroll
        for (int i = 0; i < 16; ++i) o = fmaf(S[i], rs[cur][jb + i], o);
        o += __shfl_xor(o, 1);
        o += __shfl_xor(o, 2);
        if (q == 0) y[(size_t)t * C_DIM + cb + vrow] = o;
        if (t + 1 < T_LEN) {
            if (role == 0)      { rs[nxt][lane] = p0;  ews[nxt][lane] = p1; }
            else if (role == 1) { ks[nxt][lane] = p0;  vs[nxt][lane]  = p1; }
            else if (role == 2) { aas[nxt][lane] = p0; bbs[nxt][lane] = p1; }
        }
        __syncthreads();
    }
}

// ---------------------------------------------------------------------------
// GroupNorm + bonus + *g
// ---------------------------------------------------------------------------
__global__ __launch_bounds__(256) void gn_bonus(
    float* __restrict__ y, const float* __restrict__ rb, const float* __restrict__ kb,
    const float* __restrict__ vb, const float* __restrict__ gb,
    const float* __restrict__ r_k, const float* __restrict__ lnw,
    const float* __restrict__ lnb)
{
    const int t = blockIdx.x, tid = threadIdx.x;
    const int c0 = tid << 2;
    const size_t base = (size_t)t * C_DIM + c0;
    float4 yv = *(float4*)(y + base);
    float sum = yv.x + yv.y + yv.z + yv.w;
    float ss  = yv.x * yv.x + yv.y * yv.y + yv.z * yv.z + yv.w * yv.w;
    float4 rv = *(const float4*)(rb + base);
    float4 kv = *(const float4*)(kb + base);
    float4 rkv = *(const float4*)(r_k + c0);
    float dot = rv.x * kv.x * rkv.x + rv.y * kv.y * rkv.y +
                rv.z * kv.z * rkv.z + rv.w * kv.w * rkv.w;
#pragma unroll
    for (int m = 1; m <= 8; m <<= 1) {
        sum += __shfl_xor(sum, m);
        ss  += __shfl_xor(ss, m);
        dot += __shfl_xor(dot, m);
    }
    const float mu = sum * 0.015625f;
    const float var = ss * 0.015625f - mu * mu;
    const float rstd = rsqrtf(var + 0.00064f);
    float4 wv = *(const float4*)(lnw + c0);
    float4 bv = *(const float4*)(lnb + c0);
    float4 vv = *(const float4*)(vb + base);
    float4 gv = *(const float4*)(gb + base);
    float4 o;
    o.x = ((yv.x - mu) * rstd * wv.x + bv.x + dot * vv.x) * gv.x;
    o.y = ((yv.y - mu) * rstd * wv.y + bv.y + dot * vv.y) * gv.y;
    o.z = ((yv.z - mu) * rstd * wv.z + bv.z + dot * vv.z) * gv.z;
    o.w = ((yv.w - mu) * rstd * wv.w + bv.w + dot * vv.w) * gv.w;
    *(float4*)(y + base) = o;
}

// ---------------------------------------------------------------------------
extern "C" void kernel_launch(void* const* d_in, const int* in_sizes, int n_in,
                              void* d_out, int out_size, void* d_ws, size_t ws_size,
                              hipStream_t stream)
{
    (void)in_sizes; (void)n_in; (void)out_size;
    const float* x       = (const float*)d_in[0];
    const float* v_first = (const float*)d_in[1];
    const float* x_prev  = (const float*)d_in[2];
    const float* init_st = (const float*)d_in[3];
    const float* x_r = (const float*)d_in[4];
    const float* x_w = (const float*)d_in[5];
    const float* x_k = (const float*)d_in[6];
    const float* x_v = (const float*)d_in[7];
    const float* x_a = (const float*)d_in[8];
    const float* x_g = (const float*)d_in[9];
    const float* w0  = (const float*)d_in[10];
    const float* a0  = (const float*)d_in[11];
    const float* v0  = (const float*)d_in[12];
    const float* k_k = (const float*)d_in[13];
    const float* k_a = (const float*)d_in[14];
    const float* w1  = (const float*)d_in[15];
    const float* w2  = (const float*)d_in[16];
    const float* a1  = (const float*)d_in[17];
    const float* a2  = (const float*)d_in[18];
    const float* v1  = (const float*)d_in[19];
    const float* v2  = (const float*)d_in[20];
    const float* g1  = (const float*)d_in[21];
    const float* g2  = (const float*)d_in[22];
    const float* r_k = (const float*)d_in[23];
    const float* Wr  = (const float*)d_in[24];
    const float* Wk  = (const float*)d_in[25];
    const float* Wv  = (const float*)d_in[26];
    const float* Wo  = (const float*)d_in[27];
    const float* ln_w = (const float*)d_in[28];
    const float* ln_b = (const float*)d_in[29];

    float* out = (float*)d_out;
    float* ws  = (float*)d_ws;
    const size_t NE = (size_t)T_LEN * C_DIM;
    float* rB  = ws;
    float* ewB = ws + NE;
    float* kB  = ws + 2 * NE;
    float* vB  = ws + 3 * NE;
    float* aB  = ws + 4 * NE;   // a, then bb
    float* gB  = ws + 5 * NE;
    float* kkB = ws + 6 * NE;
    float* yB  = ws + 7 * NE;
    float* hB  = ws + 8 * NE;
    float* tiles = ws + 9 * NE;
    const size_t need_bytes = (9 * NE + (size_t)2048 * TSTRIDE) * sizeof(float);
    const bool chunked = ws_size >= need_bytes;

    dim3 gg(16, 32);
    gemm_nt<<<gg, 256, 0, stream>>>(x, x_prev, x_r, Wr, rB);
    gemm_nt<<<gg, 256, 0, stream>>>(x, x_prev, x_k, Wk, kB);
    gemm_nt<<<gg, 256, 0, stream>>>(x, x_prev, x_v, Wv, vB);

    lora1<<<512, 256, 0, stream>>>(x, x_prev, x_w, w1, hB, 64, 1);
    lora2<<<dim3(4, T_LEN), 256, 0, stream>>>(hB, w2, w0, ewB, nullptr, 64, 0);
    lora1<<<512, 256, 0, stream>>>(x, x_prev, x_a, a1, hB, 64, 0);
    lora2<<<dim3(4, T_LEN), 256, 0, stream>>>(hB, a2, a0, aB, nullptr, 64, 1);
    lora1<<<256, 256, 0, stream>>>(x, x_prev, x_v, v1, hB, 32, 0);
    lora2<<<dim3(4, T_LEN), 256, 0, stream>>>(hB, v2, v0, vB, v_first, 32, 2);
    lora1<<<1024, 256, 0, stream>>>(x, x_prev, x_g, g1, hB, 128, 2);
    lora2<<<dim3(4, T_LEN), 256, 0, stream>>>(hB, g2, nullptr, gB, nullptr, 128, 3);

    kpost<<<T_LEN, 256, 0, stream>>>(kB, aB, kkB, k_k, k_a);
    if (chunked) {
        chunk_prep<<<dim3(128, 16), 256, 0, stream>>>(rB, ewB, kB, vB, kkB, aB,
                                                      tiles, yB);
        chunk_scan<<<16, 256, 0, stream>>>(tiles, init_st, yB);
    } else {
        scan_kernel<<<16, 256, 0, stream>>>(rB, ewB, kB, vB, kkB, aB, init_st, yB);
    }
    gn_bonus<<<T_LEN, 256, 0, stream>>>(yB, rB, kB, vB, gB, r_k, ln_w, ln_b);
    gemm_nt<<<gg, 256, 0, stream>>>(yB, yB, nullptr, Wo, out);
}

// Round 3
// 1491.805 us; speedup vs baseline: 1.7403x; 1.7403x over previous
//
#include <hip/hip_runtime.h>

#define T_LEN 2048
#define C_DIM 1024
// chunked-scan tile layout (floats per (head,chunk) tile), padded to 25 KB
// offsets: R~ 0, A~ 1024, B^ 2048, K^ 3072, Zl[t][v] 4096, V[t][v] 5120, pL 6144
#define TSTRIDE 6400

static __device__ __forceinline__ float sigf(float x) {
    return 1.f / (1.f + __expf(-x));
}

// ---------------------------------------------------------------------------
// NT GEMM: out[t,i] = sum_c A(t,c) * W[i,c];  A = mixv ? x + (shift-x)*mix : X
// ---------------------------------------------------------------------------
__global__ __launch_bounds__(256) void gemm_nt(
    const float* __restrict__ X, const float* __restrict__ xprev,
    const float* __restrict__ mixv, const float* __restrict__ W,
    float* __restrict__ out)
{
    __shared__ __align__(16) float As[16][68];
    __shared__ __align__(16) float Ws[16][68];
    const int tid = threadIdx.x;
    const int t0 = blockIdx.y * 64;
    const int n0 = blockIdx.x * 64;
    const int lr = tid >> 2;
    const int lk = (tid & 3) << 2;
    const int ty = tid >> 4;
    const int tx = tid & 15;
    float acc[4][4] = {{0.f}};

    const int trow = t0 + lr;
    const float* xrow  = X + (size_t)trow * C_DIM;
    const float* xprow = (trow == 0) ? xprev : (X + (size_t)(trow - 1) * C_DIM);
    const float* wrow  = W + (size_t)(n0 + lr) * C_DIM;

    for (int k0 = 0; k0 < C_DIM; k0 += 16) {
        float4 xv = *(const float4*)(xrow + k0 + lk);
        if (mixv) {
            float4 pv = *(const float4*)(xprow + k0 + lk);
            float4 mv = *(const float4*)(mixv + k0 + lk);
            xv.x += (pv.x - xv.x) * mv.x;
            xv.y += (pv.y - xv.y) * mv.y;
            xv.z += (pv.z - xv.z) * mv.z;
            xv.w += (pv.w - xv.w) * mv.w;
        }
        As[lk + 0][lr] = xv.x; As[lk + 1][lr] = xv.y;
        As[lk + 2][lr] = xv.z; As[lk + 3][lr] = xv.w;
        float4 wv = *(const float4*)(wrow + k0 + lk);
        Ws[lk + 0][lr] = wv.x; Ws[lk + 1][lr] = wv.y;
        Ws[lk + 2][lr] = wv.z; Ws[lk + 3][lr] = wv.w;
        __syncthreads();
#pragma unroll
        for (int kk = 0; kk < 16; ++kk) {
            float4 av = *(const float4*)&As[kk][ty << 2];
            float4 bv = *(const float4*)&Ws[kk][tx << 2];
            float a_[4] = {av.x, av.y, av.z, av.w};
            float b_[4] = {bv.x, bv.y, bv.z, bv.w};
#pragma unroll
            for (int i = 0; i < 4; ++i)
#pragma unroll
                for (int j = 0; j < 4; ++j)
                    acc[i][j] = fmaf(a_[i], b_[j], acc[i][j]);
        }
        __syncthreads();
    }
#pragma unroll
    for (int i = 0; i < 4; ++i) {
        float4 o4 = {acc[i][0], acc[i][1], acc[i][2], acc[i][3]};
        *(float4*)(out + (size_t)(t0 + (ty << 2) + i) * C_DIM + n0 + (tx << 2)) = o4;
    }
}

// ---------------------------------------------------------------------------
// LoRA stage 1
// ---------------------------------------------------------------------------
__global__ __launch_bounds__(256) void lora1(
    const float* __restrict__ X, const float* __restrict__ xprev,
    const float* __restrict__ mixv, const float* __restrict__ W1,
    float* __restrict__ hbuf, int Kh, int act)
{
    __shared__ __align__(16) float As[8192];
    const int tid = threadIdx.x;
    const int tpb = 256 / Kh;
    const int t0 = blockIdx.x * tpb;
    for (int idx = tid; idx < (tpb << 10); idx += 256) {
        int l = idx >> 10, cc = idx & 1023;
        int t = t0 + l;
        float xv = X[(size_t)t * C_DIM + cc];
        float pv = (t == 0) ? xprev[cc] : X[(size_t)(t - 1) * C_DIM + cc];
        As[idx] = xv + (pv - xv) * mixv[cc];
    }
    __syncthreads();
    const int l = tid / Kh;
    const int j = tid % Kh;
    const float* arow = As + (l << 10);
    float acc = 0.f;
#pragma unroll 4
    for (int cc = 0; cc < 1024; ++cc)
        acc = fmaf(arow[cc], W1[(size_t)cc * Kh + j], acc);
    if (act == 1) acc = tanhf(acc);
    else if (act == 2) acc = sigf(acc);
    hbuf[(size_t)(t0 + l) * Kh + j] = acc;
}

// ---------------------------------------------------------------------------
// LoRA stage 2
// ---------------------------------------------------------------------------
__global__ __launch_bounds__(256) void lora2(
    const float* __restrict__ hbuf, const float* __restrict__ W2,
    const float* __restrict__ bias, float* __restrict__ outp,
    const float* __restrict__ vfirst, int Kh, int mode)
{
    __shared__ __align__(16) float hs[128];
    const int t = blockIdx.y;
    const int i = blockIdx.x * 256 + threadIdx.x;
    if (threadIdx.x < Kh) hs[threadIdx.x] = hbuf[(size_t)t * Kh + threadIdx.x];
    __syncthreads();
    float acc = bias ? bias[i] : 0.f;
#pragma unroll 8
    for (int j = 0; j < Kh; ++j)
        acc = fmaf(hs[j], W2[(size_t)j * C_DIM + i], acc);
    const size_t idx = (size_t)t * C_DIM + i;
    if (mode == 0) {
        outp[idx] = __expf(-0.6065306597126334f * sigf(acc));
    } else if (mode == 1) {
        outp[idx] = sigf(acc);
    } else if (mode == 2) {
        float s = sigf(acc);
        float vr = outp[idx];
        outp[idx] = vr + (vfirst[idx] - vr) * s;
    } else {
        outp[idx] = acc;
    }
}

// ---------------------------------------------------------------------------
// k post-process
// ---------------------------------------------------------------------------
__global__ __launch_bounds__(256) void kpost(
    float* __restrict__ kbuf, float* __restrict__ abuf, float* __restrict__ kkbuf,
    const float* __restrict__ k_k, const float* __restrict__ k_a)
{
    const int t = blockIdx.x, tid = threadIdx.x;
    const int c0 = tid << 2;
    const size_t base = (size_t)t * C_DIM + c0;
    float4 kr  = *(float4*)(kbuf + base);
    float4 kkw = *(const float4*)(k_k + c0);
    float4 kav = *(const float4*)(k_a + c0);
    float4 av  = *(float4*)(abuf + base);
    float4 kn = {kr.x * kkw.x, kr.y * kkw.y, kr.z * kkw.z, kr.w * kkw.w};
    float ss = kn.x * kn.x + kn.y * kn.y + kn.z * kn.z + kn.w * kn.w;
#pragma unroll
    for (int m = 1; m <= 8; m <<= 1) ss += __shfl_xor(ss, m);
    const float scale = 1.f / fmaxf(sqrtf(ss), 1e-12f);
    float4 kkv = {kn.x * scale, kn.y * scale, kn.z * scale, kn.w * scale};
    *(float4*)(kkbuf + base) = kkv;
    float4 bb = {kkv.x * av.x, kkv.y * av.y, kkv.z * av.z, kkv.w * av.w};
    *(float4*)(abuf + base) = bb;
    float4 kf = {kr.x * (1.f + (av.x - 1.f) * kav.x),
                 kr.y * (1.f + (av.y - 1.f) * kav.y),
                 kr.z * (1.f + (av.z - 1.f) * kav.z),
                 kr.w * (1.f + (av.w - 1.f) * kav.w)};
    *(float4*)(kbuf + base) = kf;
}

// ---------------------------------------------------------------------------
// Chunked scan phase A (parallel over head x chunk, L=16).
// Tiles per (h,c): R~[t][j], A~[t][j], B^[s][j], K^[s][j], Zl[t][v], V[s][v], pL
// Also writes O_loc into yB.
// ---------------------------------------------------------------------------
__global__ __launch_bounds__(256) void chunk_prep(
    const float* __restrict__ rb, const float* __restrict__ ewb,
    const float* __restrict__ kb, const float* __restrict__ vb,
    const float* __restrict__ kkb, const float* __restrict__ bbb,
    float* __restrict__ tiles, float* __restrict__ yB)
{
    const int c = blockIdx.x;   // chunk 0..127
    const int h = blockIdx.y;   // head 0..15
    const int tid = threadIdx.x;
    __shared__ float sQ[16][64];
    __shared__ float sP[16][64];
    __shared__ float sA[16][68], sB[16][68], sK[16][68], sR[16][68], sV[16][68];
    __shared__ float sY[16][68], sZ[16][68], sAt[16][68];
    __shared__ float mG[16][17], mGk[16][17], mRB[16][17], mRK[16][17], mM[16][17];

    const size_t gbase = (size_t)(c * 16) * C_DIM + h * 64;
    const size_t tb = (size_t)(h * 128 + c) * TSTRIDE;

    // 1. load exp(w) tile
    for (int e = tid; e < 1024; e += 256) {
        const int i = e >> 6, j = e & 63;
        sP[i][j] = ewb[gbase + (size_t)i * C_DIM + j];
    }
    __syncthreads();
    // 2. cumprods
    if (tid < 64) {
        const int j = tid;
        float q = 1.f;
#pragma unroll
        for (int i = 0; i < 16; ++i) {
            const float e = sP[i][j];
            sQ[i][j] = q;
            q *= e;
            sP[i][j] = q;
        }
        tiles[tb + 6144 + j] = q;   // p_L
    }
    __syncthreads();
    // 3. hat quantities
    for (int e = tid; e < 1024; e += 256) {
        const int i = e >> 6, j = e & 63;
        const size_t g = gbase + (size_t)i * C_DIM + j;
        const float q = sQ[i][j], p = sP[i][j];
        const float rp = 1.f / p;
        const float ah = -kkb[g] * q;   // a = -kk
        const float bh = bbb[g] * rp;
        const float kh = kb[g] * rp;
        const float rh = rb[g] * p;
        const float vv = vb[g];
        sA[i][j] = ah; sB[i][j] = bh; sK[i][j] = kh; sR[i][j] = rh; sV[i][j] = vv;
        tiles[tb + 2048 + i * 64 + j] = bh;
        tiles[tb + 3072 + i * 64 + j] = kh;
        tiles[tb + 5120 + i * 64 + j] = vv;       // V[s][v]
    }
    __syncthreads();
    // 4. 16x16 gram matrices
    {
        const int t = tid >> 4, s = tid & 15;
        float gab = 0.f, gak = 0.f, grb = 0.f, grk = 0.f;
#pragma unroll 8
        for (int j = 0; j < 64; ++j) {
            const float at = sA[t][j], rt = sR[t][j];
            const float bs = sB[s][j], ks = sK[s][j];
            gab = fmaf(at, bs, gab);
            gak = fmaf(at, ks, gak);
            grb = fmaf(rt, bs, grb);
            grk = fmaf(rt, ks, grk);
        }
        mG[t][s]  = (s < t)  ? gab : 0.f;
        mGk[t][s] = (s < t)  ? gak : 0.f;
        mRB[t][s] = (s <= t) ? grb : 0.f;
        mRK[t][s] = (s <= t) ? grk : 0.f;
    }
    __syncthreads();
    // 5. M = (I - mG)^{-1} forward substitution
    if (tid < 16) {
        const int col = tid;
        float m[16];
        for (int t = 0; t < 16; ++t) {
            float acc = (t == col) ? 1.f : 0.f;
            for (int s = col; s < t; ++s)
                acc = fmaf(mG[t][s], m[s], acc);
            m[t] = acc;
        }
        for (int t = 0; t < 16; ++t) mM[t][col] = m[t];
    }
    __syncthreads();
    // 6. Y = Gak*V ; A~ = M*A
    {
        const int t = tid >> 4, j0 = (tid & 15) * 4;
        float y[4] = {0,0,0,0}, a[4] = {0,0,0,0};
#pragma unroll
        for (int s = 0; s < 16; ++s) {
            const float gk = mGk[t][s], mm = mM[t][s];
#pragma unroll
            for (int u = 0; u < 4; ++u) {
                y[u] = fmaf(gk, sV[s][j0 + u], y[u]);
                a[u] = fmaf(mm, sA[s][j0 + u], a[u]);
            }
        }
#pragma unroll
        for (int u = 0; u < 4; ++u) {
            sY[t][j0 + u] = y[u];
            sAt[t][j0 + u] = a[u];
            tiles[tb + 1024 + t * 64 + j0 + u] = a[u];
        }
    }
    __syncthreads();
    // 7. Zl = M*Y ; R~ = R^ + RB*A~
    {
        const int t = tid >> 4, j0 = (tid & 15) * 4;
        float z[4] = {0,0,0,0};
        float rt[4];
#pragma unroll
        for (int u = 0; u < 4; ++u) rt[u] = sR[t][j0 + u];
#pragma unroll
        for (int s = 0; s < 16; ++s) {
            const float mm = mM[t][s], rb_ = mRB[t][s];
#pragma unroll
            for (int u = 0; u < 4; ++u) {
                z[u] = fmaf(mm, sY[s][j0 + u], z[u]);
                rt[u] = fmaf(rb_, sAt[s][j0 + u], rt[u]);
            }
        }
#pragma unroll
        for (int u = 0; u < 4; ++u) {
            sZ[t][j0 + u] = z[u];
            tiles[tb + 4096 + t * 64 + j0 + u] = z[u];   // Zl[t][v]
            tiles[tb + 0 + t * 64 + j0 + u] = rt[u];
        }
    }
    __syncthreads();
    // 8. O_loc = RB*Zl + RK*V  -> yB
    {
        const int t = tid >> 4, j0 = (tid & 15) * 4;
        float o[4] = {0,0,0,0};
#pragma unroll
        for (int s = 0; s < 16; ++s) {
            const float rb_ = mRB[t][s], rk_ = mRK[t][s];
#pragma unroll
            for (int u = 0; u < 4; ++u)
                o[u] = fmaf(rb_, sZ[s][j0 + u], fmaf(rk_, sV[s][j0 + u], o[u]));
        }
#pragma unroll
        for (int u = 0; u < 4; ++u)
            yB[(size_t)(c * 16 + t) * C_DIM + h * 64 + j0 + u] = o[u];
    }
}

// ---------------------------------------------------------------------------
// Chunked scan phase B: sequential over 128 chunks, one block per head.
// LDS double-buffered tile staging via global_load_lds; prefetch of chunk c+1
// overlaps Z-assembly + state update of chunk c, drained at the end barrier.
// ---------------------------------------------------------------------------
__global__ __launch_bounds__(256) void chunk_scan2(
    const float* __restrict__ tiles, const float* __restrict__ init_state,
    float* __restrict__ yB)
{
    const int h = blockIdx.x;
    const int tid = threadIdx.x;
    const int l = tid & 63;
    const int w = __builtin_amdgcn_readfirstlane(tid >> 6);
    const int jb = w << 4;
    __shared__ __align__(16) float buf[2][TSTRIDE];
    __shared__ float redO[4][16][64];
    __shared__ float redZ[4][16][64];

    float S[16];
    {
        const float* is = init_state + h * 4096 + l * 64 + jb;
#pragma unroll
        for (int u = 0; u < 4; ++u) {
            float4 t4 = *(const float4*)(is + u * 4);
            S[u * 4 + 0] = t4.x; S[u * 4 + 1] = t4.y;
            S[u * 4 + 2] = t4.z; S[u * 4 + 3] = t4.w;
        }
    }
    // preload chunk 0 (25 KB = 25 x 1KB wave-instructions, split across waves)
    {
        const float* src = tiles + (size_t)(h * 128) * TSTRIDE;
        for (int i = w; i < 25; i += 4)
            __builtin_amdgcn_global_load_lds(
                (const __attribute__((address_space(1))) unsigned int*)(src + i * 256 + l * 4),
                (__attribute__((address_space(3))) unsigned int*)(&buf[0][i * 256 + l * 4]),
                16, 0, 0);
    }
    __syncthreads();

    for (int c = 0; c < 128; ++c) {
        const int cur = c & 1, nxt = cur ^ 1;
        const float* tp = buf[cur];
        // partial o/z over this wave's j-slice (wave-uniform LDS broadcasts)
#pragma unroll
        for (int t = 0; t < 16; ++t) {
            const float4* rt4 = (const float4*)(tp + t * 64 + jb);
            const float4* at4 = (const float4*)(tp + 1024 + t * 64 + jb);
            float o = 0.f, z = 0.f;
#pragma unroll
            for (int u = 0; u < 4; ++u) {
                const float4 rv = rt4[u], av = at4[u];
                o = fmaf(rv.x, S[u * 4 + 0], o); z = fmaf(av.x, S[u * 4 + 0], z);
                o = fmaf(rv.y, S[u * 4 + 1], o); z = fmaf(av.y, S[u * 4 + 1], z);
                o = fmaf(rv.z, S[u * 4 + 2], o); z = fmaf(av.z, S[u * 4 + 2], z);
                o = fmaf(rv.w, S[u * 4 + 3], o); z = fmaf(av.w, S[u * 4 + 3], z);
            }
            redO[w][t][l] = o;
            redZ[w][t][l] = z;
        }
        __syncthreads();
        // prefetch next chunk (in flight during the rest of this iteration)
        if (c + 1 < 128) {
            const float* src = tiles + (size_t)(h * 128 + c + 1) * TSTRIDE;
            for (int i = w; i < 25; i += 4)
                __builtin_amdgcn_global_load_lds(
                    (const __attribute__((address_space(1))) unsigned int*)(src + i * 256 + l * 4),
                    (__attribute__((address_space(3))) unsigned int*)(&buf[nxt][i * 256 + l * 4]),
                    16, 0, 0);
        }
        // assemble full Z rows and V rows for value-row v = l (conflict-free)
        float Zf[16], Vv[16];
#pragma unroll
        for (int s = 0; s < 16; ++s) {
            Zf[s] = tp[4096 + s * 64 + l] + redZ[0][s][l] + redZ[1][s][l]
                  + redZ[2][s][l] + redZ[3][s][l];
            Vv[s] = tp[5120 + s * 64 + l];
        }
        // O rows t = 4w..4w+3 -> accumulate onto O_loc in yB (coalesced)
#pragma unroll
        for (int u = 0; u < 4; ++u) {
            const int t = 4 * w + u;
            const float o = redO[0][t][l] + redO[1][t][l]
                          + redO[2][t][l] + redO[3][t][l];
            yB[(size_t)(c * 16 + t) * C_DIM + h * 64 + l] += o;
        }
        // state update: S[v][j] += Z[s][v]*B^[s][j] + V[s][v]*K^[s][j], then *pL
#pragma unroll
        for (int s = 0; s < 16; ++s) {
            const float4* bh4 = (const float4*)(tp + 2048 + s * 64 + jb);
            const float4* kh4 = (const float4*)(tp + 3072 + s * 64 + jb);
            const float zs = Zf[s], vs = Vv[s];
#pragma unroll
            for (int u = 0; u < 4; ++u) {
                const float4 bv = bh4[u], kv = kh4[u];
                S[u * 4 + 0] = fmaf(zs, bv.x, fmaf(vs, kv.x, S[u * 4 + 0]));
                S[u * 4 + 1] = fmaf(zs, bv.y, fmaf(vs, kv.y, S[u * 4 + 1]));
                S[u * 4 + 2] = fmaf(zs, bv.z, fmaf(vs, kv.z, S[u * 4 + 2]));
                S[u * 4 + 3] = fmaf(zs, bv.w, fmaf(vs, kv.w, S[u * 4 + 3]));
            }
        }
        {
            const float4* pl4 = (const float4*)(tp + 6144 + jb);
#pragma unroll
            for (int u = 0; u < 4; ++u) {
                const float4 pv = pl4[u];
                S[u * 4 + 0] *= pv.x; S[u * 4 + 1] *= pv.y;
                S[u * 4 + 2] *= pv.z; S[u * 4 + 3] *= pv.w;
            }
        }
        __syncthreads();   // drains prefetch vmcnt + protects red buffers
    }
}

// ---------------------------------------------------------------------------
// Fallback sequential scan (used only if workspace too small for tiles)
// ---------------------------------------------------------------------------
__global__ __launch_bounds__(256) void scan_kernel(
    const float* __restrict__ rb, const float* __restrict__ ewb,
    const float* __restrict__ kb, const float* __restrict__ vb,
    const float* __restrict__ kkb, const float* __restrict__ bbb,
    const float* __restrict__ init_state, float* __restrict__ y)
{
    const int h = blockIdx.x;
    const int tid = threadIdx.x;
    const int vrow = tid >> 2;
    const int q = tid & 3;
    const int jb = q << 4;
    __shared__ __align__(16) float rs[2][64], ews[2][64], ks[2][64],
                                   vs[2][64], aas[2][64], bbs[2][64];
    float S[16];
    const float* is = init_state + h * 4096 + vrow * 64 + jb;
#pragma unroll
    for (int i = 0; i < 16; ++i) S[i] = is[i];

    const int cb = h * 64;
    const int role = tid >> 6;
    const int lane = tid & 63;

    float p0 = 0.f, p1 = 0.f;
    {
        const int base = cb + lane;
        if (role == 0)      { p0 = rb[base];  p1 = ewb[base]; }
        else if (role == 1) { p0 = kb[base];  p1 = vb[base]; }
        else if (role == 2) { p0 = -kkb[base]; p1 = bbb[base]; }
    }
    if (role == 0)      { rs[0][lane] = p0;  ews[0][lane] = p1; }
    else if (role == 1) { ks[0][lane] = p0;  vs[0][lane]  = p1; }
    else if (role == 2) { aas[0][lane] = p0; bbs[0][lane] = p1; }
    __syncthreads();

    for (int t = 0; t < T_LEN; ++t) {
        const int cur = t & 1, nxt = cur ^ 1;
        if (t + 1 < T_LEN) {
            const int base = (t + 1) * C_DIM + cb + lane;
            if (role == 0)      { p0 = rb[base];  p1 = ewb[base]; }
            else if (role == 1) { p0 = kb[base];  p1 = vb[base]; }
            else if (role == 2) { p0 = -kkb[base]; p1 = bbb[base]; }
        }
        float sa = 0.f;
#pragma unroll
        for (int i = 0; i < 16; ++i) sa = fmaf(S[i], aas[cur][jb + i], sa);
        sa += __shfl_xor(sa, 1);
        sa += __shfl_xor(sa, 2);
        const float vv = vs[cur][vrow];
#pragma unroll
        for (int i = 0; i < 16; ++i)
            S[i] = fmaf(vv, ks[cur][jb + i],
                        fmaf(sa, bbs[cur][jb + i], S[i] * ews[cur][jb + i]));
        float o = 0.f;
#pragma unroll
        for (int i = 0; i < 16; ++i) o = fmaf(S[i], rs[cur][jb + i], o);
        o += __shfl_xor(o, 1);
        o += __shfl_xor(o, 2);
        if (q == 0) y[(size_t)t * C_DIM + cb + vrow] = o;
        if (t + 1 < T_LEN) {
            if (role == 0)      { rs[nxt][lane] = p0;  ews[nxt][lane] = p1; }
            else if (role == 1) { ks[nxt][lane] = p0;  vs[nxt][lane]  = p1; }
            else if (role == 2) { aas[nxt][lane] = p0; bbs[nxt][lane] = p1; }
        }
        __syncthreads();
    }
}

// ---------------------------------------------------------------------------
// GroupNorm + bonus + *g
// ---------------------------------------------------------------------------
__global__ __launch_bounds__(256) void gn_bonus(
    float* __restrict__ y, const float* __restrict__ rb, const float* __restrict__ kb,
    const float* __restrict__ vb, const float* __restrict__ gb,
    const float* __restrict__ r_k, const float* __restrict__ lnw,
    const float* __restrict__ lnb)
{
    const int t = blockIdx.x, tid = threadIdx.x;
    const int c0 = tid << 2;
    const size_t base = (size_t)t * C_DIM + c0;
    float4 yv = *(float4*)(y + base);
    float sum = yv.x + yv.y + yv.z + yv.w;
    float ss  = yv.x * yv.x + yv.y * yv.y + yv.z * yv.z + yv.w * yv.w;
    float4 rv = *(const float4*)(rb + base);
    float4 kv = *(const float4*)(kb + base);
    float4 rkv = *(const float4*)(r_k + c0);
    float dot = rv.x * kv.x * rkv.x + rv.y * kv.y * rkv.y +
                rv.z * kv.z * rkv.z + rv.w * kv.w * rkv.w;
#pragma unroll
    for (int m = 1; m <= 8; m <<= 1) {
        sum += __shfl_xor(sum, m);
        ss  += __shfl_xor(ss, m);
        dot += __shfl_xor(dot, m);
    }
    const float mu = sum * 0.015625f;
    const float var = ss * 0.015625f - mu * mu;
    const float rstd = rsqrtf(var + 0.00064f);
    float4 wv = *(const float4*)(lnw + c0);
    float4 bv = *(const float4*)(lnb + c0);
    float4 vv = *(const float4*)(vb + base);
    float4 gv = *(const float4*)(gb + base);
    float4 o;
    o.x = ((yv.x - mu) * rstd * wv.x + bv.x + dot * vv.x) * gv.x;
    o.y = ((yv.y - mu) * rstd * wv.y + bv.y + dot * vv.y) * gv.y;
    o.z = ((yv.z - mu) * rstd * wv.z + bv.z + dot * vv.z) * gv.z;
    o.w = ((yv.w - mu) * rstd * wv.w + bv.w + dot * vv.w) * gv.w;
    *(float4*)(y + base) = o;
}

// ---------------------------------------------------------------------------
extern "C" void kernel_launch(void* const* d_in, const int* in_sizes, int n_in,
                              void* d_out, int out_size, void* d_ws, size_t ws_size,
                              hipStream_t stream)
{
    (void)in_sizes; (void)n_in; (void)out_size;
    const float* x       = (const float*)d_in[0];
    const float* v_first = (const float*)d_in[1];
    const float* x_prev  = (const float*)d_in[2];
    const float* init_st = (const float*)d_in[3];
    const float* x_r = (const float*)d_in[4];
    const float* x_w = (const float*)d_in[5];
    const float* x_k = (const float*)d_in[6];
    const float* x_v = (const float*)d_in[7];
    const float* x_a = (const float*)d_in[8];
    const float* x_g = (const float*)d_in[9];
    const float* w0  = (const float*)d_in[10];
    const float* a0  = (const float*)d_in[11];
    const float* v0  = (const float*)d_in[12];
    const float* k_k = (const float*)d_in[13];
    const float* k_a = (const float*)d_in[14];
    const float* w1  = (const float*)d_in[15];
    const float* w2  = (const float*)d_in[16];
    const float* a1  = (const float*)d_in[17];
    const float* a2  = (const float*)d_in[18];
    const float* v1  = (const float*)d_in[19];
    const float* v2  = (const float*)d_in[20];
    const float* g1  = (const float*)d_in[21];
    const float* g2  = (const float*)d_in[22];
    const float* r_k = (const float*)d_in[23];
    const float* Wr  = (const float*)d_in[24];
    const float* Wk  = (const float*)d_in[25];
    const float* Wv  = (const float*)d_in[26];
    const float* Wo  = (const float*)d_in[27];
    const float* ln_w = (const float*)d_in[28];
    const float* ln_b = (const float*)d_in[29];

    float* out = (float*)d_out;
    float* ws  = (float*)d_ws;
    const size_t NE = (size_t)T_LEN * C_DIM;
    float* rB  = ws;
    float* ewB = ws + NE;
    float* kB  = ws + 2 * NE;
    float* vB  = ws + 3 * NE;
    float* aB  = ws + 4 * NE;   // a, then bb
    float* gB  = ws + 5 * NE;
    float* kkB = ws + 6 * NE;
    float* yB  = ws + 7 * NE;
    float* hB  = ws + 8 * NE;
    float* tiles = ws + 9 * NE;
    const size_t need_bytes = (9 * NE + (size_t)2048 * TSTRIDE) * sizeof(float);
    const bool chunked = ws_size >= need_bytes;

    dim3 gg(16, 32);
    gemm_nt<<<gg, 256, 0, stream>>>(x, x_prev, x_r, Wr, rB);
    gemm_nt<<<gg, 256, 0, stream>>>(x, x_prev, x_k, Wk, kB);
    gemm_nt<<<gg, 256, 0, stream>>>(x, x_prev, x_v, Wv, vB);

    lora1<<<512, 256, 0, stream>>>(x, x_prev, x_w, w1, hB, 64, 1);
    lora2<<<dim3(4, T_LEN), 256, 0, stream>>>(hB, w2, w0, ewB, nullptr, 64, 0);
    lora1<<<512, 256, 0, stream>>>(x, x_prev, x_a, a1, hB, 64, 0);
    lora2<<<dim3(4, T_LEN), 256, 0, stream>>>(hB, a2, a0, aB, nullptr, 64, 1);
    lora1<<<256, 256, 0, stream>>>(x, x_prev, x_v, v1, hB, 32, 0);
    lora2<<<dim3(4, T_LEN), 256, 0, stream>>>(hB, v2, v0, vB, v_first, 32, 2);
    lora1<<<1024, 256, 0, stream>>>(x, x_prev, x_g, g1, hB, 128, 2);
    lora2<<<dim3(4, T_LEN), 256, 0, stream>>>(hB, g2, nullptr, gB, nullptr, 128, 3);

    kpost<<<T_LEN, 256, 0, stream>>>(kB, aB, kkB, k_k, k_a);
    if (chunked) {
        chunk_prep<<<dim3(128, 16), 256, 0, stream>>>(rB, ewB, kB, vB, kkB, aB,
                                                      tiles, yB);
        chunk_scan2<<<16, 256, 0, stream>>>(tiles, init_st, yB);
    } else {
        scan_kernel<<<16, 256, 0, stream>>>(rB, ewB, kB, vB, kkB, aB, init_st, yB);
    }
    gn_bonus<<<T_LEN, 256, 0, stream>>>(yB, rB, kB, vB, gB, r_k, ln_w, ln_b);
    gemm_nt<<<gg, 256, 0, stream>>>(yB, yB, nullptr, Wo, out);
}

// Round 4
// 1151.198 us; speedup vs baseline: 2.2551x; 1.2959x over previous
//
#include <hip/hip_runtime.h>

#define T_LEN 2048
#define C_DIM 1024

static __device__ __forceinline__ float sigf(float x) {
    return 1.f / (1.f + __expf(-x));
}

// ---------------------------------------------------------------------------
// NT GEMM: out[t,i] = sum_c A(t,c) * W[i,c];  A = mixv ? x + (shift-x)*mix : X
// ---------------------------------------------------------------------------
__global__ __launch_bounds__(256) void gemm_nt(
    const float* __restrict__ X, const float* __restrict__ xprev,
    const float* __restrict__ mixv, const float* __restrict__ W,
    float* __restrict__ out)
{
    __shared__ __align__(16) float As[16][68];
    __shared__ __align__(16) float Ws[16][68];
    const int tid = threadIdx.x;
    const int t0 = blockIdx.y * 64;
    const int n0 = blockIdx.x * 64;
    const int lr = tid >> 2;
    const int lk = (tid & 3) << 2;
    const int ty = tid >> 4;
    const int tx = tid & 15;
    float acc[4][4] = {{0.f}};

    const int trow = t0 + lr;
    const float* xrow  = X + (size_t)trow * C_DIM;
    const float* xprow = (trow == 0) ? xprev : (X + (size_t)(trow - 1) * C_DIM);
    const float* wrow  = W + (size_t)(n0 + lr) * C_DIM;

    for (int k0 = 0; k0 < C_DIM; k0 += 16) {
        float4 xv = *(const float4*)(xrow + k0 + lk);
        if (mixv) {
            float4 pv = *(const float4*)(xprow + k0 + lk);
            float4 mv = *(const float4*)(mixv + k0 + lk);
            xv.x += (pv.x - xv.x) * mv.x;
            xv.y += (pv.y - xv.y) * mv.y;
            xv.z += (pv.z - xv.z) * mv.z;
            xv.w += (pv.w - xv.w) * mv.w;
        }
        As[lk + 0][lr] = xv.x; As[lk + 1][lr] = xv.y;
        As[lk + 2][lr] = xv.z; As[lk + 3][lr] = xv.w;
        float4 wv = *(const float4*)(wrow + k0 + lk);
        Ws[lk + 0][lr] = wv.x; Ws[lk + 1][lr] = wv.y;
        Ws[lk + 2][lr] = wv.z; Ws[lk + 3][lr] = wv.w;
        __syncthreads();
#pragma unroll
        for (int kk = 0; kk < 16; ++kk) {
            float4 av = *(const float4*)&As[kk][ty << 2];
            float4 bv = *(const float4*)&Ws[kk][tx << 2];
            float a_[4] = {av.x, av.y, av.z, av.w};
            float b_[4] = {bv.x, bv.y, bv.z, bv.w};
#pragma unroll
            for (int i = 0; i < 4; ++i)
#pragma unroll
                for (int j = 0; j < 4; ++j)
                    acc[i][j] = fmaf(a_[i], b_[j], acc[i][j]);
        }
        __syncthreads();
    }
#pragma unroll
    for (int i = 0; i < 4; ++i) {
        float4 o4 = {acc[i][0], acc[i][1], acc[i][2], acc[i][3]};
        *(float4*)(out + (size_t)(t0 + (ty << 2) + i) * C_DIM + n0 + (tx << 2)) = o4;
    }
}

// ---------------------------------------------------------------------------
// LoRA stage 1
// ---------------------------------------------------------------------------
__global__ __launch_bounds__(256) void lora1(
    const float* __restrict__ X, const float* __restrict__ xprev,
    const float* __restrict__ mixv, const float* __restrict__ W1,
    float* __restrict__ hbuf, int Kh, int act)
{
    __shared__ __align__(16) float As[8192];
    const int tid = threadIdx.x;
    const int tpb = 256 / Kh;
    const int t0 = blockIdx.x * tpb;
    for (int idx = tid; idx < (tpb << 10); idx += 256) {
        int l = idx >> 10, cc = idx & 1023;
        int t = t0 + l;
        float xv = X[(size_t)t * C_DIM + cc];
        float pv = (t == 0) ? xprev[cc] : X[(size_t)(t - 1) * C_DIM + cc];
        As[idx] = xv + (pv - xv) * mixv[cc];
    }
    __syncthreads();
    const int l = tid / Kh;
    const int j = tid % Kh;
    const float* arow = As + (l << 10);
    float acc = 0.f;
#pragma unroll 4
    for (int cc = 0; cc < 1024; ++cc)
        acc = fmaf(arow[cc], W1[(size_t)cc * Kh + j], acc);
    if (act == 1) acc = tanhf(acc);
    else if (act == 2) acc = sigf(acc);
    hbuf[(size_t)(t0 + l) * Kh + j] = acc;
}

// ---------------------------------------------------------------------------
// LoRA stage 2
// ---------------------------------------------------------------------------
__global__ __launch_bounds__(256) void lora2(
    const float* __restrict__ hbuf, const float* __restrict__ W2,
    const float* __restrict__ bias, float* __restrict__ outp,
    const float* __restrict__ vfirst, int Kh, int mode)
{
    __shared__ __align__(16) float hs[128];
    const int t = blockIdx.y;
    const int i = blockIdx.x * 256 + threadIdx.x;
    if (threadIdx.x < Kh) hs[threadIdx.x] = hbuf[(size_t)t * Kh + threadIdx.x];
    __syncthreads();
    float acc = bias ? bias[i] : 0.f;
#pragma unroll 8
    for (int j = 0; j < Kh; ++j)
        acc = fmaf(hs[j], W2[(size_t)j * C_DIM + i], acc);
    const size_t idx = (size_t)t * C_DIM + i;
    if (mode == 0) {
        outp[idx] = __expf(-0.6065306597126334f * sigf(acc));
    } else if (mode == 1) {
        outp[idx] = sigf(acc);
    } else if (mode == 2) {
        float s = sigf(acc);
        float vr = outp[idx];
        outp[idx] = vr + (vfirst[idx] - vr) * s;
    } else {
        outp[idx] = acc;
    }
}

// ---------------------------------------------------------------------------
// k post-process: kk = normalize(k*k_k); aa = -kk (stored); bb = kk*a;
// k = k*(1+(a-1)*k_a)
// ---------------------------------------------------------------------------
__global__ __launch_bounds__(256) void kpost(
    float* __restrict__ kbuf, float* __restrict__ abuf, float* __restrict__ aabuf,
    const float* __restrict__ k_k, const float* __restrict__ k_a)
{
    const int t = blockIdx.x, tid = threadIdx.x;
    const int c0 = tid << 2;
    const size_t base = (size_t)t * C_DIM + c0;
    float4 kr  = *(float4*)(kbuf + base);
    float4 kkw = *(const float4*)(k_k + c0);
    float4 kav = *(const float4*)(k_a + c0);
    float4 av  = *(float4*)(abuf + base);
    float4 kn = {kr.x * kkw.x, kr.y * kkw.y, kr.z * kkw.z, kr.w * kkw.w};
    float ss = kn.x * kn.x + kn.y * kn.y + kn.z * kn.z + kn.w * kn.w;
#pragma unroll
    for (int m = 1; m <= 8; m <<= 1) ss += __shfl_xor(ss, m);
    const float scale = 1.f / fmaxf(sqrtf(ss), 1e-12f);
    float4 kkv = {kn.x * scale, kn.y * scale, kn.z * scale, kn.w * scale};
    float4 bb = {kkv.x * av.x, kkv.y * av.y, kkv.z * av.z, kkv.w * av.w};
    float4 aa = {-kkv.x, -kkv.y, -kkv.z, -kkv.w};
    *(float4*)(aabuf + base) = aa;
    *(float4*)(abuf + base) = bb;
    float4 kf = {kr.x * (1.f + (av.x - 1.f) * kav.x),
                 kr.y * (1.f + (av.y - 1.f) * kav.y),
                 kr.z * (1.f + (av.z - 1.f) * kav.z),
                 kr.w * (1.f + (av.w - 1.f) * kav.w)};
    *(float4*)(kbuf + base) = kf;
}

// ---------------------------------------------------------------------------
// v-row-parallel scan. 256 blocks x 64 threads: block = (head, group of 4
// v-rows); lane l owns v-row (l>>4) of the group, j-slice 4*(l&15)..+4.
// Per step: sa = sum_j S*aa (4-FMA partial + 4-level DPP row_ror reduce over
// the 16-lane row), S = S*ew + sa*bb + v*k, o = sum_j S*r (same reduce).
// No LDS, no barriers; inputs register-prefetched 2 steps ahead (unroll-4).
// ---------------------------------------------------------------------------
struct StepIn { float4 r, e, k, a, b; float v; };

static __device__ __forceinline__ float red16(float x) {
    // rotate-reduce within each 16-lane row: every lane gets the row sum
    int xi;
    xi = __builtin_amdgcn_mov_dpp(__float_as_int(x), 0x128, 0xf, 0xf, true);
    x += __int_as_float(xi);   // + ror8
    xi = __builtin_amdgcn_mov_dpp(__float_as_int(x), 0x124, 0xf, 0xf, true);
    x += __int_as_float(xi);   // + ror4
    xi = __builtin_amdgcn_mov_dpp(__float_as_int(x), 0x122, 0xf, 0xf, true);
    x += __int_as_float(xi);   // + ror2
    xi = __builtin_amdgcn_mov_dpp(__float_as_int(x), 0x121, 0xf, 0xf, true);
    x += __int_as_float(xi);   // + ror1
    return x;
}

static __device__ __forceinline__ StepIn load_step(
    const float* __restrict__ rb, const float* __restrict__ ewb,
    const float* __restrict__ kb, const float* __restrict__ vb,
    const float* __restrict__ aab, const float* __restrict__ bbb,
    int t, int cb, int j0, int vidx)
{
    StepIn s;
    const size_t base = (size_t)t * C_DIM + cb;
    s.r = *(const float4*)(rb + base + j0);
    s.e = *(const float4*)(ewb + base + j0);
    s.k = *(const float4*)(kb + base + j0);
    s.a = *(const float4*)(aab + base + j0);
    s.b = *(const float4*)(bbb + base + j0);
    s.v = vb[base + vidx];
    return s;
}

static __device__ __forceinline__ void step_compute(
    float4& S, const StepIn& st, float* __restrict__ y,
    int t, int cb, int vidx, int lane)
{
    float sa = S.x * st.a.x;
    sa = fmaf(S.y, st.a.y, sa);
    sa = fmaf(S.z, st.a.z, sa);
    sa = fmaf(S.w, st.a.w, sa);
    sa = red16(sa);
    S.x = fmaf(st.v, st.k.x, fmaf(sa, st.b.x, S.x * st.e.x));
    S.y = fmaf(st.v, st.k.y, fmaf(sa, st.b.y, S.y * st.e.y));
    S.z = fmaf(st.v, st.k.z, fmaf(sa, st.b.z, S.z * st.e.z));
    S.w = fmaf(st.v, st.k.w, fmaf(sa, st.b.w, S.w * st.e.w));
    float o = S.x * st.r.x;
    o = fmaf(S.y, st.r.y, o);
    o = fmaf(S.z, st.r.z, o);
    o = fmaf(S.w, st.r.w, o);
    o = red16(o);
    if ((lane & 15) == 0)
        y[(size_t)t * C_DIM + cb + vidx] = o;
}

__global__ __launch_bounds__(64) void vscan(
    const float* __restrict__ rb, const float* __restrict__ ewb,
    const float* __restrict__ kb, const float* __restrict__ vb,
    const float* __restrict__ aab, const float* __restrict__ bbb,
    const float* __restrict__ init_state, float* __restrict__ y)
{
    const int h  = blockIdx.x >> 4;
    const int wv = blockIdx.x & 15;
    const int l  = threadIdx.x;
    const int vidx = wv * 4 + (l >> 4);   // v-row within head
    const int j0 = (l & 15) * 4;
    const int cb = h * 64;

    float4 S = *(const float4*)(init_state + h * 4096 + vidx * 64 + j0);

    StepIn X0 = load_step(rb, ewb, kb, vb, aab, bbb, 0, cb, j0, vidx);
    StepIn X1 = load_step(rb, ewb, kb, vb, aab, bbb, 1, cb, j0, vidx);
    for (int t = 0; t < T_LEN; t += 4) {
        StepIn X2 = load_step(rb, ewb, kb, vb, aab, bbb,
                              (t + 2) & (T_LEN - 1), cb, j0, vidx);
        step_compute(S, X0, y, t, cb, vidx, l);
        StepIn X3 = load_step(rb, ewb, kb, vb, aab, bbb,
                              (t + 3) & (T_LEN - 1), cb, j0, vidx);
        step_compute(S, X1, y, t + 1, cb, vidx, l);
        X0 = load_step(rb, ewb, kb, vb, aab, bbb,
                       (t + 4) & (T_LEN - 1), cb, j0, vidx);
        step_compute(S, X2, y, t + 2, cb, vidx, l);
        X1 = load_step(rb, ewb, kb, vb, aab, bbb,
                       (t + 5) & (T_LEN - 1), cb, j0, vidx);
        step_compute(S, X3, y, t + 3, cb, vidx, l);
    }
}

// ---------------------------------------------------------------------------
// GroupNorm + bonus + *g
// ---------------------------------------------------------------------------
__global__ __launch_bounds__(256) void gn_bonus(
    float* __restrict__ y, const float* __restrict__ rb, const float* __restrict__ kb,
    const float* __restrict__ vb, const float* __restrict__ gb,
    const float* __restrict__ r_k, const float* __restrict__ lnw,
    const float* __restrict__ lnb)
{
    const int t = blockIdx.x, tid = threadIdx.x;
    const int c0 = tid << 2;
    const size_t base = (size_t)t * C_DIM + c0;
    float4 yv = *(float4*)(y + base);
    float sum = yv.x + yv.y + yv.z + yv.w;
    float ss  = yv.x * yv.x + yv.y * yv.y + yv.z * yv.z + yv.w * yv.w;
    float4 rv = *(const float4*)(rb + base);
    float4 kv = *(const float4*)(kb + base);
    float4 rkv = *(const float4*)(r_k + c0);
    float dot = rv.x * kv.x * rkv.x + rv.y * kv.y * rkv.y +
                rv.z * kv.z * rkv.z + rv.w * kv.w * rkv.w;
#pragma unroll
    for (int m = 1; m <= 8; m <<= 1) {
        sum += __shfl_xor(sum, m);
        ss  += __shfl_xor(ss, m);
        dot += __shfl_xor(dot, m);
    }
    const float mu = sum * 0.015625f;
    const float var = ss * 0.015625f - mu * mu;
    const float rstd = rsqrtf(var + 0.00064f);
    float4 wv = *(const float4*)(lnw + c0);
    float4 bv = *(const float4*)(lnb + c0);
    float4 vv = *(const float4*)(vb + base);
    float4 gv = *(const float4*)(gb + base);
    float4 o;
    o.x = ((yv.x - mu) * rstd * wv.x + bv.x + dot * vv.x) * gv.x;
    o.y = ((yv.y - mu) * rstd * wv.y + bv.y + dot * vv.y) * gv.y;
    o.z = ((yv.z - mu) * rstd * wv.z + bv.z + dot * vv.z) * gv.z;
    o.w = ((yv.w - mu) * rstd * wv.w + bv.w + dot * vv.w) * gv.w;
    *(float4*)(y + base) = o;
}

// ---------------------------------------------------------------------------
extern "C" void kernel_launch(void* const* d_in, const int* in_sizes, int n_in,
                              void* d_out, int out_size, void* d_ws, size_t ws_size,
                              hipStream_t stream)
{
    (void)in_sizes; (void)n_in; (void)out_size; (void)ws_size;
    const float* x       = (const float*)d_in[0];
    const float* v_first = (const float*)d_in[1];
    const float* x_prev  = (const float*)d_in[2];
    const float* init_st = (const float*)d_in[3];
    const float* x_r = (const float*)d_in[4];
    const float* x_w = (const float*)d_in[5];
    const float* x_k = (const float*)d_in[6];
    const float* x_v = (const float*)d_in[7];
    const float* x_a = (const float*)d_in[8];
    const float* x_g = (const float*)d_in[9];
    const float* w0  = (const float*)d_in[10];
    const float* a0  = (const float*)d_in[11];
    const float* v0  = (const float*)d_in[12];
    const float* k_k = (const float*)d_in[13];
    const float* k_a = (const float*)d_in[14];
    const float* w1  = (const float*)d_in[15];
    const float* w2  = (const float*)d_in[16];
    const float* a1  = (const float*)d_in[17];
    const float* a2  = (const float*)d_in[18];
    const float* v1  = (const float*)d_in[19];
    const float* v2  = (const float*)d_in[20];
    const float* g1  = (const float*)d_in[21];
    const float* g2  = (const float*)d_in[22];
    const float* r_k = (const float*)d_in[23];
    const float* Wr  = (const float*)d_in[24];
    const float* Wk  = (const float*)d_in[25];
    const float* Wv  = (const float*)d_in[26];
    const float* Wo  = (const float*)d_in[27];
    const float* ln_w = (const float*)d_in[28];
    const float* ln_b = (const float*)d_in[29];

    float* out = (float*)d_out;
    float* ws  = (float*)d_ws;
    const size_t NE = (size_t)T_LEN * C_DIM;
    float* rB  = ws;
    float* ewB = ws + NE;
    float* kB  = ws + 2 * NE;
    float* vB  = ws + 3 * NE;
    float* aB  = ws + 4 * NE;   // a, then bb
    float* gB  = ws + 5 * NE;
    float* aaB = ws + 6 * NE;   // aa = -kk
    float* yB  = ws + 7 * NE;
    float* hB  = ws + 8 * NE;

    dim3 gg(16, 32);
    gemm_nt<<<gg, 256, 0, stream>>>(x, x_prev, x_r, Wr, rB);
    gemm_nt<<<gg, 256, 0, stream>>>(x, x_prev, x_k, Wk, kB);
    gemm_nt<<<gg, 256, 0, stream>>>(x, x_prev, x_v, Wv, vB);

    lora1<<<512, 256, 0, stream>>>(x, x_prev, x_w, w1, hB, 64, 1);
    lora2<<<dim3(4, T_LEN), 256, 0, stream>>>(hB, w2, w0, ewB, nullptr, 64, 0);
    lora1<<<512, 256, 0, stream>>>(x, x_prev, x_a, a1, hB, 64, 0);
    lora2<<<dim3(4, T_LEN), 256, 0, stream>>>(hB, a2, a0, aB, nullptr, 64, 1);
    lora1<<<256, 256, 0, stream>>>(x, x_prev, x_v, v1, hB, 32, 0);
    lora2<<<dim3(4, T_LEN), 256, 0, stream>>>(hB, v2, v0, vB, v_first, 32, 2);
    lora1<<<1024, 256, 0, stream>>>(x, x_prev, x_g, g1, hB, 128, 2);
    lora2<<<dim3(4, T_LEN), 256, 0, stream>>>(hB, g2, nullptr, gB, nullptr, 128, 3);

    kpost<<<T_LEN, 256, 0, stream>>>(kB, aB, aaB, k_k, k_a);
    vscan<<<256, 64, 0, stream>>>(rB, ewB, kB, vB, aaB, aB, init_st, yB);
    gn_bonus<<<T_LEN, 256, 0, stream>>>(yB, rB, kB, vB, gB, r_k, ln_w, ln_b);
    gemm_nt<<<gg, 256, 0, stream>>>(yB, yB, nullptr, Wo, out);
}

// Round 6
// 1056.297 us; speedup vs baseline: 2.4578x; 1.0898x over previous
//
#include <hip/hip_runtime.h>

#define T_LEN 2048
#define C_DIM 1024

typedef __attribute__((ext_vector_type(8))) short bf8_t;
typedef __attribute__((ext_vector_type(4))) float f4_t;

static __device__ __forceinline__ float sigf(float x) {
    return 1.f / (1.f + __expf(-x));
}
static __device__ __forceinline__ unsigned short f2bf(float f) {
    unsigned u = __float_as_uint(f);
    u += 0x7fff + ((u >> 16) & 1);
    return (unsigned short)(u >> 16);
}

// ---------------------------------------------------------------------------
// Convert the four 1024x1024 fp32 weights into one contiguous bf16 block
// (strides of C_DIM*C_DIM = 1M elements: Wr | Wk | Wv | Wo).
// ---------------------------------------------------------------------------
__global__ __launch_bounds__(256) void wcvt4(
    const float* __restrict__ Wr, const float* __restrict__ Wk,
    const float* __restrict__ Wv, const float* __restrict__ Wo,
    unsigned short* __restrict__ dst)
{
    const size_t idx = ((size_t)blockIdx.x * 256 + threadIdx.x) * 4;
    const int sel = (int)(idx >> 20);
    const float* src = sel == 0 ? Wr : sel == 1 ? Wk : sel == 2 ? Wv : Wo;
    float4 v = *(const float4*)(src + (idx & 0xFFFFF));
    ushort4 o = {f2bf(v.x), f2bf(v.y), f2bf(v.z), f2bf(v.w)};
    *(ushort4*)(dst + idx) = o;
}

// ---------------------------------------------------------------------------
// Token-shift mix -> bf16 A-matrices for the r/k/v projections.
// ---------------------------------------------------------------------------
__global__ __launch_bounds__(256) void xcvt(
    const float* __restrict__ x, const float* __restrict__ xprev,
    const float* __restrict__ x_r, const float* __restrict__ x_k,
    const float* __restrict__ x_v,
    unsigned short* __restrict__ xr16, unsigned short* __restrict__ xk16,
    unsigned short* __restrict__ xv16)
{
    const int t = blockIdx.x;
    const int c0 = threadIdx.x * 4;
    const size_t base = (size_t)t * C_DIM + c0;
    float4 xv = *(const float4*)(x + base);
    float4 pv = (t == 0) ? *(const float4*)(xprev + c0)
                         : *(const float4*)(x + base - C_DIM);
    float4 dx = {pv.x - xv.x, pv.y - xv.y, pv.z - xv.z, pv.w - xv.w};
    float4 mr = *(const float4*)(x_r + c0);
    float4 mk = *(const float4*)(x_k + c0);
    float4 mv = *(const float4*)(x_v + c0);
    ushort4 orr = {f2bf(xv.x + dx.x * mr.x), f2bf(xv.y + dx.y * mr.y),
                   f2bf(xv.z + dx.z * mr.z), f2bf(xv.w + dx.w * mr.w)};
    ushort4 ok = {f2bf(xv.x + dx.x * mk.x), f2bf(xv.y + dx.y * mk.y),
                  f2bf(xv.z + dx.z * mk.z), f2bf(xv.w + dx.w * mk.w)};
    ushort4 ov = {f2bf(xv.x + dx.x * mv.x), f2bf(xv.y + dx.y * mv.y),
                  f2bf(xv.z + dx.z * mv.z), f2bf(xv.w + dx.w * mv.w)};
    *(ushort4*)(xr16 + base) = orr;
    *(ushort4*)(xk16 + base) = ok;
    *(ushort4*)(xv16 + base) = ov;
}

// ---------------------------------------------------------------------------
// bf16 MFMA NT GEMM: out[t,i] = sum_c A[t,c]*W[i,c], fp32 accumulate.
// 128x64 tile, BK=32, 256 threads (4 waves, each 64x32), double-buffered LDS
// staged with global_load_lds width=16.
// ---------------------------------------------------------------------------
__global__ __launch_bounds__(256) void gemm_bf16(
    const unsigned short* __restrict__ A, const unsigned short* __restrict__ W,
    float* __restrict__ out)
{
    __shared__ unsigned short Ab[2][128 * 32];
    __shared__ unsigned short Bb[2][64 * 32];
    const int tid = threadIdx.x;
    const int lane = tid & 63;
    const int w = tid >> 6;
    const int n0 = blockIdx.x * 64;
    const int t0 = blockIdx.y * 128;
    const int wm = (w & 1) * 64;
    const int wn = (w >> 1) * 32;
    const int srow = lane >> 2;
    const int scol = (lane & 3) * 8;

    f4_t acc[4][2];
#pragma unroll
    for (int i = 0; i < 4; ++i)
#pragma unroll
        for (int j = 0; j < 2; ++j)
            acc[i][j] = (f4_t){0.f, 0.f, 0.f, 0.f};

    // stage k0 = 0 into buffer 0
#pragma unroll
    for (int s = 0; s < 2; ++s) {
        const int i = 2 * w + s;
        __builtin_amdgcn_global_load_lds(
            (const __attribute__((address_space(1))) unsigned int*)
                (A + (size_t)(t0 + i * 16 + srow) * 1024 + scol),
            (__attribute__((address_space(3))) unsigned int*)
                (&Ab[0][i * 512 + lane * 8]), 16, 0, 0);
    }
    __builtin_amdgcn_global_load_lds(
        (const __attribute__((address_space(1))) unsigned int*)
            (W + (size_t)(n0 + w * 16 + srow) * 1024 + scol),
        (__attribute__((address_space(3))) unsigned int*)
            (&Bb[0][w * 512 + lane * 8]), 16, 0, 0);

    const int mrow = lane & 15;
    const int kq = (lane >> 4) * 8;
    for (int k0 = 0; k0 < 1024; k0 += 32) {
        const int cur = (k0 >> 5) & 1, nxt = cur ^ 1;
        __syncthreads();                       // drains stage into cur
        if (k0 + 32 < 1024) {                  // prefetch next K-slab
            const int k1 = k0 + 32;
#pragma unroll
            for (int s = 0; s < 2; ++s) {
                const int i = 2 * w + s;
                __builtin_amdgcn_global_load_lds(
                    (const __attribute__((address_space(1))) unsigned int*)
                        (A + (size_t)(t0 + i * 16 + srow) * 1024 + k1 + scol),
                    (__attribute__((address_space(3))) unsigned int*)
                        (&Ab[nxt][i * 512 + lane * 8]), 16, 0, 0);
            }
            __builtin_amdgcn_global_load_lds(
                (const __attribute__((address_space(1))) unsigned int*)
                    (W + (size_t)(n0 + w * 16 + srow) * 1024 + k1 + scol),
                (__attribute__((address_space(3))) unsigned int*)
                    (&Bb[nxt][w * 512 + lane * 8]), 16, 0, 0);
        }
        bf8_t af[4], bfr[2];
#pragma unroll
        for (int i = 0; i < 4; ++i)
            af[i] = *(const bf8_t*)(&Ab[cur][(wm + 16 * i + mrow) * 32 + kq]);
#pragma unroll
        for (int j = 0; j < 2; ++j)
            bfr[j] = *(const bf8_t*)(&Bb[cur][(wn + 16 * j + mrow) * 32 + kq]);
#pragma unroll
        for (int i = 0; i < 4; ++i)
#pragma unroll
            for (int j = 0; j < 2; ++j)
                acc[i][j] = __builtin_amdgcn_mfma_f32_16x16x32_bf16(
                    af[i], bfr[j], acc[i][j], 0, 0, 0);
    }
    const int crow = (lane >> 4) * 4;
    const int ccol = lane & 15;
#pragma unroll
    for (int i = 0; i < 4; ++i)
#pragma unroll
        for (int j = 0; j < 2; ++j)
#pragma unroll
            for (int u = 0; u < 4; ++u)
                out[(size_t)(t0 + wm + 16 * i + crow + u) * 1024
                    + n0 + wn + 16 * j + ccol] = acc[i][j][u];
}

// ---------------------------------------------------------------------------
// LoRA stage 1 (fp32)
// ---------------------------------------------------------------------------
__global__ __launch_bounds__(256) void lora1(
    const float* __restrict__ X, const float* __restrict__ xprev,
    const float* __restrict__ mixv, const float* __restrict__ W1,
    float* __restrict__ hbuf, int Kh, int act)
{
    __shared__ __align__(16) float As[8192];
    const int tid = threadIdx.x;
    const int tpb = 256 / Kh;
    const int t0 = blockIdx.x * tpb;
    for (int idx = tid; idx < (tpb << 10); idx += 256) {
        int l = idx >> 10, cc = idx & 1023;
        int t = t0 + l;
        float xv = X[(size_t)t * C_DIM + cc];
        float pv = (t == 0) ? xprev[cc] : X[(size_t)(t - 1) * C_DIM + cc];
        As[idx] = xv + (pv - xv) * mixv[cc];
    }
    __syncthreads();
    const int l = tid / Kh;
    const int j = tid % Kh;
    const float* arow = As + (l << 10);
    float acc = 0.f;
#pragma unroll 4
    for (int cc = 0; cc < 1024; ++cc)
        acc = fmaf(arow[cc], W1[(size_t)cc * Kh + j], acc);
    if (act == 1) acc = tanhf(acc);
    else if (act == 2) acc = sigf(acc);
    hbuf[(size_t)(t0 + l) * Kh + j] = acc;
}

// ---------------------------------------------------------------------------
// LoRA stage 2: 16 tokens per block (W2 reused 16x), j-chunks of 4.
// ---------------------------------------------------------------------------
__global__ __launch_bounds__(256) void lora2(
    const float* __restrict__ hbuf, const float* __restrict__ W2,
    const float* __restrict__ bias, float* __restrict__ outp,
    const float* __restrict__ vfirst, int Kh, int mode)
{
    __shared__ __align__(16) float hs[16 * 128];
    const int tid = threadIdx.x;
    const int t0 = blockIdx.y * 16;
    const int i = blockIdx.x * 256 + tid;
    for (int idx = tid; idx < 16 * Kh; idx += 256)
        hs[idx] = hbuf[(size_t)t0 * Kh + idx];
    __syncthreads();
    const float b0 = bias ? bias[i] : 0.f;
    float acc[16];
#pragma unroll
    for (int tt = 0; tt < 16; ++tt) acc[tt] = b0;
    for (int j = 0; j < Kh; j += 4) {
        const float w0_ = W2[(size_t)(j + 0) * C_DIM + i];
        const float w1_ = W2[(size_t)(j + 1) * C_DIM + i];
        const float w2_ = W2[(size_t)(j + 2) * C_DIM + i];
        const float w3_ = W2[(size_t)(j + 3) * C_DIM + i];
#pragma unroll
        for (int tt = 0; tt < 16; ++tt) {
            float4 h4 = *(const float4*)(hs + tt * Kh + j);
            acc[tt] = fmaf(h4.x, w0_, acc[tt]);
            acc[tt] = fmaf(h4.y, w1_, acc[tt]);
            acc[tt] = fmaf(h4.z, w2_, acc[tt]);
            acc[tt] = fmaf(h4.w, w3_, acc[tt]);
        }
    }
#pragma unroll
    for (int tt = 0; tt < 16; ++tt) {
        const size_t idx = (size_t)(t0 + tt) * C_DIM + i;
        if (mode == 0) {
            outp[idx] = __expf(-0.6065306597126334f * sigf(acc[tt]));
        } else if (mode == 1) {
            outp[idx] = sigf(acc[tt]);
        } else if (mode == 2) {
            float s = sigf(acc[tt]);
            float vr = outp[idx];
            outp[idx] = vr + (vfirst[idx] - vr) * s;
        } else {
            outp[idx] = acc[tt];
        }
    }
}

// ---------------------------------------------------------------------------
// k post-process: kk = normalize(k*k_k); aa = -kk; bb = kk*a; k = k*(1+(a-1)*k_a)
// ---------------------------------------------------------------------------
__global__ __launch_bounds__(256) void kpost(
    float* __restrict__ kbuf, float* __restrict__ abuf, float* __restrict__ aabuf,
    const float* __restrict__ k_k, const float* __restrict__ k_a)
{
    const int t = blockIdx.x, tid = threadIdx.x;
    const int c0 = tid << 2;
    const size_t base = (size_t)t * C_DIM + c0;
    float4 kr  = *(float4*)(kbuf + base);
    float4 kkw = *(const float4*)(k_k + c0);
    float4 kav = *(const float4*)(k_a + c0);
    float4 av  = *(float4*)(abuf + base);
    float4 kn = {kr.x * kkw.x, kr.y * kkw.y, kr.z * kkw.z, kr.w * kkw.w};
    float ss = kn.x * kn.x + kn.y * kn.y + kn.z * kn.z + kn.w * kn.w;
#pragma unroll
    for (int m = 1; m <= 8; m <<= 1) ss += __shfl_xor(ss, m);
    const float scale = 1.f / fmaxf(sqrtf(ss), 1e-12f);
    float4 kkv = {kn.x * scale, kn.y * scale, kn.z * scale, kn.w * scale};
    float4 bb = {kkv.x * av.x, kkv.y * av.y, kkv.z * av.z, kkv.w * av.w};
    float4 aa = {-kkv.x, -kkv.y, -kkv.z, -kkv.w};
    *(float4*)(aabuf + base) = aa;
    *(float4*)(abuf + base) = bb;
    float4 kf = {kr.x * (1.f + (av.x - 1.f) * kav.x),
                 kr.y * (1.f + (av.y - 1.f) * kav.y),
                 kr.z * (1.f + (av.z - 1.f) * kav.z),
                 kr.w * (1.f + (av.w - 1.f) * kav.w)};
    *(float4*)(kbuf + base) = kf;
}

// ---------------------------------------------------------------------------
// v-row-parallel scan. 256 blocks x 64 threads. Block b -> head (b&15), so all
// 16 blocks of a head share b%8 (same XCD -> L2-local input streams).
// Register prefetch distance 4.
// ---------------------------------------------------------------------------
struct StepIn { float4 r, e, k, a, b; float v; };

static __device__ __forceinline__ float red16(float x) {
    int xi;
    xi = __builtin_amdgcn_mov_dpp(__float_as_int(x), 0x128, 0xf, 0xf, true);
    x += __int_as_float(xi);
    xi = __builtin_amdgcn_mov_dpp(__float_as_int(x), 0x124, 0xf, 0xf, true);
    x += __int_as_float(xi);
    xi = __builtin_amdgcn_mov_dpp(__float_as_int(x), 0x122, 0xf, 0xf, true);
    x += __int_as_float(xi);
    xi = __builtin_amdgcn_mov_dpp(__float_as_int(x), 0x121, 0xf, 0xf, true);
    x += __int_as_float(xi);
    return x;
}

static __device__ __forceinline__ StepIn load_step(
    const float* __restrict__ rb, const float* __restrict__ ewb,
    const float* __restrict__ kb, const float* __restrict__ vb,
    const float* __restrict__ aab, const float* __restrict__ bbb,
    int t, int cb, int j0, int vidx)
{
    StepIn s;
    const size_t base = (size_t)t * C_DIM + cb;
    s.r = *(const float4*)(rb + base + j0);
    s.e = *(const float4*)(ewb + base + j0);
    s.k = *(const float4*)(kb + base + j0);
    s.a = *(const float4*)(aab + base + j0);
    s.b = *(const float4*)(bbb + base + j0);
    s.v = vb[base + vidx];
    return s;
}

static __device__ __forceinline__ void step_compute(
    float4& S, const StepIn& st, float* __restrict__ y,
    int t, int cb, int vidx, int lane)
{
    float sa = S.x * st.a.x;
    sa = fmaf(S.y, st.a.y, sa);
    sa = fmaf(S.z, st.a.z, sa);
    sa = fmaf(S.w, st.a.w, sa);
    sa = red16(sa);
    S.x = fmaf(st.v, st.k.x, fmaf(sa, st.b.x, S.x * st.e.x));
    S.y = fmaf(st.v, st.k.y, fmaf(sa, st.b.y, S.y * st.e.y));
    S.z = fmaf(st.v, st.k.z, fmaf(sa, st.b.z, S.z * st.e.z));
    S.w = fmaf(st.v, st.k.w, fmaf(sa, st.b.w, S.w * st.e.w));
    float o = S.x * st.r.x;
    o = fmaf(S.y, st.r.y, o);
    o = fmaf(S.z, st.r.z, o);
    o = fmaf(S.w, st.r.w, o);
    o = red16(o);
    if ((lane & 15) == 0)
        y[(size_t)t * C_DIM + cb + vidx] = o;
}

__global__ __launch_bounds__(64) void vscan(
    const float* __restrict__ rb, const float* __restrict__ ewb,
    const float* __restrict__ kb, const float* __restrict__ vb,
    const float* __restrict__ aab, const float* __restrict__ bbb,
    const float* __restrict__ init_state, float* __restrict__ y)
{
    const int h  = blockIdx.x & 15;     // b%8 == h%8 -> per-head XCD locality
    const int wv = blockIdx.x >> 4;
    const int l  = threadIdx.x;
    const int vidx = wv * 4 + (l >> 4);
    const int j0 = (l & 15) * 4;
    const int cb = h * 64;

    float4 S = *(const float4*)(init_state + h * 4096 + vidx * 64 + j0);

    StepIn X0 = load_step(rb, ewb, kb, vb, aab, bbb, 0, cb, j0, vidx);
    StepIn X1 = load_step(rb, ewb, kb, vb, aab, bbb, 1, cb, j0, vidx);
    StepIn X2 = load_step(rb, ewb, kb, vb, aab, bbb, 2, cb, j0, vidx);
    StepIn X3 = load_step(rb, ewb, kb, vb, aab, bbb, 3, cb, j0, vidx);
    for (int t = 0; t < T_LEN; t += 4) {
        step_compute(S, X0, y, t, cb, vidx, l);
        X0 = load_step(rb, ewb, kb, vb, aab, bbb,
                       (t + 4) & (T_LEN - 1), cb, j0, vidx);
        step_compute(S, X1, y, t + 1, cb, vidx, l);
        X1 = load_step(rb, ewb, kb, vb, aab, bbb,
                       (t + 5) & (T_LEN - 1), cb, j0, vidx);
        step_compute(S, X2, y, t + 2, cb, vidx, l);
        X2 = load_step(rb, ewb, kb, vb, aab, bbb,
                       (t + 6) & (T_LEN - 1), cb, j0, vidx);
        step_compute(S, X3, y, t + 3, cb, vidx, l);
        X3 = load_step(rb, ewb, kb, vb, aab, bbb,
                       (t + 7) & (T_LEN - 1), cb, j0, vidx);
    }
}

// ---------------------------------------------------------------------------
// GroupNorm + bonus + *g ; writes bf16 (xo*g) for the final MFMA GEMM.
// ---------------------------------------------------------------------------
__global__ __launch_bounds__(256) void gn_bonus(
    const float* __restrict__ y, const float* __restrict__ rb,
    const float* __restrict__ kb, const float* __restrict__ vb,
    const float* __restrict__ gb, const float* __restrict__ r_k,
    const float* __restrict__ lnw, const float* __restrict__ lnb,
    unsigned short* __restrict__ yg)
{
    const int t = blockIdx.x, tid = threadIdx.x;
    const int c0 = tid << 2;
    const size_t base = (size_t)t * C_DIM + c0;
    float4 yv = *(const float4*)(y + base);
    float sum = yv.x + yv.y + yv.z + yv.w;
    float ss  = yv.x * yv.x + yv.y * yv.y + yv.z * yv.z + yv.w * yv.w;
    float4 rv = *(const float4*)(rb + base);
    float4 kv = *(const float4*)(kb + base);
    float4 rkv = *(const float4*)(r_k + c0);
    float dot = rv.x * kv.x * rkv.x + rv.y * kv.y * rkv.y +
                rv.z * kv.z * rkv.z + rv.w * kv.w * rkv.w;
#pragma unroll
    for (int m = 1; m <= 8; m <<= 1) {
        sum += __shfl_xor(sum, m);
        ss  += __shfl_xor(ss, m);
        dot += __shfl_xor(dot, m);
    }
    const float mu = sum * 0.015625f;
    const float var = ss * 0.015625f - mu * mu;
    const float rstd = rsqrtf(var + 0.00064f);
    float4 wv = *(const float4*)(lnw + c0);
    float4 bv = *(const float4*)(lnb + c0);
    float4 vv = *(const float4*)(vb + base);
    float4 gv = *(const float4*)(gb + base);
    ushort4 o;
    o.x = f2bf(((yv.x - mu) * rstd * wv.x + bv.x + dot * vv.x) * gv.x);
    o.y = f2bf(((yv.y - mu) * rstd * wv.y + bv.y + dot * vv.y) * gv.y);
    o.z = f2bf(((yv.z - mu) * rstd * wv.z + bv.z + dot * vv.z) * gv.z);
    o.w = f2bf(((yv.w - mu) * rstd * wv.w + bv.w + dot * vv.w) * gv.w);
    *(ushort4*)(yg + base) = o;
}

// ---------------------------------------------------------------------------
extern "C" void kernel_launch(void* const* d_in, const int* in_sizes, int n_in,
                              void* d_out, int out_size, void* d_ws, size_t ws_size,
                              hipStream_t stream)
{
    (void)in_sizes; (void)n_in; (void)out_size; (void)ws_size;
    const float* x       = (const float*)d_in[0];
    const float* v_first = (const float*)d_in[1];
    const float* x_prev  = (const float*)d_in[2];
    const float* init_st = (const float*)d_in[3];
    const float* x_r = (const float*)d_in[4];
    const float* x_w = (const float*)d_in[5];
    const float* x_k = (const float*)d_in[6];
    const float* x_v = (const float*)d_in[7];
    const float* x_a = (const float*)d_in[8];
    const float* x_g = (const float*)d_in[9];
    const float* w0  = (const float*)d_in[10];
    const float* a0  = (const float*)d_in[11];
    const float* v0  = (const float*)d_in[12];
    const float* k_k = (const float*)d_in[13];
    const float* k_a = (const float*)d_in[14];
    const float* w1  = (const float*)d_in[15];
    const float* w2  = (const float*)d_in[16];
    const float* a1  = (const float*)d_in[17];
    const float* a2  = (const float*)d_in[18];
    const float* v1  = (const float*)d_in[19];
    const float* v2  = (const float*)d_in[20];
    const float* g1  = (const float*)d_in[21];
    const float* g2  = (const float*)d_in[22];
    const float* r_k = (const float*)d_in[23];
    const float* Wr  = (const float*)d_in[24];
    const float* Wk  = (const float*)d_in[25];
    const float* Wv  = (const float*)d_in[26];
    const float* Wo  = (const float*)d_in[27];
    const float* ln_w = (const float*)d_in[28];
    const float* ln_b = (const float*)d_in[29];

    float* out = (float*)d_out;
    float* ws  = (float*)d_ws;
    const size_t NE = (size_t)T_LEN * C_DIM;   // 2M activation elements
    const size_t WE = (size_t)C_DIM * C_DIM;   // 1M weight elements
    float* rB  = ws;
    float* ewB = ws + NE;
    float* kB  = ws + 2 * NE;
    float* vB  = ws + 3 * NE;
    float* aB  = ws + 4 * NE;   // a, then bb
    float* gB  = ws + 5 * NE;
    float* aaB = ws + 6 * NE;   // aa = -kk
    float* yB  = ws + 7 * NE;
    float* hB  = ws + 8 * NE;   // LoRA hidden (<= NE/8 words used)
    unsigned short* b16 = (unsigned short*)(ws + 8 * NE + NE / 4);
    unsigned short* xr16 = b16;                 // NE shorts
    unsigned short* xk16 = b16 + NE;            // NE
    unsigned short* xv16 = b16 + 2 * NE;        // NE
    unsigned short* Wr16 = b16 + 3 * NE;        // 4 x WE (matches wcvt4 layout)
    unsigned short* Wk16 = Wr16 + WE;
    unsigned short* Wv16 = Wr16 + 2 * WE;
    unsigned short* Wo16 = Wr16 + 3 * WE;
    unsigned short* yg16 = Wr16 + 4 * WE;       // NE

    wcvt4<<<4096, 256, 0, stream>>>(Wr, Wk, Wv, Wo, Wr16);
    xcvt<<<T_LEN, 256, 0, stream>>>(x, x_prev, x_r, x_k, x_v, xr16, xk16, xv16);

    dim3 gg(16, 16);
    gemm_bf16<<<gg, 256, 0, stream>>>(xr16, Wr16, rB);
    gemm_bf16<<<gg, 256, 0, stream>>>(xk16, Wk16, kB);
    gemm_bf16<<<gg, 256, 0, stream>>>(xv16, Wv16, vB);

    lora1<<<512, 256, 0, stream>>>(x, x_prev, x_w, w1, hB, 64, 1);
    lora2<<<dim3(4, 128), 256, 0, stream>>>(hB, w2, w0, ewB, nullptr, 64, 0);
    lora1<<<512, 256, 0, stream>>>(x, x_prev, x_a, a1, hB, 64, 0);
    lora2<<<dim3(4, 128), 256, 0, stream>>>(hB, a2, a0, aB, nullptr, 64, 1);
    lora1<<<256, 256, 0, stream>>>(x, x_prev, x_v, v1, hB, 32, 0);
    lora2<<<dim3(4, 128), 256, 0, stream>>>(hB, v2, v0, vB, v_first, 32, 2);
    lora1<<<1024, 256, 0, stream>>>(x, x_prev, x_g, g1, hB, 128, 2);
    lora2<<<dim3(4, 128), 256, 0, stream>>>(hB, g2, nullptr, gB, nullptr, 128, 3);

    kpost<<<T_LEN, 256, 0, stream>>>(kB, aB, aaB, k_k, k_a);
    vscan<<<256, 64, 0, stream>>>(rB, ewB, kB, vB, aaB, aB, init_st, yB);
    gn_bonus<<<T_LEN, 256, 0, stream>>>(yB, rB, kB, vB, gB, r_k, ln_w, ln_b, yg16);
    gemm_bf16<<<gg, 256, 0, stream>>>(yg16, Wo16, out);
}

// Round 9
// 913.677 us; speedup vs baseline: 2.8414x; 1.1561x over previous
//
#include <hip/hip_runtime.h>

#define T_LEN 2048
#define C_DIM 1024
#define BSTEP 8            // vscan steps per LDS batch
#define STEP_F 384         // floats per (head,step) packet: r,ew,k,v,aa,bb x64
#define BATCH_F (BSTEP * STEP_F)   // 3072 floats, contiguous per batch

#define AS1 __attribute__((address_space(1)))
#define AS3 __attribute__((address_space(3)))
// Real compiler fence + HW drain of all outstanding vmem (loads+stores).
#define VM_FENCE0() asm volatile("s_waitcnt vmcnt(0)" ::: "memory")

typedef __attribute__((ext_vector_type(8))) short bf8_t;
typedef __attribute__((ext_vector_type(4))) float f4_t;

static __device__ __forceinline__ float sigf(float x) {
    return 1.f / (1.f + __expf(-x));
}
static __device__ __forceinline__ unsigned short f2bf(float f) {
    unsigned u = __float_as_uint(f);
    u += 0x7fff + ((u >> 16) & 1);
    return (unsigned short)(u >> 16);
}

// ---------------------------------------------------------------------------
// Convert the four 1024x1024 fp32 weights into one bf16 block (1M strides).
// ---------------------------------------------------------------------------
__global__ __launch_bounds__(256) void wcvt4(
    const float* __restrict__ Wr, const float* __restrict__ Wk,
    const float* __restrict__ Wv, const float* __restrict__ Wo,
    unsigned short* __restrict__ dst)
{
    const size_t idx = ((size_t)blockIdx.x * 256 + threadIdx.x) * 4;
    const int sel = (int)(idx >> 20);
    const float* src = sel == 0 ? Wr : sel == 1 ? Wk : sel == 2 ? Wv : Wo;
    float4 v = *(const float4*)(src + (idx & 0xFFFFF));
    ushort4 o = {f2bf(v.x), f2bf(v.y), f2bf(v.z), f2bf(v.w)};
    *(ushort4*)(dst + idx) = o;
}

// ---------------------------------------------------------------------------
// Token-shift mix -> bf16 A-matrices for the r/k/v projections.
// ---------------------------------------------------------------------------
__global__ __launch_bounds__(256) void xcvt(
    const float* __restrict__ x, const float* __restrict__ xprev,
    const float* __restrict__ x_r, const float* __restrict__ x_k,
    const float* __restrict__ x_v,
    unsigned short* __restrict__ xr16, unsigned short* __restrict__ xk16,
    unsigned short* __restrict__ xv16)
{
    const int t = blockIdx.x;
    const int c0 = threadIdx.x * 4;
    const size_t base = (size_t)t * C_DIM + c0;
    float4 xv = *(const float4*)(x + base);
    float4 pv = (t == 0) ? *(const float4*)(xprev + c0)
                         : *(const float4*)(x + base - C_DIM);
    float4 dx = {pv.x - xv.x, pv.y - xv.y, pv.z - xv.z, pv.w - xv.w};
    float4 mr = *(const float4*)(x_r + c0);
    float4 mk = *(const float4*)(x_k + c0);
    float4 mv = *(const float4*)(x_v + c0);
    ushort4 orr = {f2bf(xv.x + dx.x * mr.x), f2bf(xv.y + dx.y * mr.y),
                   f2bf(xv.z + dx.z * mr.z), f2bf(xv.w + dx.w * mr.w)};
    ushort4 ok = {f2bf(xv.x + dx.x * mk.x), f2bf(xv.y + dx.y * mk.y),
                  f2bf(xv.z + dx.z * mk.z), f2bf(xv.w + dx.w * mk.w)};
    ushort4 ov = {f2bf(xv.x + dx.x * mv.x), f2bf(xv.y + dx.y * mv.y),
                  f2bf(xv.z + dx.z * mv.z), f2bf(xv.w + dx.w * mv.w)};
    *(ushort4*)(xr16 + base) = orr;
    *(ushort4*)(xk16 + base) = ok;
    *(ushort4*)(xv16 + base) = ov;
}

// ---------------------------------------------------------------------------
// bf16 MFMA NT GEMM core: out[t,i] = sum_c A[t,c]*W[i,c], fp32 accumulate.
// 128x64 tile, BK=32, 256 threads, double-buffered LDS via global_load_lds.
// ---------------------------------------------------------------------------
static __device__ __forceinline__ void gemm_core(
    const unsigned short* __restrict__ A, const unsigned short* __restrict__ W,
    float* __restrict__ out)
{
    __shared__ unsigned short Ab[2][128 * 32];
    __shared__ unsigned short Bb[2][64 * 32];
    const int tid = threadIdx.x;
    const int lane = tid & 63;
    const int w = tid >> 6;
    const int n0 = blockIdx.x * 64;
    const int t0 = blockIdx.y * 128;
    const int wm = (w & 1) * 64;
    const int wn = (w >> 1) * 32;
    const int srow = lane >> 2;
    const int scol = (lane & 3) * 8;

    f4_t acc[4][2];
#pragma unroll
    for (int i = 0; i < 4; ++i)
#pragma unroll
        for (int j = 0; j < 2; ++j)
            acc[i][j] = (f4_t){0.f, 0.f, 0.f, 0.f};

#pragma unroll
    for (int s = 0; s < 2; ++s) {
        const int i = 2 * w + s;
        __builtin_amdgcn_global_load_lds(
            (const AS1 unsigned int*)(A + (size_t)(t0 + i * 16 + srow) * 1024 + scol),
            (AS3 unsigned int*)(&Ab[0][i * 512 + lane * 8]), 16, 0, 0);
    }
    __builtin_amdgcn_global_load_lds(
        (const AS1 unsigned int*)(W + (size_t)(n0 + w * 16 + srow) * 1024 + scol),
        (AS3 unsigned int*)(&Bb[0][w * 512 + lane * 8]), 16, 0, 0);

    const int mrow = lane & 15;
    const int kq = (lane >> 4) * 8;
    for (int k0 = 0; k0 < 1024; k0 += 32) {
        const int cur = (k0 >> 5) & 1, nxt = cur ^ 1;
        __syncthreads();
        if (k0 + 32 < 1024) {
            const int k1 = k0 + 32;
#pragma unroll
            for (int s = 0; s < 2; ++s) {
                const int i = 2 * w + s;
                __builtin_amdgcn_global_load_lds(
                    (const AS1 unsigned int*)(A + (size_t)(t0 + i * 16 + srow) * 1024 + k1 + scol),
                    (AS3 unsigned int*)(&Ab[nxt][i * 512 + lane * 8]), 16, 0, 0);
            }
            __builtin_amdgcn_global_load_lds(
                (const AS1 unsigned int*)(W + (size_t)(n0 + w * 16 + srow) * 1024 + k1 + scol),
                (AS3 unsigned int*)(&Bb[nxt][w * 512 + lane * 8]), 16, 0, 0);
        }
        bf8_t af[4], bfr[2];
#pragma unroll
        for (int i = 0; i < 4; ++i)
            af[i] = *(const bf8_t*)(&Ab[cur][(wm + 16 * i + mrow) * 32 + kq]);
#pragma unroll
        for (int j = 0; j < 2; ++j)
            bfr[j] = *(const bf8_t*)(&Bb[cur][(wn + 16 * j + mrow) * 32 + kq]);
#pragma unroll
        for (int i = 0; i < 4; ++i)
#pragma unroll
            for (int j = 0; j < 2; ++j)
                acc[i][j] = __builtin_amdgcn_mfma_f32_16x16x32_bf16(
                    af[i], bfr[j], acc[i][j], 0, 0, 0);
    }
    const int crow = (lane >> 4) * 4;
    const int ccol = lane & 15;
#pragma unroll
    for (int i = 0; i < 4; ++i)
#pragma unroll
        for (int j = 0; j < 2; ++j)
#pragma unroll
            for (int u = 0; u < 4; ++u)
                out[(size_t)(t0 + wm + 16 * i + crow + u) * 1024
                    + n0 + wn + 16 * j + ccol] = acc[i][j][u];
}

// Fused r/k/v projections: blockIdx.z selects the (A, W, out) triple.
__global__ __launch_bounds__(256) void gemm_bf16_3(
    const unsigned short* __restrict__ xr, const unsigned short* __restrict__ xk,
    const unsigned short* __restrict__ xv,
    const unsigned short* __restrict__ Wr, const unsigned short* __restrict__ Wk,
    const unsigned short* __restrict__ Wv,
    float* __restrict__ rB, float* __restrict__ kB, float* __restrict__ vB)
{
    const int z = blockIdx.z;
    const unsigned short* A = z == 0 ? xr : z == 1 ? xk : xv;
    const unsigned short* W = z == 0 ? Wr : z == 1 ? Wk : Wv;
    float* out = z == 0 ? rB : z == 1 ? kB : vB;
    gemm_core(A, W, out);
}

__global__ __launch_bounds__(256) void gemm_bf16(
    const unsigned short* __restrict__ A, const unsigned short* __restrict__ W,
    float* __restrict__ out)
{
    gemm_core(A, W, out);
}

// ---------------------------------------------------------------------------
// LoRA stage 1 (fp32)
// ---------------------------------------------------------------------------
__global__ __launch_bounds__(256) void lora1(
    const float* __restrict__ X, const float* __restrict__ xprev,
    const float* __restrict__ mixv, const float* __restrict__ W1,
    float* __restrict__ hbuf, int Kh, int act)
{
    __shared__ __align__(16) float As[8192];
    const int tid = threadIdx.x;
    const int tpb = 256 / Kh;
    const int t0 = blockIdx.x * tpb;
    for (int idx = tid; idx < (tpb << 10); idx += 256) {
        int l = idx >> 10, cc = idx & 1023;
        int t = t0 + l;
        float xv = X[(size_t)t * C_DIM + cc];
        float pv = (t == 0) ? xprev[cc] : X[(size_t)(t - 1) * C_DIM + cc];
        As[idx] = xv + (pv - xv) * mixv[cc];
    }
    __syncthreads();
    const int l = tid / Kh;
    const int j = tid % Kh;
    const float* arow = As + (l << 10);
    float acc = 0.f;
#pragma unroll 4
    for (int cc = 0; cc < 1024; ++cc)
        acc = fmaf(arow[cc], W1[(size_t)cc * Kh + j], acc);
    if (act == 1) acc = tanhf(acc);
    else if (act == 2) acc = sigf(acc);
    hbuf[(size_t)(t0 + l) * Kh + j] = acc;
}

// ---------------------------------------------------------------------------
// Fused LoRA-2 for all four paths + k post-process + vscan-stream packing.
// Block = 16 tokens x 256 channels. Head = 64 consecutive channels = 1 wave.
// Writes: kB/vB/gB (final) and pk[h][t][{r,ew,k,v,aa,bb}][64].
// ---------------------------------------------------------------------------
__global__ __launch_bounds__(256) void lora2f(
    const float* __restrict__ hwB, const float* __restrict__ haB,
    const float* __restrict__ hvB, const float* __restrict__ hgB,
    const float* __restrict__ w2, const float* __restrict__ a2,
    const float* __restrict__ v2, const float* __restrict__ g2,
    const float* __restrict__ w0, const float* __restrict__ a0,
    const float* __restrict__ v0,
    const float* __restrict__ k_k, const float* __restrict__ k_a,
    const float* __restrict__ v_first, const float* __restrict__ rB,
    float* __restrict__ kB, float* __restrict__ vB, float* __restrict__ gB,
    float* __restrict__ pk)
{
    __shared__ __align__(16) float hsW[16 * 64], hsA[16 * 64];
    __shared__ __align__(16) float hsV[16 * 32], hsG[16 * 128];
    const int tid = threadIdx.x;
    const int t0 = blockIdx.y * 16;
    const int i  = blockIdx.x * 256 + tid;
    const int h  = i >> 6;
    const int j  = i & 63;
    for (int idx = tid; idx < 16 * 64; idx += 256) {
        hsW[idx] = hwB[(size_t)t0 * 64 + idx];
        hsA[idx] = haB[(size_t)t0 * 64 + idx];
    }
    for (int idx = tid; idx < 16 * 32; idx += 256)
        hsV[idx] = hvB[(size_t)t0 * 32 + idx];
    for (int idx = tid; idx < 16 * 128; idx += 256)
        hsG[idx] = hgB[(size_t)t0 * 128 + idx];
    __syncthreads();

    float av[16], ew[16], vf[16];
    { // a = sigmoid(a0 + ha@a2)
        float acc[16];
        const float b0 = a0[i];
#pragma unroll
        for (int tt = 0; tt < 16; ++tt) acc[tt] = b0;
        for (int jj = 0; jj < 64; jj += 4) {
            const float q0 = a2[(size_t)(jj + 0) * C_DIM + i];
            const float q1 = a2[(size_t)(jj + 1) * C_DIM + i];
            const float q2 = a2[(size_t)(jj + 2) * C_DIM + i];
            const float q3 = a2[(size_t)(jj + 3) * C_DIM + i];
#pragma unroll
            for (int tt = 0; tt < 16; ++tt) {
                float4 h4 = *(const float4*)(hsA + tt * 64 + jj);
                acc[tt] = fmaf(h4.x, q0, acc[tt]);
                acc[tt] = fmaf(h4.y, q1, acc[tt]);
                acc[tt] = fmaf(h4.z, q2, acc[tt]);
                acc[tt] = fmaf(h4.w, q3, acc[tt]);
            }
        }
#pragma unroll
        for (int tt = 0; tt < 16; ++tt) av[tt] = sigf(acc[tt]);
    }
    { // exp(w) = exp(-e^{-0.5} * sigmoid(w0 + hw@w2))
        float acc[16];
        const float b0 = w0[i];
#pragma unroll
        for (int tt = 0; tt < 16; ++tt) acc[tt] = b0;
        for (int jj = 0; jj < 64; jj += 4) {
            const float q0 = w2[(size_t)(jj + 0) * C_DIM + i];
            const float q1 = w2[(size_t)(jj + 1) * C_DIM + i];
            const float q2 = w2[(size_t)(jj + 2) * C_DIM + i];
            const float q3 = w2[(size_t)(jj + 3) * C_DIM + i];
#pragma unroll
            for (int tt = 0; tt < 16; ++tt) {
                float4 h4 = *(const float4*)(hsW + tt * 64 + jj);
                acc[tt] = fmaf(h4.x, q0, acc[tt]);
                acc[tt] = fmaf(h4.y, q1, acc[tt]);
                acc[tt] = fmaf(h4.z, q2, acc[tt]);
                acc[tt] = fmaf(h4.w, q3, acc[tt]);
            }
        }
#pragma unroll
        for (int tt = 0; tt < 16; ++tt)
            ew[tt] = __expf(-0.6065306597126334f * sigf(acc[tt]));
    }
    { // v = v_raw + (v_first - v_raw) * sigmoid(v0 + hv@v2)
        float acc[16];
        const float b0 = v0[i];
#pragma unroll
        for (int tt = 0; tt < 16; ++tt) acc[tt] = b0;
        for (int jj = 0; jj < 32; jj += 4) {
            const float q0 = v2[(size_t)(jj + 0) * C_DIM + i];
            const float q1 = v2[(size_t)(jj + 1) * C_DIM + i];
            const float q2 = v2[(size_t)(jj + 2) * C_DIM + i];
            const float q3 = v2[(size_t)(jj + 3) * C_DIM + i];
#pragma unroll
            for (int tt = 0; tt < 16; ++tt) {
                float4 h4 = *(const float4*)(hsV + tt * 32 + jj);
                acc[tt] = fmaf(h4.x, q0, acc[tt]);
                acc[tt] = fmaf(h4.y, q1, acc[tt]);
                acc[tt] = fmaf(h4.z, q2, acc[tt]);
                acc[tt] = fmaf(h4.w, q3, acc[tt]);
            }
        }
#pragma unroll
        for (int tt = 0; tt < 16; ++tt) {
            const size_t gi = (size_t)(t0 + tt) * C_DIM + i;
            const float s = sigf(acc[tt]);
            const float vr = vB[gi];
            vf[tt] = vr + (v_first[gi] - vr) * s;
            vB[gi] = vf[tt];
        }
    }
    { // g = (sigmoid hidden) @ g2
        float acc[16];
#pragma unroll
        for (int tt = 0; tt < 16; ++tt) acc[tt] = 0.f;
        for (int jj = 0; jj < 128; jj += 4) {
            const float q0 = g2[(size_t)(jj + 0) * C_DIM + i];
            const float q1 = g2[(size_t)(jj + 1) * C_DIM + i];
            const float q2 = g2[(size_t)(jj + 2) * C_DIM + i];
            const float q3 = g2[(size_t)(jj + 3) * C_DIM + i];
#pragma unroll
            for (int tt = 0; tt < 16; ++tt) {
                float4 h4 = *(const float4*)(hsG + tt * 128 + jj);
                acc[tt] = fmaf(h4.x, q0, acc[tt]);
                acc[tt] = fmaf(h4.y, q1, acc[tt]);
                acc[tt] = fmaf(h4.z, q2, acc[tt]);
                acc[tt] = fmaf(h4.w, q3, acc[tt]);
            }
        }
#pragma unroll
        for (int tt = 0; tt < 16; ++tt)
            gB[(size_t)(t0 + tt) * C_DIM + i] = acc[tt];
    }
    // k post-process + pack (head = full wave: 64 consecutive channels)
    const float kkw = k_k[i], kaw = k_a[i];
    const size_t pbase = (size_t)h * T_LEN * STEP_F;
#pragma unroll 4
    for (int tt = 0; tt < 16; ++tt) {
        const int t = t0 + tt;
        const size_t gi = (size_t)t * C_DIM + i;
        const float kraw = kB[gi];
        const float kn = kraw * kkw;
        float ss = kn * kn;
#pragma unroll
        for (int m = 1; m <= 32; m <<= 1) ss += __shfl_xor(ss, m);
        const float sc = 1.f / fmaxf(sqrtf(ss), 1e-12f);
        const float kk = kn * sc;
        const float a_ = av[tt];
        const float kf = kraw * (1.f + (a_ - 1.f) * kaw);
        kB[gi] = kf;
        float* p = pk + pbase + (size_t)t * STEP_F;
        p[j]        = rB[gi];
        p[64 + j]   = ew[tt];
        p[128 + j]  = kf;
        p[192 + j]  = vf[tt];
        p[256 + j]  = -kk;
        p[320 + j]  = kk * a_;
    }
}

// ---------------------------------------------------------------------------
// v-row-parallel scan, batched LDS double-buffer.
// 256 blocks x 64 threads; block b -> head (b&15) (XCD-local streams).
// A batch of 8 steps is a CONTIGUOUS 3072-float span of pk, staged with 12
// full-wave 16B global_load_lds (exec-uniform, no predication). Fence =
// asm s_waitcnt vmcnt(0) + memory clobber.
// ---------------------------------------------------------------------------
struct Step { float4 r, e, k, a, b; float v; };

static __device__ __forceinline__ float red16(float x) {
    int xi;
    xi = __builtin_amdgcn_mov_dpp(__float_as_int(x), 0x128, 0xf, 0xf, true);
    x += __int_as_float(xi);
    xi = __builtin_amdgcn_mov_dpp(__float_as_int(x), 0x124, 0xf, 0xf, true);
    x += __int_as_float(xi);
    xi = __builtin_amdgcn_mov_dpp(__float_as_int(x), 0x122, 0xf, 0xf, true);
    x += __int_as_float(xi);
    xi = __builtin_amdgcn_mov_dpp(__float_as_int(x), 0x121, 0xf, 0xf, true);
    x += __int_as_float(xi);
    return x;
}

static __device__ __forceinline__ void issue_batch(
    const float* __restrict__ hbase, float* __restrict__ buf, int batch, int l)
{
    const float* src = hbase + (size_t)batch * BATCH_F;
#pragma unroll
    for (int i = 0; i < BATCH_F / 256; ++i)   // 12 full-wave 16B loads
        __builtin_amdgcn_global_load_lds(
            (const AS1 unsigned int*)(src + i * 256 + l * 4),
            (AS3 unsigned int*)(&buf[i * 256 + l * 4]), 16, 0, 0);
}

static __device__ __forceinline__ Step slot_read(
    const float* __restrict__ buf, int s, int j0, int vidx)
{
    Step st;
    const float* p = buf + s * STEP_F;
    st.r = *(const float4*)(p + j0);
    st.e = *(const float4*)(p + 64 + j0);
    st.k = *(const float4*)(p + 128 + j0);
    st.v = p[192 + vidx];
    st.a = *(const float4*)(p + 256 + j0);
    st.b = *(const float4*)(p + 320 + j0);
    return st;
}

static __device__ __forceinline__ void step_compute(
    float4& S, const Step& st, float* __restrict__ y,
    int t, int cb, int vidx, int lane)
{
    float sa = S.x * st.a.x;
    sa = fmaf(S.y, st.a.y, sa);
    sa = fmaf(S.z, st.a.z, sa);
    sa = fmaf(S.w, st.a.w, sa);
    sa = red16(sa);
    S.x = fmaf(st.v, st.k.x, fmaf(sa, st.b.x, S.x * st.e.x));
    S.y = fmaf(st.v, st.k.y, fmaf(sa, st.b.y, S.y * st.e.y));
    S.z = fmaf(st.v, st.k.z, fmaf(sa, st.b.z, S.z * st.e.z));
    S.w = fmaf(st.v, st.k.w, fmaf(sa, st.b.w, S.w * st.e.w));
    float o = S.x * st.r.x;
    o = fmaf(S.y, st.r.y, o);
    o = fmaf(S.z, st.r.z, o);
    o = fmaf(S.w, st.r.w, o);
    o = red16(o);
    if ((lane & 15) == 0)
        y[(size_t)t * C_DIM + cb + vidx] = o;
}

__global__ __launch_bounds__(64) void vscan(
    const float* __restrict__ pk, const float* __restrict__ init_state,
    float* __restrict__ y)
{
    const int h  = blockIdx.x & 15;     // b%8 == h%8 -> per-head XCD locality
    const int wv = blockIdx.x >> 4;
    const int l  = threadIdx.x;
    const int vidx = wv * 4 + (l >> 4);
    const int j0 = (l & 15) * 4;
    const int cb = h * 64;

    __shared__ __align__(16) float buf[2][BATCH_F];
    const float* hbase = pk + (size_t)h * T_LEN * STEP_F;

    float4 S = *(const float4*)(init_state + h * 4096 + vidx * 64 + j0);

    issue_batch(hbase, buf[0], 0, l);
    VM_FENCE0();
    const int NB = T_LEN / BSTEP;
    for (int b = 0; b < NB; ++b) {
        if (b + 1 < NB)
            issue_batch(hbase, buf[(b + 1) & 1], b + 1, l);
        const float* cbuf = buf[b & 1];
#pragma unroll
        for (int s = 0; s < BSTEP; ++s) {
            Step st = slot_read(cbuf, s, j0, vidx);
            step_compute(S, st, y, b * BSTEP + s, cb, vidx, l);
        }
        VM_FENCE0();   // next batch fully landed; also drains o-stores
    }
}

// ---------------------------------------------------------------------------
// GroupNorm + bonus + *g ; writes bf16 (xo*g) for the final MFMA GEMM.
// ---------------------------------------------------------------------------
__global__ __launch_bounds__(256) void gn_bonus(
    const float* __restrict__ y, const float* __restrict__ rb,
    const float* __restrict__ kb, const float* __restrict__ vb,
    const float* __restrict__ gb, const float* __restrict__ r_k,
    const float* __restrict__ lnw, const float* __restrict__ lnb,
    unsigned short* __restrict__ yg)
{
    const int t = blockIdx.x, tid = threadIdx.x;
    const int c0 = tid << 2;
    const size_t base = (size_t)t * C_DIM + c0;
    float4 yv = *(const float4*)(y + base);
    float sum = yv.x + yv.y + yv.z + yv.w;
    float ss  = yv.x * yv.x + yv.y * yv.y + yv.z * yv.z + yv.w * yv.w;
    float4 rv = *(const float4*)(rb + base);
    float4 kv = *(const float4*)(kb + base);
    float4 rkv = *(const float4*)(r_k + c0);
    float dot = rv.x * kv.x * rkv.x + rv.y * kv.y * rkv.y +
                rv.z * kv.z * rkv.z + rv.w * kv.w * rkv.w;
#pragma unroll
    for (int m = 1; m <= 8; m <<= 1) {
        sum += __shfl_xor(sum, m);
        ss  += __shfl_xor(ss, m);
        dot += __shfl_xor(dot, m);
    }
    const float mu = sum * 0.015625f;
    const float var = ss * 0.015625f - mu * mu;
    const float rstd = rsqrtf(var + 0.00064f);
    float4 wv = *(const float4*)(lnw + c0);
    float4 bv = *(const float4*)(lnb + c0);
    float4 vv = *(const float4*)(vb + base);
    float4 gv = *(const float4*)(gb + base);
    ushort4 o;
    o.x = f2bf(((yv.x - mu) * rstd * wv.x + bv.x + dot * vv.x) * gv.x);
    o.y = f2bf(((yv.y - mu) * rstd * wv.y + bv.y + dot * vv.y) * gv.y);
    o.z = f2bf(((yv.z - mu) * rstd * wv.z + bv.z + dot * vv.z) * gv.z);
    o.w = f2bf(((yv.w - mu) * rstd * wv.w + bv.w + dot * vv.w) * gv.w);
    *(ushort4*)(yg + base) = o;
}

// ---------------------------------------------------------------------------
extern "C" void kernel_launch(void* const* d_in, const int* in_sizes, int n_in,
                              void* d_out, int out_size, void* d_ws, size_t ws_size,
                              hipStream_t stream)
{
    (void)in_sizes; (void)n_in; (void)out_size; (void)ws_size;
    const float* x       = (const float*)d_in[0];
    const float* v_first = (const float*)d_in[1];
    const float* x_prev  = (const float*)d_in[2];
    const float* init_st = (const float*)d_in[3];
    const float* x_r = (const float*)d_in[4];
    const float* x_w = (const float*)d_in[5];
    const float* x_k = (const float*)d_in[6];
    const float* x_v = (const float*)d_in[7];
    const float* x_a = (const float*)d_in[8];
    const float* x_g = (const float*)d_in[9];
    const float* w0  = (const float*)d_in[10];
    const float* a0  = (const float*)d_in[11];
    const float* v0  = (const float*)d_in[12];
    const float* k_k = (const float*)d_in[13];
    const float* k_a = (const float*)d_in[14];
    const float* w1  = (const float*)d_in[15];
    const float* w2  = (const float*)d_in[16];
    const float* a1  = (const float*)d_in[17];
    const float* a2  = (const float*)d_in[18];
    const float* v1  = (const float*)d_in[19];
    const float* v2  = (const float*)d_in[20];
    const float* g1  = (const float*)d_in[21];
    const float* g2  = (const float*)d_in[22];
    const float* r_k = (const float*)d_in[23];
    const float* Wr  = (const float*)d_in[24];
    const float* Wk  = (const float*)d_in[25];
    const float* Wv  = (const float*)d_in[26];
    const float* Wo  = (const float*)d_in[27];
    const float* ln_w = (const float*)d_in[28];
    const float* ln_b = (const float*)d_in[29];

    float* out = (float*)d_out;
    float* ws  = (float*)d_ws;
    const size_t NE = (size_t)T_LEN * C_DIM;   // 2M
    const size_t WE = (size_t)C_DIM * C_DIM;   // 1M
    float* rB  = ws;
    float* kB  = ws + NE;
    float* vB  = ws + 2 * NE;
    float* gB  = ws + 3 * NE;
    float* hwB = ws + 4 * NE;                  // T*64
    float* haB = hwB + (size_t)T_LEN * 64;
    float* hvB = haB + (size_t)T_LEN * 64;
    float* hgB = hvB + (size_t)T_LEN * 32;     // h region < NE/2
    float* pk  = ws + 4 * NE + NE / 2;         // 16*T*384 = 6*NE floats
    unsigned short* b16 = (unsigned short*)(ws + 10 * NE + NE / 2);
    unsigned short* xr16 = b16;                // NE shorts
    unsigned short* xk16 = b16 + NE;
    unsigned short* xv16 = b16 + 2 * NE;
    unsigned short* Wr16 = b16 + 3 * NE;       // 4*WE shorts
    unsigned short* Wk16 = Wr16 + WE;
    unsigned short* Wv16 = Wr16 + 2 * WE;
    unsigned short* Wo16 = Wr16 + 3 * WE;
    unsigned short* yg16 = b16 + 5 * NE;       // NE shorts
    // yB aliases xr16/xk16 (consumed by gemms before vscan writes it)
    float* yB = (float*)xr16;

    wcvt4<<<4096, 256, 0, stream>>>(Wr, Wk, Wv, Wo, Wr16);
    xcvt<<<T_LEN, 256, 0, stream>>>(x, x_prev, x_r, x_k, x_v, xr16, xk16, xv16);

    gemm_bf16_3<<<dim3(16, 16, 3), 256, 0, stream>>>(
        xr16, xk16, xv16, Wr16, Wk16, Wv16, rB, kB, vB);

    lora1<<<512, 256, 0, stream>>>(x, x_prev, x_w, w1, hwB, 64, 1);
    lora1<<<512, 256, 0, stream>>>(x, x_prev, x_a, a1, haB, 64, 0);
    lora1<<<256, 256, 0, stream>>>(x, x_prev, x_v, v1, hvB, 32, 0);
    lora1<<<1024, 256, 0, stream>>>(x, x_prev, x_g, g1, hgB, 128, 2);

    lora2f<<<dim3(4, 128), 256, 0, stream>>>(
        hwB, haB, hvB, hgB, w2, a2, v2, g2, w0, a0, v0,
        k_k, k_a, v_first, rB, kB, vB, gB, pk);

    vscan<<<256, 64, 0, stream>>>(pk, init_st, yB);
    gn_bonus<<<T_LEN, 256, 0, stream>>>(yB, rB, kB, vB, gB, r_k, ln_w, ln_b, yg16);
    gemm_bf16<<<dim3(16, 16), 256, 0, stream>>>(yg16, Wo16, out);
}

// Round 10
// 582.123 us; speedup vs baseline: 4.4597x; 1.5696x over previous
//
#include <hip/hip_runtime.h>

#define T_LEN 2048
#define C_DIM 1024
#define BSTEP 8            // vscan steps per LDS batch
#define STEP_F 384         // floats per (head,step) packet: r,ew,k,v,aa,bb x64
#define BATCH_F (BSTEP * STEP_F)   // 3072 floats, contiguous per batch

#define AS1 __attribute__((address_space(1)))
#define AS3 __attribute__((address_space(3)))
#define VM_FENCE0() asm volatile("s_waitcnt vmcnt(0)" ::: "memory")
// compiler-only memory barrier: pins program order of vmem ops around it
#define C_FENCE() asm volatile("" ::: "memory")
// wait until <=8 outstanding vmem (the 12 prefetch loads done; stores may fly)
#define VM_FENCE8() asm volatile("s_waitcnt vmcnt(8)" ::: "memory")

typedef __attribute__((ext_vector_type(8))) short bf8_t;
typedef __attribute__((ext_vector_type(4))) float f4_t;

static __device__ __forceinline__ float sigf(float x) {
    return 1.f / (1.f + __expf(-x));
}
static __device__ __forceinline__ unsigned short f2bf(float f) {
    unsigned u = __float_as_uint(f);
    u += 0x7fff + ((u >> 16) & 1);
    return (unsigned short)(u >> 16);
}

// ---------------------------------------------------------------------------
// Convert the four 1024x1024 fp32 weights into one bf16 block (1M strides).
// ---------------------------------------------------------------------------
__global__ __launch_bounds__(256) void wcvt4(
    const float* __restrict__ Wr, const float* __restrict__ Wk,
    const float* __restrict__ Wv, const float* __restrict__ Wo,
    unsigned short* __restrict__ dst)
{
    const size_t idx = ((size_t)blockIdx.x * 256 + threadIdx.x) * 4;
    const int sel = (int)(idx >> 20);
    const float* src = sel == 0 ? Wr : sel == 1 ? Wk : sel == 2 ? Wv : Wo;
    float4 v = *(const float4*)(src + (idx & 0xFFFFF));
    ushort4 o = {f2bf(v.x), f2bf(v.y), f2bf(v.z), f2bf(v.w)};
    *(ushort4*)(dst + idx) = o;
}

// ---------------------------------------------------------------------------
// Convert + transpose LoRA stage-1 weights to bf16 row-major [N][K].
// lw16 layout: w1t[64][1024] | a1t[64][1024] | v1t[64][1024] | g1t[128][1024]
// (v1t rows 32..63 left unwritten; consumers guard.)
// ---------------------------------------------------------------------------
__global__ __launch_bounds__(256) void wcvt_lora(
    const float* __restrict__ w1, const float* __restrict__ a1,
    const float* __restrict__ v1, const float* __restrict__ g1,
    unsigned short* __restrict__ lw16)
{
    const int row = blockIdx.x;       // 0..287
    const float* src; int Kh, i; unsigned short* dst;
    if (row < 64)       { src = w1; Kh = 64;  i = row;       dst = lw16 + (size_t)row * 1024; }
    else if (row < 128) { src = a1; Kh = 64;  i = row - 64;  dst = lw16 + (size_t)row * 1024; }
    else if (row < 160) { src = v1; Kh = 32;  i = row - 128; dst = lw16 + (size_t)(row - 128 + 128) * 1024; }
    else                { src = g1; Kh = 128; i = row - 160; dst = lw16 + (size_t)(row - 160 + 192) * 1024; }
    const int c0 = threadIdx.x * 4;
#pragma unroll
    for (int u = 0; u < 4; ++u)
        dst[c0 + u] = f2bf(src[(size_t)(c0 + u) * Kh + i]);
}

// ---------------------------------------------------------------------------
// Token-shift mix -> bf16 A-matrices for r/k/v projections and w/a/g LoRA.
// ---------------------------------------------------------------------------
__global__ __launch_bounds__(256) void xcvt(
    const float* __restrict__ x, const float* __restrict__ xprev,
    const float* __restrict__ x_r, const float* __restrict__ x_k,
    const float* __restrict__ x_v, const float* __restrict__ x_w,
    const float* __restrict__ x_a, const float* __restrict__ x_g,
    unsigned short* __restrict__ xr16, unsigned short* __restrict__ xk16,
    unsigned short* __restrict__ xv16, unsigned short* __restrict__ xw16,
    unsigned short* __restrict__ xa16, unsigned short* __restrict__ xg16)
{
    const int t = blockIdx.x;
    const int c0 = threadIdx.x * 4;
    const size_t base = (size_t)t * C_DIM + c0;
    float4 xv = *(const float4*)(x + base);
    float4 pv = (t == 0) ? *(const float4*)(xprev + c0)
                         : *(const float4*)(x + base - C_DIM);
    float4 dx = {pv.x - xv.x, pv.y - xv.y, pv.z - xv.z, pv.w - xv.w};
#define MIXOUT(mixp, dstp)                                                    \
    {                                                                          \
        float4 mv = *(const float4*)(mixp + c0);                               \
        ushort4 o = {f2bf(xv.x + dx.x * mv.x), f2bf(xv.y + dx.y * mv.y),       \
                     f2bf(xv.z + dx.z * mv.z), f2bf(xv.w + dx.w * mv.w)};      \
        *(ushort4*)(dstp + base) = o;                                          \
    }
    MIXOUT(x_r, xr16) MIXOUT(x_k, xk16) MIXOUT(x_v, xv16)
    MIXOUT(x_w, xw16) MIXOUT(x_a, xa16) MIXOUT(x_g, xg16)
#undef MIXOUT
}

// ---------------------------------------------------------------------------
// bf16 MFMA NT GEMM core: out[t,i] = sum_c A[t,c]*W[i,c], fp32 accumulate.
// 128x64 tile, BK=32, 256 threads, double-buffered LDS via global_load_lds.
// ---------------------------------------------------------------------------
static __device__ __forceinline__ void gemm_core(
    const unsigned short* __restrict__ A, const unsigned short* __restrict__ W,
    float* __restrict__ out)
{
    __shared__ unsigned short Ab[2][128 * 32];
    __shared__ unsigned short Bb[2][64 * 32];
    const int tid = threadIdx.x;
    const int lane = tid & 63;
    const int w = tid >> 6;
    const int n0 = blockIdx.x * 64;
    const int t0 = blockIdx.y * 128;
    const int wm = (w & 1) * 64;
    const int wn = (w >> 1) * 32;
    const int srow = lane >> 2;
    const int scol = (lane & 3) * 8;

    f4_t acc[4][2];
#pragma unroll
    for (int i = 0; i < 4; ++i)
#pragma unroll
        for (int j = 0; j < 2; ++j)
            acc[i][j] = (f4_t){0.f, 0.f, 0.f, 0.f};

#pragma unroll
    for (int s = 0; s < 2; ++s) {
        const int i = 2 * w + s;
        __builtin_amdgcn_global_load_lds(
            (const AS1 unsigned int*)(A + (size_t)(t0 + i * 16 + srow) * 1024 + scol),
            (AS3 unsigned int*)(&Ab[0][i * 512 + lane * 8]), 16, 0, 0);
    }
    __builtin_amdgcn_global_load_lds(
        (const AS1 unsigned int*)(W + (size_t)(n0 + w * 16 + srow) * 1024 + scol),
        (AS3 unsigned int*)(&Bb[0][w * 512 + lane * 8]), 16, 0, 0);

    const int mrow = lane & 15;
    const int kq = (lane >> 4) * 8;
    for (int k0 = 0; k0 < 1024; k0 += 32) {
        const int cur = (k0 >> 5) & 1, nxt = cur ^ 1;
        __syncthreads();
        if (k0 + 32 < 1024) {
            const int k1 = k0 + 32;
#pragma unroll
            for (int s = 0; s < 2; ++s) {
                const int i = 2 * w + s;
                __builtin_amdgcn_global_load_lds(
                    (const AS1 unsigned int*)(A + (size_t)(t0 + i * 16 + srow) * 1024 + k1 + scol),
                    (AS3 unsigned int*)(&Ab[nxt][i * 512 + lane * 8]), 16, 0, 0);
            }
            __builtin_amdgcn_global_load_lds(
                (const AS1 unsigned int*)(W + (size_t)(n0 + w * 16 + srow) * 1024 + k1 + scol),
                (AS3 unsigned int*)(&Bb[nxt][w * 512 + lane * 8]), 16, 0, 0);
        }
        bf8_t af[4], bfr[2];
#pragma unroll
        for (int i = 0; i < 4; ++i)
            af[i] = *(const bf8_t*)(&Ab[cur][(wm + 16 * i + mrow) * 32 + kq]);
#pragma unroll
        for (int j = 0; j < 2; ++j)
            bfr[j] = *(const bf8_t*)(&Bb[cur][(wn + 16 * j + mrow) * 32 + kq]);
#pragma unroll
        for (int i = 0; i < 4; ++i)
#pragma unroll
            for (int j = 0; j < 2; ++j)
                acc[i][j] = __builtin_amdgcn_mfma_f32_16x16x32_bf16(
                    af[i], bfr[j], acc[i][j], 0, 0, 0);
    }
    const int crow = (lane >> 4) * 4;
    const int ccol = lane & 15;
#pragma unroll
    for (int i = 0; i < 4; ++i)
#pragma unroll
        for (int j = 0; j < 2; ++j)
#pragma unroll
            for (int u = 0; u < 4; ++u)
                out[(size_t)(t0 + wm + 16 * i + crow + u) * 1024
                    + n0 + wn + 16 * j + ccol] = acc[i][j][u];
}

// Fused r/k/v projections: blockIdx.z selects the (A, W, out) triple.
__global__ __launch_bounds__(256) void gemm_bf16_3(
    const unsigned short* __restrict__ xr, const unsigned short* __restrict__ xk,
    const unsigned short* __restrict__ xv,
    const unsigned short* __restrict__ Wr, const unsigned short* __restrict__ Wk,
    const unsigned short* __restrict__ Wv,
    float* __restrict__ rB, float* __restrict__ kB, float* __restrict__ vB)
{
    const int z = blockIdx.z;
    const unsigned short* A = z == 0 ? xr : z == 1 ? xk : xv;
    const unsigned short* W = z == 0 ? Wr : z == 1 ? Wk : Wv;
    float* out = z == 0 ? rB : z == 1 ? kB : vB;
    gemm_core(A, W, out);
}

__global__ __launch_bounds__(256) void gemm_bf16(
    const unsigned short* __restrict__ A, const unsigned short* __restrict__ W,
    float* __restrict__ out)
{
    gemm_core(A, W, out);
}

// ---------------------------------------------------------------------------
// Fused LoRA stage-1 via MFMA: z = 0:w(tanh,N=64) 1:a(N=64) 2:v(N=32) 3:g(sig,N=128)
// Same tile structure as gemm_core; W rows padded to 64/128; store guarded.
// ---------------------------------------------------------------------------
__global__ __launch_bounds__(256) void lora1m(
    const unsigned short* __restrict__ xw, const unsigned short* __restrict__ xa,
    const unsigned short* __restrict__ xv, const unsigned short* __restrict__ xg,
    const unsigned short* __restrict__ lw16,
    float* __restrict__ hw, float* __restrict__ ha, float* __restrict__ hv,
    float* __restrict__ hg)
{
    const int z = blockIdx.z;
    const unsigned short* A = z == 0 ? xw : z == 1 ? xa : z == 2 ? xv : xg;
    const unsigned short* W = lw16 + (size_t)(z == 0 ? 0 : z == 1 ? 64 : z == 2 ? 128 : 192) * 1024;
    float* out = z == 0 ? hw : z == 1 ? ha : z == 2 ? hv : hg;
    const int N  = z == 3 ? 128 : z == 2 ? 32 : 64;   // true column count
    const int Ns = z == 3 ? 128 : 64;                 // padded W rows
    const int n0 = blockIdx.x * 64;
    if (n0 >= Ns) return;

    __shared__ unsigned short Ab[2][128 * 32];
    __shared__ unsigned short Bb[2][64 * 32];
    const int tid = threadIdx.x;
    const int lane = tid & 63;
    const int w = tid >> 6;
    const int t0 = blockIdx.y * 128;
    const int wm = (w & 1) * 64;
    const int wn = (w >> 1) * 32;
    const int srow = lane >> 2;
    const int scol = (lane & 3) * 8;

    f4_t acc[4][2];
#pragma unroll
    for (int i = 0; i < 4; ++i)
#pragma unroll
        for (int j = 0; j < 2; ++j)
            acc[i][j] = (f4_t){0.f, 0.f, 0.f, 0.f};

#pragma unroll
    for (int s = 0; s < 2; ++s) {
        const int i = 2 * w + s;
        __builtin_amdgcn_global_load_lds(
            (const AS1 unsigned int*)(A + (size_t)(t0 + i * 16 + srow) * 1024 + scol),
            (AS3 unsigned int*)(&Ab[0][i * 512 + lane * 8]), 16, 0, 0);
    }
    __builtin_amdgcn_global_load_lds(
        (const AS1 unsigned int*)(W + (size_t)(n0 + w * 16 + srow) * 1024 + scol),
        (AS3 unsigned int*)(&Bb[0][w * 512 + lane * 8]), 16, 0, 0);

    const int mrow = lane & 15;
    const int kq = (lane >> 4) * 8;
    for (int k0 = 0; k0 < 1024; k0 += 32) {
        const int cur = (k0 >> 5) & 1, nxt = cur ^ 1;
        __syncthreads();
        if (k0 + 32 < 1024) {
            const int k1 = k0 + 32;
#pragma unroll
            for (int s = 0; s < 2; ++s) {
                const int i = 2 * w + s;
                __builtin_amdgcn_global_load_lds(
                    (const AS1 unsigned int*)(A + (size_t)(t0 + i * 16 + srow) * 1024 + k1 + scol),
                    (AS3 unsigned int*)(&Ab[nxt][i * 512 + lane * 8]), 16, 0, 0);
            }
            __builtin_amdgcn_global_load_lds(
                (const AS1 unsigned int*)(W + (size_t)(n0 + w * 16 + srow) * 1024 + k1 + scol),
                (AS3 unsigned int*)(&Bb[nxt][w * 512 + lane * 8]), 16, 0, 0);
        }
        bf8_t af[4], bfr[2];
#pragma unroll
        for (int i = 0; i < 4; ++i)
            af[i] = *(const bf8_t*)(&Ab[cur][(wm + 16 * i + mrow) * 32 + kq]);
#pragma unroll
        for (int j = 0; j < 2; ++j)
            bfr[j] = *(const bf8_t*)(&Bb[cur][(wn + 16 * j + mrow) * 32 + kq]);
#pragma unroll
        for (int i = 0; i < 4; ++i)
#pragma unroll
            for (int j = 0; j < 2; ++j)
                acc[i][j] = __builtin_amdgcn_mfma_f32_16x16x32_bf16(
                    af[i], bfr[j], acc[i][j], 0, 0, 0);
    }
    const int crow = (lane >> 4) * 4;
    const int ccol = lane & 15;
#pragma unroll
    for (int i = 0; i < 4; ++i)
#pragma unroll
        for (int j = 0; j < 2; ++j) {
            const int col = n0 + wn + 16 * j + ccol;
            if (col < N) {
#pragma unroll
                for (int u = 0; u < 4; ++u) {
                    float vv = acc[i][j][u];
                    if (z == 0) vv = tanhf(vv);
                    else if (z == 3) vv = sigf(vv);
                    out[(size_t)(t0 + wm + 16 * i + crow + u) * N + col] = vv;
                }
            }
        }
}

// ---------------------------------------------------------------------------
// Fused LoRA-2 for all four paths + k post-process + vscan-stream packing.
// ---------------------------------------------------------------------------
__global__ __launch_bounds__(256) void lora2f(
    const float* __restrict__ hwB, const float* __restrict__ haB,
    const float* __restrict__ hvB, const float* __restrict__ hgB,
    const float* __restrict__ w2, const float* __restrict__ a2,
    const float* __restrict__ v2, const float* __restrict__ g2,
    const float* __restrict__ w0, const float* __restrict__ a0,
    const float* __restrict__ v0,
    const float* __restrict__ k_k, const float* __restrict__ k_a,
    const float* __restrict__ v_first, const float* __restrict__ rB,
    float* __restrict__ kB, float* __restrict__ vB, float* __restrict__ gB,
    float* __restrict__ pk)
{
    __shared__ __align__(16) float hsW[16 * 64], hsA[16 * 64];
    __shared__ __align__(16) float hsV[16 * 32], hsG[16 * 128];
    const int tid = threadIdx.x;
    const int t0 = blockIdx.y * 16;
    const int i  = blockIdx.x * 256 + tid;
    const int h  = i >> 6;
    const int j  = i & 63;
    for (int idx = tid; idx < 16 * 64; idx += 256) {
        hsW[idx] = hwB[(size_t)t0 * 64 + idx];
        hsA[idx] = haB[(size_t)t0 * 64 + idx];
    }
    for (int idx = tid; idx < 16 * 32; idx += 256)
        hsV[idx] = hvB[(size_t)t0 * 32 + idx];
    for (int idx = tid; idx < 16 * 128; idx += 256)
        hsG[idx] = hgB[(size_t)t0 * 128 + idx];
    __syncthreads();

    float av[16], ew[16], vf[16];
    { // a = sigmoid(a0 + ha@a2)
        float acc[16];
        const float b0 = a0[i];
#pragma unroll
        for (int tt = 0; tt < 16; ++tt) acc[tt] = b0;
        for (int jj = 0; jj < 64; jj += 4) {
            const float q0 = a2[(size_t)(jj + 0) * C_DIM + i];
            const float q1 = a2[(size_t)(jj + 1) * C_DIM + i];
            const float q2 = a2[(size_t)(jj + 2) * C_DIM + i];
            const float q3 = a2[(size_t)(jj + 3) * C_DIM + i];
#pragma unroll
            for (int tt = 0; tt < 16; ++tt) {
                float4 h4 = *(const float4*)(hsA + tt * 64 + jj);
                acc[tt] = fmaf(h4.x, q0, acc[tt]);
                acc[tt] = fmaf(h4.y, q1, acc[tt]);
                acc[tt] = fmaf(h4.z, q2, acc[tt]);
                acc[tt] = fmaf(h4.w, q3, acc[tt]);
            }
        }
#pragma unroll
        for (int tt = 0; tt < 16; ++tt) av[tt] = sigf(acc[tt]);
    }
    { // exp(w)
        float acc[16];
        const float b0 = w0[i];
#pragma unroll
        for (int tt = 0; tt < 16; ++tt) acc[tt] = b0;
        for (int jj = 0; jj < 64; jj += 4) {
            const float q0 = w2[(size_t)(jj + 0) * C_DIM + i];
            const float q1 = w2[(size_t)(jj + 1) * C_DIM + i];
            const float q2 = w2[(size_t)(jj + 2) * C_DIM + i];
            const float q3 = w2[(size_t)(jj + 3) * C_DIM + i];
#pragma unroll
            for (int tt = 0; tt < 16; ++tt) {
                float4 h4 = *(const float4*)(hsW + tt * 64 + jj);
                acc[tt] = fmaf(h4.x, q0, acc[tt]);
                acc[tt] = fmaf(h4.y, q1, acc[tt]);
                acc[tt] = fmaf(h4.z, q2, acc[tt]);
                acc[tt] = fmaf(h4.w, q3, acc[tt]);
            }
        }
#pragma unroll
        for (int tt = 0; tt < 16; ++tt)
            ew[tt] = __expf(-0.6065306597126334f * sigf(acc[tt]));
    }
    { // v mix
        float acc[16];
        const float b0 = v0[i];
#pragma unroll
        for (int tt = 0; tt < 16; ++tt) acc[tt] = b0;
        for (int jj = 0; jj < 32; jj += 4) {
            const float q0 = v2[(size_t)(jj + 0) * C_DIM + i];
            const float q1 = v2[(size_t)(jj + 1) * C_DIM + i];
            const float q2 = v2[(size_t)(jj + 2) * C_DIM + i];
            const float q3 = v2[(size_t)(jj + 3) * C_DIM + i];
#pragma unroll
            for (int tt = 0; tt < 16; ++tt) {
                float4 h4 = *(const float4*)(hsV + tt * 32 + jj);
                acc[tt] = fmaf(h4.x, q0, acc[tt]);
                acc[tt] = fmaf(h4.y, q1, acc[tt]);
                acc[tt] = fmaf(h4.z, q2, acc[tt]);
                acc[tt] = fmaf(h4.w, q3, acc[tt]);
            }
        }
#pragma unroll
        for (int tt = 0; tt < 16; ++tt) {
            const size_t gi = (size_t)(t0 + tt) * C_DIM + i;
            const float s = sigf(acc[tt]);
            const float vr = vB[gi];
            vf[tt] = vr + (v_first[gi] - vr) * s;
            vB[gi] = vf[tt];
        }
    }
    { // g
        float acc[16];
#pragma unroll
        for (int tt = 0; tt < 16; ++tt) acc[tt] = 0.f;
        for (int jj = 0; jj < 128; jj += 4) {
            const float q0 = g2[(size_t)(jj + 0) * C_DIM + i];
            const float q1 = g2[(size_t)(jj + 1) * C_DIM + i];
            const float q2 = g2[(size_t)(jj + 2) * C_DIM + i];
            const float q3 = g2[(size_t)(jj + 3) * C_DIM + i];
#pragma unroll
            for (int tt = 0; tt < 16; ++tt) {
                float4 h4 = *(const float4*)(hsG + tt * 128 + jj);
                acc[tt] = fmaf(h4.x, q0, acc[tt]);
                acc[tt] = fmaf(h4.y, q1, acc[tt]);
                acc[tt] = fmaf(h4.z, q2, acc[tt]);
                acc[tt] = fmaf(h4.w, q3, acc[tt]);
            }
        }
#pragma unroll
        for (int tt = 0; tt < 16; ++tt)
            gB[(size_t)(t0 + tt) * C_DIM + i] = acc[tt];
    }
    const float kkw = k_k[i], kaw = k_a[i];
    const size_t pbase = (size_t)h * T_LEN * STEP_F;
#pragma unroll 4
    for (int tt = 0; tt < 16; ++tt) {
        const int t = t0 + tt;
        const size_t gi = (size_t)t * C_DIM + i;
        const float kraw = kB[gi];
        const float kn = kraw * kkw;
        float ss = kn * kn;
#pragma unroll
        for (int m = 1; m <= 32; m <<= 1) ss += __shfl_xor(ss, m);
        const float sc = 1.f / fmaxf(sqrtf(ss), 1e-12f);
        const float kk = kn * sc;
        const float a_ = av[tt];
        const float kf = kraw * (1.f + (a_ - 1.f) * kaw);
        kB[gi] = kf;
        float* p = pk + pbase + (size_t)t * STEP_F;
        p[j]        = rB[gi];
        p[64 + j]   = ew[tt];
        p[128 + j]  = kf;
        p[192 + j]  = vf[tt];
        p[256 + j]  = -kk;
        p[320 + j]  = kk * a_;
    }
}

// ---------------------------------------------------------------------------
// v-row-parallel scan, batched LDS double-buffer + REGISTER pipelining.
// 256 blocks x 64 threads; block b -> head (b&15) (XCD-local streams).
// Slot s+1's Step is read into registers before computing slot s; batch fence
// is vmcnt(8): waits for the 12 prefetch loads, leaves the 8 y-stores in
// flight. C_FENCE pins load-before-store program order for the count.
// ---------------------------------------------------------------------------
struct Step { float4 r, e, k, a, b; float v; };

static __device__ __forceinline__ float red16(float x) {
    int xi;
    xi = __builtin_amdgcn_mov_dpp(__float_as_int(x), 0x128, 0xf, 0xf, true);
    x += __int_as_float(xi);
    xi = __builtin_amdgcn_mov_dpp(__float_as_int(x), 0x124, 0xf, 0xf, true);
    x += __int_as_float(xi);
    xi = __builtin_amdgcn_mov_dpp(__float_as_int(x), 0x122, 0xf, 0xf, true);
    x += __int_as_float(xi);
    xi = __builtin_amdgcn_mov_dpp(__float_as_int(x), 0x121, 0xf, 0xf, true);
    x += __int_as_float(xi);
    return x;
}

static __device__ __forceinline__ void issue_batch(
    const float* __restrict__ hbase, float* __restrict__ buf, int batch, int l)
{
    const float* src = hbase + (size_t)batch * BATCH_F;
#pragma unroll
    for (int i = 0; i < BATCH_F / 256; ++i)   // 12 full-wave 16B loads
        __builtin_amdgcn_global_load_lds(
            (const AS1 unsigned int*)(src + i * 256 + l * 4),
            (AS3 unsigned int*)(&buf[i * 256 + l * 4]), 16, 0, 0);
}

static __device__ __forceinline__ Step slot_read(
    const float* __restrict__ buf, int s, int j0, int vidx)
{
    Step st;
    const float* p = buf + s * STEP_F;
    st.r = *(const float4*)(p + j0);
    st.e = *(const float4*)(p + 64 + j0);
    st.k = *(const float4*)(p + 128 + j0);
    st.v = p[192 + vidx];
    st.a = *(const float4*)(p + 256 + j0);
    st.b = *(const float4*)(p + 320 + j0);
    return st;
}

static __device__ __forceinline__ void step_compute(
    float4& S, const Step& st, float* __restrict__ y,
    int t, int cb, int vidx, int lane)
{
    float sa = S.x * st.a.x;
    sa = fmaf(S.y, st.a.y, sa);
    sa = fmaf(S.z, st.a.z, sa);
    sa = fmaf(S.w, st.a.w, sa);
    sa = red16(sa);
    S.x = fmaf(st.v, st.k.x, fmaf(sa, st.b.x, S.x * st.e.x));
    S.y = fmaf(st.v, st.k.y, fmaf(sa, st.b.y, S.y * st.e.y));
    S.z = fmaf(st.v, st.k.z, fmaf(sa, st.b.z, S.z * st.e.z));
    S.w = fmaf(st.v, st.k.w, fmaf(sa, st.b.w, S.w * st.e.w));
    float o = S.x * st.r.x;
    o = fmaf(S.y, st.r.y, o);
    o = fmaf(S.z, st.r.z, o);
    o = fmaf(S.w, st.r.w, o);
    o = red16(o);
    if ((lane & 15) == 0)
        y[(size_t)t * C_DIM + cb + vidx] = o;
}

__global__ __launch_bounds__(64) void vscan(
    const float* __restrict__ pk, const float* __restrict__ init_state,
    float* __restrict__ y)
{
    const int h  = blockIdx.x & 15;
    const int wv = blockIdx.x >> 4;
    const int l  = threadIdx.x;
    const int vidx = wv * 4 + (l >> 4);
    const int j0 = (l & 15) * 4;
    const int cb = h * 64;

    __shared__ __align__(16) float buf[2][BATCH_F];
    const float* hbase = pk + (size_t)h * T_LEN * STEP_F;

    float4 S = *(const float4*)(init_state + h * 4096 + vidx * 64 + j0);

    issue_batch(hbase, buf[0], 0, l);
    VM_FENCE0();
    Step cur = slot_read(buf[0], 0, j0, vidx);
    const int NB = T_LEN / BSTEP;
    for (int b = 0; b < NB; ++b) {
        if (b + 1 < NB)
            issue_batch(hbase, buf[(b + 1) & 1], b + 1, l);
        C_FENCE();                   // keep the 12 loads ahead of the stores
        const float* cbuf = buf[b & 1];
#pragma unroll
        for (int s = 0; s < BSTEP; ++s) {
            Step nxt;
            if (s + 1 < BSTEP) nxt = slot_read(cbuf, s + 1, j0, vidx);
            step_compute(S, cur, y, b * BSTEP + s, cb, vidx, l);
            if (s + 1 < BSTEP) cur = nxt;
        }
        VM_FENCE8();                 // 12 prefetch loads landed; stores fly on
        cur = slot_read(buf[(b + 1) & 1], 0, j0, vidx);  // junk at b=NB-1, unused
    }
}

// ---------------------------------------------------------------------------
// GroupNorm + bonus + *g ; writes bf16 (xo*g) for the final MFMA GEMM.
// ---------------------------------------------------------------------------
__global__ __launch_bounds__(256) void gn_bonus(
    const float* __restrict__ y, const float* __restrict__ rb,
    const float* __restrict__ kb, const float* __restrict__ vb,
    const float* __restrict__ gb, const float* __restrict__ r_k,
    const float* __restrict__ lnw, const float* __restrict__ lnb,
    unsigned short* __restrict__ yg)
{
    const int t = blockIdx.x, tid = threadIdx.x;
    const int c0 = tid << 2;
    const size_t base = (size_t)t * C_DIM + c0;
    float4 yv = *(const float4*)(y + base);
    float sum = yv.x + yv.y + yv.z + yv.w;
    float ss  = yv.x * yv.x + yv.y * yv.y + yv.z * yv.z + yv.w * yv.w;
    float4 rv = *(const float4*)(rb + base);
    float4 kv = *(const float4*)(kb + base);
    float4 rkv = *(const float4*)(r_k + c0);
    float dot = rv.x * kv.x * rkv.x + rv.y * kv.y * rkv.y +
                rv.z * kv.z * rkv.z + rv.w * kv.w * rkv.w;
#pragma unroll
    for (int m = 1; m <= 8; m <<= 1) {
        sum += __shfl_xor(sum, m);
        ss  += __shfl_xor(ss, m);
        dot += __shfl_xor(dot, m);
    }
    const float mu = sum * 0.015625f;
    const float var = ss * 0.015625f - mu * mu;
    const float rstd = rsqrtf(var + 0.00064f);
    float4 wv = *(const float4*)(lnw + c0);
    float4 bv = *(const float4*)(lnb + c0);
    float4 vv = *(const float4*)(vb + base);
    float4 gv = *(const float4*)(gb + base);
    ushort4 o;
    o.x = f2bf(((yv.x - mu) * rstd * wv.x + bv.x + dot * vv.x) * gv.x);
    o.y = f2bf(((yv.y - mu) * rstd * wv.y + bv.y + dot * vv.y) * gv.y);
    o.z = f2bf(((yv.z - mu) * rstd * wv.z + bv.z + dot * vv.z) * gv.z);
    o.w = f2bf(((yv.w - mu) * rstd * wv.w + bv.w + dot * vv.w) * gv.w);
    *(ushort4*)(yg + base) = o;
}

// ---------------------------------------------------------------------------
extern "C" void kernel_launch(void* const* d_in, const int* in_sizes, int n_in,
                              void* d_out, int out_size, void* d_ws, size_t ws_size,
                              hipStream_t stream)
{
    (void)in_sizes; (void)n_in; (void)out_size; (void)ws_size;
    const float* x       = (const float*)d_in[0];
    const float* v_first = (const float*)d_in[1];
    const float* x_prev  = (const float*)d_in[2];
    const float* init_st = (const float*)d_in[3];
    const float* x_r = (const float*)d_in[4];
    const float* x_w = (const float*)d_in[5];
    const float* x_k = (const float*)d_in[6];
    const float* x_v = (const float*)d_in[7];
    const float* x_a = (const float*)d_in[8];
    const float* x_g = (const float*)d_in[9];
    const float* w0  = (const float*)d_in[10];
    const float* a0  = (const float*)d_in[11];
    const float* v0  = (const float*)d_in[12];
    const float* k_k = (const float*)d_in[13];
    const float* k_a = (const float*)d_in[14];
    const float* w1  = (const float*)d_in[15];
    const float* w2  = (const float*)d_in[16];
    const float* a1  = (const float*)d_in[17];
    const float* a2  = (const float*)d_in[18];
    const float* v1  = (const float*)d_in[19];
    const float* v2  = (const float*)d_in[20];
    const float* g1  = (const float*)d_in[21];
    const float* g2  = (const float*)d_in[22];
    const float* r_k = (const float*)d_in[23];
    const float* Wr  = (const float*)d_in[24];
    const float* Wk  = (const float*)d_in[25];
    const float* Wv  = (const float*)d_in[26];
    const float* Wo  = (const float*)d_in[27];
    const float* ln_w = (const float*)d_in[28];
    const float* ln_b = (const float*)d_in[29];

    float* out = (float*)d_out;
    float* ws  = (float*)d_ws;
    const size_t NE = (size_t)T_LEN * C_DIM;   // 2M
    const size_t WE = (size_t)C_DIM * C_DIM;   // 1M
    float* rB  = ws;
    float* kB  = ws + NE;
    float* vB  = ws + 2 * NE;
    float* gB  = ws + 3 * NE;
    float* hwB = ws + 4 * NE;                  // T*64
    float* haB = hwB + (size_t)T_LEN * 64;
    float* hvB = haB + (size_t)T_LEN * 64;
    float* hgB = hvB + (size_t)T_LEN * 32;     // h region < NE/2
    float* pk  = ws + 4 * NE + NE / 2;         // 6*NE floats
    unsigned short* b16 = (unsigned short*)(ws + 10 * NE + NE / 2);
    unsigned short* xr16 = b16;                // NE shorts
    unsigned short* xk16 = b16 + NE;
    unsigned short* xv16 = b16 + 2 * NE;
    unsigned short* Wr16 = b16 + 3 * NE;       // 4*WE shorts
    unsigned short* Wk16 = Wr16 + WE;
    unsigned short* Wv16 = Wr16 + 2 * WE;
    unsigned short* Wo16 = Wr16 + 3 * WE;
    unsigned short* yg16 = b16 + 3 * NE + 4 * WE;  // NE shorts
    unsigned short* lw16 = yg16 + NE;              // 320K shorts (LoRA weights)
    // xw/xa/xg bf16 live in the pk region (pk written later by lora2f)
    unsigned short* xw16 = (unsigned short*)pk;
    unsigned short* xa16 = xw16 + NE;
    unsigned short* xg16 = xw16 + 2 * NE;
    // yB aliases xr16/xk16 (consumed by gemms before vscan writes it)
    float* yB = (float*)xr16;

    wcvt4<<<4096, 256, 0, stream>>>(Wr, Wk, Wv, Wo, Wr16);
    wcvt_lora<<<288, 256, 0, stream>>>(w1, a1, v1, g1, lw16);
    xcvt<<<T_LEN, 256, 0, stream>>>(x, x_prev, x_r, x_k, x_v, x_w, x_a, x_g,
                                    xr16, xk16, xv16, xw16, xa16, xg16);

    gemm_bf16_3<<<dim3(16, 16, 3), 256, 0, stream>>>(
        xr16, xk16, xv16, Wr16, Wk16, Wv16, rB, kB, vB);

    lora1m<<<dim3(2, 16, 4), 256, 0, stream>>>(
        xw16, xa16, xv16, xg16, lw16, hwB, haB, hvB, hgB);

    lora2f<<<dim3(4, 128), 256, 0, stream>>>(
        hwB, haB, hvB, hgB, w2, a2, v2, g2, w0, a0, v0,
        k_k, k_a, v_first, rB, kB, vB, gB, pk);

    vscan<<<256, 64, 0, stream>>>(pk, init_st, yB);
    gn_bonus<<<T_LEN, 256, 0, stream>>>(yB, rB, kB, vB, gB, r_k, ln_w, ln_b, yg16);
    gemm_bf16<<<dim3(16, 16), 256, 0, stream>>>(yg16, Wo16, out);
}

// Round 11
// 562.818 us; speedup vs baseline: 4.6127x; 1.0343x over previous
//
#include <hip/hip_runtime.h>

#define T_LEN 2048
#define C_DIM 1024
#define PAIR_F 768          // floats per (head, step-pair) packet
#define BPAIR 4             // pairs per vscan LDS batch
#define BATCH_F (BPAIR * PAIR_F)   // 3072 floats, contiguous per batch

#define AS1 __attribute__((address_space(1)))
#define AS3 __attribute__((address_space(3)))
#define VM_FENCE0() asm volatile("s_waitcnt vmcnt(0)" ::: "memory")
#define C_FENCE() asm volatile("" ::: "memory")
#define VM_FENCE8() asm volatile("s_waitcnt vmcnt(8)" ::: "memory")

typedef __attribute__((ext_vector_type(8))) short bf8_t;
typedef __attribute__((ext_vector_type(4))) float f4_t;

static __device__ __forceinline__ float sigf(float x) {
    return 1.f / (1.f + __expf(-x));
}
static __device__ __forceinline__ unsigned short f2bf(float f) {
    unsigned u = __float_as_uint(f);
    u += 0x7fff + ((u >> 16) & 1);
    return (unsigned short)(u >> 16);
}

// ---------------------------------------------------------------------------
// Convert the four 1024x1024 fp32 weights into one bf16 block (1M strides),
// plus the transposed LoRA stage-1 weights (blocks 4096..4383).
// lw16 layout: w1t[64][1024] | a1t[64][1024] | v1t[64][1024] | g1t[128][1024]
// ---------------------------------------------------------------------------
__global__ __launch_bounds__(256) void wcvtall(
    const float* __restrict__ Wr, const float* __restrict__ Wk,
    const float* __restrict__ Wv, const float* __restrict__ Wo,
    const float* __restrict__ w1, const float* __restrict__ a1,
    const float* __restrict__ v1, const float* __restrict__ g1,
    unsigned short* __restrict__ dst, unsigned short* __restrict__ lw16)
{
    const int b = blockIdx.x;
    if (b < 4096) {
        const size_t idx = ((size_t)b * 256 + threadIdx.x) * 4;
        const int sel = (int)(idx >> 20);
        const float* src = sel == 0 ? Wr : sel == 1 ? Wk : sel == 2 ? Wv : Wo;
        float4 v = *(const float4*)(src + (idx & 0xFFFFF));
        ushort4 o = {f2bf(v.x), f2bf(v.y), f2bf(v.z), f2bf(v.w)};
        *(ushort4*)(dst + idx) = o;
        return;
    }
    const int row = b - 4096;         // 0..287
    const float* src; int Kh, i; unsigned short* dl;
    if (row < 64)       { src = w1; Kh = 64;  i = row;       dl = lw16 + (size_t)row * 1024; }
    else if (row < 128) { src = a1; Kh = 64;  i = row - 64;  dl = lw16 + (size_t)row * 1024; }
    else if (row < 160) { src = v1; Kh = 32;  i = row - 128; dl = lw16 + (size_t)(row - 128 + 128) * 1024; }
    else                { src = g1; Kh = 128; i = row - 160; dl = lw16 + (size_t)(row - 160 + 192) * 1024; }
    const int c0 = threadIdx.x * 4;
#pragma unroll
    for (int u = 0; u < 4; ++u)
        dl[c0 + u] = f2bf(src[(size_t)(c0 + u) * Kh + i]);
}

// ---------------------------------------------------------------------------
// Token-shift mix -> bf16 A-matrices for r/k/v projections and w/a/g LoRA.
// ---------------------------------------------------------------------------
__global__ __launch_bounds__(256) void xcvt(
    const float* __restrict__ x, const float* __restrict__ xprev,
    const float* __restrict__ x_r, const float* __restrict__ x_k,
    const float* __restrict__ x_v, const float* __restrict__ x_w,
    const float* __restrict__ x_a, const float* __restrict__ x_g,
    unsigned short* __restrict__ xr16, unsigned short* __restrict__ xk16,
    unsigned short* __restrict__ xv16, unsigned short* __restrict__ xw16,
    unsigned short* __restrict__ xa16, unsigned short* __restrict__ xg16)
{
    const int t = blockIdx.x;
    const int c0 = threadIdx.x * 4;
    const size_t base = (size_t)t * C_DIM + c0;
    float4 xv = *(const float4*)(x + base);
    float4 pv = (t == 0) ? *(const float4*)(xprev + c0)
                         : *(const float4*)(x + base - C_DIM);
    float4 dx = {pv.x - xv.x, pv.y - xv.y, pv.z - xv.z, pv.w - xv.w};
#define MIXOUT(mixp, dstp)                                                    \
    {                                                                          \
        float4 mv = *(const float4*)(mixp + c0);                               \
        ushort4 o = {f2bf(xv.x + dx.x * mv.x), f2bf(xv.y + dx.y * mv.y),       \
                     f2bf(xv.z + dx.z * mv.z), f2bf(xv.w + dx.w * mv.w)};      \
        *(ushort4*)(dstp + base) = o;                                          \
    }
    MIXOUT(x_r, xr16) MIXOUT(x_k, xk16) MIXOUT(x_v, xv16)
    MIXOUT(x_w, xw16) MIXOUT(x_a, xa16) MIXOUT(x_g, xg16)
#undef MIXOUT
}

// ---------------------------------------------------------------------------
// bf16 MFMA NT GEMM core: out[t,i] = sum_c A[t,c]*W[i,c], fp32 accumulate.
// ---------------------------------------------------------------------------
static __device__ __forceinline__ void gemm_core(
    const unsigned short* __restrict__ A, const unsigned short* __restrict__ W,
    float* __restrict__ out)
{
    __shared__ unsigned short Ab[2][128 * 32];
    __shared__ unsigned short Bb[2][64 * 32];
    const int tid = threadIdx.x;
    const int lane = tid & 63;
    const int w = tid >> 6;
    const int n0 = blockIdx.x * 64;
    const int t0 = blockIdx.y * 128;
    const int wm = (w & 1) * 64;
    const int wn = (w >> 1) * 32;
    const int srow = lane >> 2;
    const int scol = (lane & 3) * 8;

    f4_t acc[4][2];
#pragma unroll
    for (int i = 0; i < 4; ++i)
#pragma unroll
        for (int j = 0; j < 2; ++j)
            acc[i][j] = (f4_t){0.f, 0.f, 0.f, 0.f};

#pragma unroll
    for (int s = 0; s < 2; ++s) {
        const int i = 2 * w + s;
        __builtin_amdgcn_global_load_lds(
            (const AS1 unsigned int*)(A + (size_t)(t0 + i * 16 + srow) * 1024 + scol),
            (AS3 unsigned int*)(&Ab[0][i * 512 + lane * 8]), 16, 0, 0);
    }
    __builtin_amdgcn_global_load_lds(
        (const AS1 unsigned int*)(W + (size_t)(n0 + w * 16 + srow) * 1024 + scol),
        (AS3 unsigned int*)(&Bb[0][w * 512 + lane * 8]), 16, 0, 0);

    const int mrow = lane & 15;
    const int kq = (lane >> 4) * 8;
    for (int k0 = 0; k0 < 1024; k0 += 32) {
        const int cur = (k0 >> 5) & 1, nxt = cur ^ 1;
        __syncthreads();
        if (k0 + 32 < 1024) {
            const int k1 = k0 + 32;
#pragma unroll
            for (int s = 0; s < 2; ++s) {
                const int i = 2 * w + s;
                __builtin_amdgcn_global_load_lds(
                    (const AS1 unsigned int*)(A + (size_t)(t0 + i * 16 + srow) * 1024 + k1 + scol),
                    (AS3 unsigned int*)(&Ab[nxt][i * 512 + lane * 8]), 16, 0, 0);
            }
            __builtin_amdgcn_global_load_lds(
                (const AS1 unsigned int*)(W + (size_t)(n0 + w * 16 + srow) * 1024 + k1 + scol),
                (AS3 unsigned int*)(&Bb[nxt][w * 512 + lane * 8]), 16, 0, 0);
        }
        bf8_t af[4], bfr[2];
#pragma unroll
        for (int i = 0; i < 4; ++i)
            af[i] = *(const bf8_t*)(&Ab[cur][(wm + 16 * i + mrow) * 32 + kq]);
#pragma unroll
        for (int j = 0; j < 2; ++j)
            bfr[j] = *(const bf8_t*)(&Bb[cur][(wn + 16 * j + mrow) * 32 + kq]);
#pragma unroll
        for (int i = 0; i < 4; ++i)
#pragma unroll
            for (int j = 0; j < 2; ++j)
                acc[i][j] = __builtin_amdgcn_mfma_f32_16x16x32_bf16(
                    af[i], bfr[j], acc[i][j], 0, 0, 0);
    }
    const int crow = (lane >> 4) * 4;
    const int ccol = lane & 15;
#pragma unroll
    for (int i = 0; i < 4; ++i)
#pragma unroll
        for (int j = 0; j < 2; ++j)
#pragma unroll
            for (int u = 0; u < 4; ++u)
                out[(size_t)(t0 + wm + 16 * i + crow + u) * 1024
                    + n0 + wn + 16 * j + ccol] = acc[i][j][u];
}

__global__ __launch_bounds__(256) void gemm_bf16_3(
    const unsigned short* __restrict__ xr, const unsigned short* __restrict__ xk,
    const unsigned short* __restrict__ xv,
    const unsigned short* __restrict__ Wr, const unsigned short* __restrict__ Wk,
    const unsigned short* __restrict__ Wv,
    float* __restrict__ rB, float* __restrict__ kB, float* __restrict__ vB)
{
    const int z = blockIdx.z;
    const unsigned short* A = z == 0 ? xr : z == 1 ? xk : xv;
    const unsigned short* W = z == 0 ? Wr : z == 1 ? Wk : Wv;
    float* out = z == 0 ? rB : z == 1 ? kB : vB;
    gemm_core(A, W, out);
}

__global__ __launch_bounds__(256) void gemm_bf16(
    const unsigned short* __restrict__ A, const unsigned short* __restrict__ W,
    float* __restrict__ out)
{
    gemm_core(A, W, out);
}

// ---------------------------------------------------------------------------
// Fused LoRA stage-1 via MFMA: z = 0:w(tanh,N=64) 1:a(N=64) 2:v(N=32) 3:g(sig,N=128)
// ---------------------------------------------------------------------------
__global__ __launch_bounds__(256) void lora1m(
    const unsigned short* __restrict__ xw, const unsigned short* __restrict__ xa,
    const unsigned short* __restrict__ xv, const unsigned short* __restrict__ xg,
    const unsigned short* __restrict__ lw16,
    float* __restrict__ hw, float* __restrict__ ha, float* __restrict__ hv,
    float* __restrict__ hg)
{
    const int z = blockIdx.z;
    const unsigned short* A = z == 0 ? xw : z == 1 ? xa : z == 2 ? xv : xg;
    const unsigned short* W = lw16 + (size_t)(z == 0 ? 0 : z == 1 ? 64 : z == 2 ? 128 : 192) * 1024;
    float* out = z == 0 ? hw : z == 1 ? ha : z == 2 ? hv : hg;
    const int N  = z == 3 ? 128 : z == 2 ? 32 : 64;
    const int Ns = z == 3 ? 128 : 64;
    const int n0 = blockIdx.x * 64;
    if (n0 >= Ns) return;

    __shared__ unsigned short Ab[2][128 * 32];
    __shared__ unsigned short Bb[2][64 * 32];
    const int tid = threadIdx.x;
    const int lane = tid & 63;
    const int w = tid >> 6;
    const int t0 = blockIdx.y * 128;
    const int wm = (w & 1) * 64;
    const int wn = (w >> 1) * 32;
    const int srow = lane >> 2;
    const int scol = (lane & 3) * 8;

    f4_t acc[4][2];
#pragma unroll
    for (int i = 0; i < 4; ++i)
#pragma unroll
        for (int j = 0; j < 2; ++j)
            acc[i][j] = (f4_t){0.f, 0.f, 0.f, 0.f};

#pragma unroll
    for (int s = 0; s < 2; ++s) {
        const int i = 2 * w + s;
        __builtin_amdgcn_global_load_lds(
            (const AS1 unsigned int*)(A + (size_t)(t0 + i * 16 + srow) * 1024 + scol),
            (AS3 unsigned int*)(&Ab[0][i * 512 + lane * 8]), 16, 0, 0);
    }
    __builtin_amdgcn_global_load_lds(
        (const AS1 unsigned int*)(W + (size_t)(n0 + w * 16 + srow) * 1024 + scol),
        (AS3 unsigned int*)(&Bb[0][w * 512 + lane * 8]), 16, 0, 0);

    const int mrow = lane & 15;
    const int kq = (lane >> 4) * 8;
    for (int k0 = 0; k0 < 1024; k0 += 32) {
        const int cur = (k0 >> 5) & 1, nxt = cur ^ 1;
        __syncthreads();
        if (k0 + 32 < 1024) {
            const int k1 = k0 + 32;
#pragma unroll
            for (int s = 0; s < 2; ++s) {
                const int i = 2 * w + s;
                __builtin_amdgcn_global_load_lds(
                    (const AS1 unsigned int*)(A + (size_t)(t0 + i * 16 + srow) * 1024 + k1 + scol),
                    (AS3 unsigned int*)(&Ab[nxt][i * 512 + lane * 8]), 16, 0, 0);
            }
            __builtin_amdgcn_global_load_lds(
                (const AS1 unsigned int*)(W + (size_t)(n0 + w * 16 + srow) * 1024 + k1 + scol),
                (AS3 unsigned int*)(&Bb[nxt][w * 512 + lane * 8]), 16, 0, 0);
        }
        bf8_t af[4], bfr[2];
#pragma unroll
        for (int i = 0; i < 4; ++i)
            af[i] = *(const bf8_t*)(&Ab[cur][(wm + 16 * i + mrow) * 32 + kq]);
#pragma unroll
        for (int j = 0; j < 2; ++j)
            bfr[j] = *(const bf8_t*)(&Bb[cur][(wn + 16 * j + mrow) * 32 + kq]);
#pragma unroll
        for (int i = 0; i < 4; ++i)
#pragma unroll
            for (int j = 0; j < 2; ++j)
                acc[i][j] = __builtin_amdgcn_mfma_f32_16x16x32_bf16(
                    af[i], bfr[j], acc[i][j], 0, 0, 0);
    }
    const int crow = (lane >> 4) * 4;
    const int ccol = lane & 15;
#pragma unroll
    for (int i = 0; i < 4; ++i)
#pragma unroll
        for (int j = 0; j < 2; ++j) {
            const int col = n0 + wn + 16 * j + ccol;
            if (col < N) {
#pragma unroll
                for (int u = 0; u < 4; ++u) {
                    float vv = acc[i][j][u];
                    if (z == 0) vv = tanhf(vv);
                    else if (z == 3) vv = sigf(vv);
                    out[(size_t)(t0 + wm + 16 * i + crow + u) * N + col] = vv;
                }
            }
        }
}

// ---------------------------------------------------------------------------
// Fused LoRA-2 (w/a/v/g) + k post-process + PAIR-COMPOSED packet packing.
// Block = 16 tokens x 256 channels; head = 64 consecutive channels = 1 wave.
// Per step-pair packet (768 floats):
//   E=e1e2 @0 | A1=aa1 @64 | A2e=e1*aa2 @128 | B1e=bb1*e2 @192 | K1e=k1*e2 @256
//   | B2=bb2 @320 | K2=k2 @384 | R1e=e1*r1 @448 | R2=r2 @512 | V1 @576 | V2 @640
//   | scalars @704: cba=bb1.aa2, cka=k1.aa2, cbr=bb1.r1, ckr=k1.r1
// ---------------------------------------------------------------------------
__global__ __launch_bounds__(256) void lora2f(
    const float* __restrict__ hwB, const float* __restrict__ haB,
    const float* __restrict__ hvB, const float* __restrict__ hgB,
    const float* __restrict__ w2, const float* __restrict__ a2,
    const float* __restrict__ v2, const float* __restrict__ g2,
    const float* __restrict__ w0, const float* __restrict__ a0,
    const float* __restrict__ v0,
    const float* __restrict__ k_k, const float* __restrict__ k_a,
    const float* __restrict__ v_first, const float* __restrict__ rB,
    float* __restrict__ kB, float* __restrict__ vB, float* __restrict__ gB,
    float* __restrict__ pk)
{
    __shared__ __align__(16) float hsW[16 * 64], hsA[16 * 64];
    __shared__ __align__(16) float hsV[16 * 32], hsG[16 * 128];
    const int tid = threadIdx.x;
    const int t0 = blockIdx.y * 16;
    const int i  = blockIdx.x * 256 + tid;
    const int h  = i >> 6;
    const int j  = i & 63;
    for (int idx = tid; idx < 16 * 64; idx += 256) {
        hsW[idx] = hwB[(size_t)t0 * 64 + idx];
        hsA[idx] = haB[(size_t)t0 * 64 + idx];
    }
    for (int idx = tid; idx < 16 * 32; idx += 256)
        hsV[idx] = hvB[(size_t)t0 * 32 + idx];
    for (int idx = tid; idx < 16 * 128; idx += 256)
        hsG[idx] = hgB[(size_t)t0 * 128 + idx];
    __syncthreads();

    float av[16], ew[16], vf[16];
    { // a = sigmoid(a0 + ha@a2)
        float acc[16];
        const float b0 = a0[i];
#pragma unroll
        for (int tt = 0; tt < 16; ++tt) acc[tt] = b0;
        for (int jj = 0; jj < 64; jj += 4) {
            const float q0 = a2[(size_t)(jj + 0) * C_DIM + i];
            const float q1 = a2[(size_t)(jj + 1) * C_DIM + i];
            const float q2 = a2[(size_t)(jj + 2) * C_DIM + i];
            const float q3 = a2[(size_t)(jj + 3) * C_DIM + i];
#pragma unroll
            for (int tt = 0; tt < 16; ++tt) {
                float4 h4 = *(const float4*)(hsA + tt * 64 + jj);
                acc[tt] = fmaf(h4.x, q0, acc[tt]);
                acc[tt] = fmaf(h4.y, q1, acc[tt]);
                acc[tt] = fmaf(h4.z, q2, acc[tt]);
                acc[tt] = fmaf(h4.w, q3, acc[tt]);
            }
        }
#pragma unroll
        for (int tt = 0; tt < 16; ++tt) av[tt] = sigf(acc[tt]);
    }
    { // exp(w)
        float acc[16];
        const float b0 = w0[i];
#pragma unroll
        for (int tt = 0; tt < 16; ++tt) acc[tt] = b0;
        for (int jj = 0; jj < 64; jj += 4) {
            const float q0 = w2[(size_t)(jj + 0) * C_DIM + i];
            const float q1 = w2[(size_t)(jj + 1) * C_DIM + i];
            const float q2 = w2[(size_t)(jj + 2) * C_DIM + i];
            const float q3 = w2[(size_t)(jj + 3) * C_DIM + i];
#pragma unroll
            for (int tt = 0; tt < 16; ++tt) {
                float4 h4 = *(const float4*)(hsW + tt * 64 + jj);
                acc[tt] = fmaf(h4.x, q0, acc[tt]);
                acc[tt] = fmaf(h4.y, q1, acc[tt]);
                acc[tt] = fmaf(h4.z, q2, acc[tt]);
                acc[tt] = fmaf(h4.w, q3, acc[tt]);
            }
        }
#pragma unroll
        for (int tt = 0; tt < 16; ++tt)
            ew[tt] = __expf(-0.6065306597126334f * sigf(acc[tt]));
    }
    { // v mix
        float acc[16];
        const float b0 = v0[i];
#pragma unroll
        for (int tt = 0; tt < 16; ++tt) acc[tt] = b0;
        for (int jj = 0; jj < 32; jj += 4) {
            const float q0 = v2[(size_t)(jj + 0) * C_DIM + i];
            const float q1 = v2[(size_t)(jj + 1) * C_DIM + i];
            const float q2 = v2[(size_t)(jj + 2) * C_DIM + i];
            const float q3 = v2[(size_t)(jj + 3) * C_DIM + i];
#pragma unroll
            for (int tt = 0; tt < 16; ++tt) {
                float4 h4 = *(const float4*)(hsV + tt * 32 + jj);
                acc[tt] = fmaf(h4.x, q0, acc[tt]);
                acc[tt] = fmaf(h4.y, q1, acc[tt]);
                acc[tt] = fmaf(h4.z, q2, acc[tt]);
                acc[tt] = fmaf(h4.w, q3, acc[tt]);
            }
        }
#pragma unroll
        for (int tt = 0; tt < 16; ++tt) {
            const size_t gi = (size_t)(t0 + tt) * C_DIM + i;
            const float s = sigf(acc[tt]);
            const float vr = vB[gi];
            vf[tt] = vr + (v_first[gi] - vr) * s;
            vB[gi] = vf[tt];
        }
    }
    { // g
        float acc[16];
#pragma unroll
        for (int tt = 0; tt < 16; ++tt) acc[tt] = 0.f;
        for (int jj = 0; jj < 128; jj += 4) {
            const float q0 = g2[(size_t)(jj + 0) * C_DIM + i];
            const float q1 = g2[(size_t)(jj + 1) * C_DIM + i];
            const float q2 = g2[(size_t)(jj + 2) * C_DIM + i];
            const float q3 = g2[(size_t)(jj + 3) * C_DIM + i];
#pragma unroll
            for (int tt = 0; tt < 16; ++tt) {
                float4 h4 = *(const float4*)(hsG + tt * 128 + jj);
                acc[tt] = fmaf(h4.x, q0, acc[tt]);
                acc[tt] = fmaf(h4.y, q1, acc[tt]);
                acc[tt] = fmaf(h4.z, q2, acc[tt]);
                acc[tt] = fmaf(h4.w, q3, acc[tt]);
            }
        }
#pragma unroll
        for (int tt = 0; tt < 16; ++tt)
            gB[(size_t)(t0 + tt) * C_DIM + i] = acc[tt];
    }
    // k post-process + pair-composed packing
    const float kkw = k_k[i], kaw = k_a[i];
    const size_t pbase = (size_t)h * 1024 * PAIR_F;
    for (int pt = 0; pt < 8; ++pt) {
        const int tt1 = 2 * pt, tt2 = 2 * pt + 1;
        float r_[2], e_[2], kf_[2], v_[2], aa_[2], bb_[2];
#pragma unroll
        for (int u = 0; u < 2; ++u) {
            const int tt = 2 * pt + u;
            const size_t gi = (size_t)(t0 + tt) * C_DIM + i;
            const float kraw = kB[gi];
            const float kn = kraw * kkw;
            float ss = kn * kn;
#pragma unroll
            for (int m = 1; m <= 32; m <<= 1) ss += __shfl_xor(ss, m);
            const float sc = 1.f / fmaxf(sqrtf(ss), 1e-12f);
            const float kk = kn * sc;
            const float a_ = av[tt];
            const float kf = kraw * (1.f + (a_ - 1.f) * kaw);
            kB[gi] = kf;
            r_[u] = rB[gi];
            e_[u] = ew[tt];
            kf_[u] = kf;
            v_[u] = vf[tt];
            aa_[u] = -kk;
            bb_[u] = kk * a_;
        }
        (void)tt1; (void)tt2;
        const float E   = e_[0] * e_[1];
        const float A2e = e_[0] * aa_[1];
        const float B1e = bb_[0] * e_[1];
        const float K1e = kf_[0] * e_[1];
        const float R1e = e_[0] * r_[0];
        float cba = bb_[0] * aa_[1];
        float cka = kf_[0] * aa_[1];
        float cbr = bb_[0] * r_[0];
        float ckr = kf_[0] * r_[0];
#pragma unroll
        for (int m = 1; m <= 32; m <<= 1) {
            cba += __shfl_xor(cba, m);
            cka += __shfl_xor(cka, m);
            cbr += __shfl_xor(cbr, m);
            ckr += __shfl_xor(ckr, m);
        }
        float* p = pk + pbase + (size_t)(blockIdx.y * 8 + pt) * PAIR_F;
        p[j]        = E;
        p[64 + j]   = aa_[0];
        p[128 + j]  = A2e;
        p[192 + j]  = B1e;
        p[256 + j]  = K1e;
        p[320 + j]  = bb_[1];
        p[384 + j]  = kf_[1];
        p[448 + j]  = R1e;
        p[512 + j]  = r_[1];
        p[576 + j]  = v_[0];
        p[640 + j]  = v_[1];
        if (j == 0) {
            p[704] = cba; p[705] = cka; p[706] = cbr; p[707] = ckr;
        }
    }
}

// ---------------------------------------------------------------------------
// v-row-parallel scan over step-PAIRS. 256 blocks x 64 threads; block b ->
// head (b&15). Per pair: 3 independent reductions (u1,u2,o1) from S_t, scalar
// fixups, 5-term update, then o2 (overlaps next pair's partials).
// LDS double-buffer of BPAIR pairs staged with 12 full-wave 16B loads.
// ---------------------------------------------------------------------------
struct Pair {
    float4 E, A1, A2e, B1e, K1e, B2, K2, R1e, R2;
    float v1, v2;
    float4 sc;   // cba, cka, cbr, ckr
};

static __device__ __forceinline__ float red16(float x) {
    int xi;
    xi = __builtin_amdgcn_mov_dpp(__float_as_int(x), 0x128, 0xf, 0xf, true);
    x += __int_as_float(xi);
    xi = __builtin_amdgcn_mov_dpp(__float_as_int(x), 0x124, 0xf, 0xf, true);
    x += __int_as_float(xi);
    xi = __builtin_amdgcn_mov_dpp(__float_as_int(x), 0x122, 0xf, 0xf, true);
    x += __int_as_float(xi);
    xi = __builtin_amdgcn_mov_dpp(__float_as_int(x), 0x121, 0xf, 0xf, true);
    x += __int_as_float(xi);
    return x;
}

static __device__ __forceinline__ float dot4(const float4& S, const float4& A) {
    float d = S.x * A.x;
    d = fmaf(S.y, A.y, d);
    d = fmaf(S.z, A.z, d);
    d = fmaf(S.w, A.w, d);
    return d;
}

static __device__ __forceinline__ void issue_batch(
    const float* __restrict__ hbase, float* __restrict__ buf, int batch, int l)
{
    const float* src = hbase + (size_t)batch * BATCH_F;
#pragma unroll
    for (int i = 0; i < BATCH_F / 256; ++i)   // 12 full-wave 16B loads
        __builtin_amdgcn_global_load_lds(
            (const AS1 unsigned int*)(src + i * 256 + l * 4),
            (AS3 unsigned int*)(&buf[i * 256 + l * 4]), 16, 0, 0);
}

static __device__ __forceinline__ Pair pair_read(
    const float* __restrict__ buf, int s, int j0, int vidx)
{
    Pair P;
    const float* p = buf + s * PAIR_F;
    P.E   = *(const float4*)(p + j0);
    P.A1  = *(const float4*)(p + 64 + j0);
    P.A2e = *(const float4*)(p + 128 + j0);
    P.B1e = *(const float4*)(p + 192 + j0);
    P.K1e = *(const float4*)(p + 256 + j0);
    P.B2  = *(const float4*)(p + 320 + j0);
    P.K2  = *(const float4*)(p + 384 + j0);
    P.R1e = *(const float4*)(p + 448 + j0);
    P.R2  = *(const float4*)(p + 512 + j0);
    P.v1  = p[576 + vidx];
    P.v2  = p[640 + vidx];
    P.sc  = *(const float4*)(p + 704);
    return P;
}

static __device__ __forceinline__ void pair_compute(
    float4& S, const Pair& P, float* __restrict__ y,
    int pi, int cb, int vidx, int lane)
{
    const float u1 = red16(dot4(S, P.A1));
    const float u2 = red16(dot4(S, P.A2e));
    float o1       = red16(dot4(S, P.R1e));
    const float sa1 = u1;
    const float sa2 = fmaf(P.v1, P.sc.y, fmaf(sa1, P.sc.x, u2));
    o1 = fmaf(P.v1, P.sc.w, fmaf(sa1, P.sc.z, o1));
    if ((lane & 15) == 0)
        y[(size_t)(2 * pi) * C_DIM + cb + vidx] = o1;
    // S = S*E + sa1*B1e + v1*K1e + sa2*B2 + v2*K2  (tree'd)
    float ax, ay, az, aw, bx, by, bz, bw;
    ax = fmaf(sa1, P.B1e.x, S.x * P.E.x); bx = fmaf(sa2, P.B2.x, P.v1 * P.K1e.x);
    ay = fmaf(sa1, P.B1e.y, S.y * P.E.y); by = fmaf(sa2, P.B2.y, P.v1 * P.K1e.y);
    az = fmaf(sa1, P.B1e.z, S.z * P.E.z); bz = fmaf(sa2, P.B2.z, P.v1 * P.K1e.z);
    aw = fmaf(sa1, P.B1e.w, S.w * P.E.w); bw = fmaf(sa2, P.B2.w, P.v1 * P.K1e.w);
    S.x = fmaf(P.v2, P.K2.x, ax + bx);
    S.y = fmaf(P.v2, P.K2.y, ay + by);
    S.z = fmaf(P.v2, P.K2.z, az + bz);
    S.w = fmaf(P.v2, P.K2.w, aw + bw);
    const float o2 = red16(dot4(S, P.R2));
    if ((lane & 15) == 0)
        y[(size_t)(2 * pi + 1) * C_DIM + cb + vidx] = o2;
}

__global__ __launch_bounds__(64) void vscan(
    const float* __restrict__ pk, const float* __restrict__ init_state,
    float* __restrict__ y)
{
    const int h  = blockIdx.x & 15;     // b%8 == h%8 -> per-head XCD locality
    const int wv = blockIdx.x >> 4;
    const int l  = threadIdx.x;
    const int vidx = wv * 4 + (l >> 4);
    const int j0 = (l & 15) * 4;
    const int cb = h * 64;

    __shared__ __align__(16) float buf[2][BATCH_F];
    const float* hbase = pk + (size_t)h * 1024 * PAIR_F;

    float4 S = *(const float4*)(init_state + h * 4096 + vidx * 64 + j0);

    issue_batch(hbase, buf[0], 0, l);
    VM_FENCE0();
    Pair cur = pair_read(buf[0], 0, j0, vidx);
    const int NB = 1024 / BPAIR;        // 256 batches
    for (int b = 0; b < NB; ++b) {
        if (b + 1 < NB)
            issue_batch(hbase, buf[(b + 1) & 1], b + 1, l);
        C_FENCE();                      // keep the 12 loads ahead of stores
        const float* cbuf = buf[b & 1];
#pragma unroll
        for (int s = 0; s < BPAIR; ++s) {
            Pair nxt;
            if (s + 1 < BPAIR) nxt = pair_read(cbuf, s + 1, j0, vidx);
            pair_compute(S, cur, y, b * BPAIR + s, cb, vidx, l);
            if (s + 1 < BPAIR) cur = nxt;
        }
        VM_FENCE8();                    // 12 prefetch loads landed
        cur = pair_read(buf[(b + 1) & 1], 0, j0, vidx);  // junk at b=NB-1, unused
    }
}

// ---------------------------------------------------------------------------
// GroupNorm + bonus + *g ; writes bf16 (xo*g) for the final MFMA GEMM.
// ---------------------------------------------------------------------------
__global__ __launch_bounds__(256) void gn_bonus(
    const float* __restrict__ y, const float* __restrict__ rb,
    const float* __restrict__ kb, const float* __restrict__ vb,
    const float* __restrict__ gb, const float* __restrict__ r_k,
    const float* __restrict__ lnw, const float* __restrict__ lnb,
    unsigned short* __restrict__ yg)
{
    const int t = blockIdx.x, tid = threadIdx.x;
    const int c0 = tid << 2;
    const size_t base = (size_t)t * C_DIM + c0;
    float4 yv = *(const float4*)(y + base);
    float sum = yv.x + yv.y + yv.z + yv.w;
    float ss  = yv.x * yv.x + yv.y * yv.y + yv.z * yv.z + yv.w * yv.w;
    float4 rv = *(const float4*)(rb + base);
    float4 kv = *(const float4*)(kb + base);
    float4 rkv = *(const float4*)(r_k + c0);
    float dot = rv.x * kv.x * rkv.x + rv.y * kv.y * rkv.y +
                rv.z * kv.z * rkv.z + rv.w * kv.w * rkv.w;
#pragma unroll
    for (int m = 1; m <= 8; m <<= 1) {
        sum += __shfl_xor(sum, m);
        ss  += __shfl_xor(ss, m);
        dot += __shfl_xor(dot, m);
    }
    const float mu = sum * 0.015625f;
    const float var = ss * 0.015625f - mu * mu;
    const float rstd = rsqrtf(var + 0.00064f);
    float4 wv = *(const float4*)(lnw + c0);
    float4 bv = *(const float4*)(lnb + c0);
    float4 vv = *(const float4*)(vb + base);
    float4 gv = *(const float4*)(gb + base);
    ushort4 o;
    o.x = f2bf(((yv.x - mu) * rstd * wv.x + bv.x + dot * vv.x) * gv.x);
    o.y = f2bf(((yv.y - mu) * rstd * wv.y + bv.y + dot * vv.y) * gv.y);
    o.z = f2bf(((yv.z - mu) * rstd * wv.z + bv.z + dot * vv.z) * gv.z);
    o.w = f2bf(((yv.w - mu) * rstd * wv.w + bv.w + dot * vv.w) * gv.w);
    *(ushort4*)(yg + base) = o;
}

// ---------------------------------------------------------------------------
extern "C" void kernel_launch(void* const* d_in, const int* in_sizes, int n_in,
                              void* d_out, int out_size, void* d_ws, size_t ws_size,
                              hipStream_t stream)
{
    (void)in_sizes; (void)n_in; (void)out_size; (void)ws_size;
    const float* x       = (const float*)d_in[0];
    const float* v_first = (const float*)d_in[1];
    const float* x_prev  = (const float*)d_in[2];
    const float* init_st = (const float*)d_in[3];
    const float* x_r = (const float*)d_in[4];
    const float* x_w = (const float*)d_in[5];
    const float* x_k = (const float*)d_in[6];
    const float* x_v = (const float*)d_in[7];
    const float* x_a = (const float*)d_in[8];
    const float* x_g = (const float*)d_in[9];
    const float* w0  = (const float*)d_in[10];
    const float* a0  = (const float*)d_in[11];
    const float* v0  = (const float*)d_in[12];
    const float* k_k = (const float*)d_in[13];
    const float* k_a = (const float*)d_in[14];
    const float* w1  = (const float*)d_in[15];
    const float* w2  = (const float*)d_in[16];
    const float* a1  = (const float*)d_in[17];
    const float* a2  = (const float*)d_in[18];
    const float* v1  = (const float*)d_in[19];
    const float* v2  = (const float*)d_in[20];
    const float* g1  = (const float*)d_in[21];
    const float* g2  = (const float*)d_in[22];
    const float* r_k = (const float*)d_in[23];
    const float* Wr  = (const float*)d_in[24];
    const float* Wk  = (const float*)d_in[25];
    const float* Wv  = (const float*)d_in[26];
    const float* Wo  = (const float*)d_in[27];
    const float* ln_w = (const float*)d_in[28];
    const float* ln_b = (const float*)d_in[29];

    float* out = (float*)d_out;
    float* ws  = (float*)d_ws;
    const size_t NE = (size_t)T_LEN * C_DIM;   // 2M
    const size_t WE = (size_t)C_DIM * C_DIM;   // 1M
    float* rB  = ws;
    float* kB  = ws + NE;
    float* vB  = ws + 2 * NE;
    float* gB  = ws + 3 * NE;
    float* hwB = ws + 4 * NE;                  // T*64
    float* haB = hwB + (size_t)T_LEN * 64;
    float* hvB = haB + (size_t)T_LEN * 64;
    float* hgB = hvB + (size_t)T_LEN * 32;     // h region < NE/2
    float* pk  = ws + 4 * NE + NE / 2;         // 6*NE floats (16*1024*768)
    unsigned short* b16 = (unsigned short*)(ws + 10 * NE + NE / 2);
    unsigned short* xr16 = b16;                // NE shorts
    unsigned short* xk16 = b16 + NE;
    unsigned short* xv16 = b16 + 2 * NE;
    unsigned short* Wr16 = b16 + 3 * NE;       // 4*WE shorts
    unsigned short* Wk16 = Wr16 + WE;
    unsigned short* Wv16 = Wr16 + 2 * WE;
    unsigned short* Wo16 = Wr16 + 3 * WE;
    unsigned short* yg16 = b16 + 3 * NE + 4 * WE;  // NE shorts
    unsigned short* lw16 = yg16 + NE;              // 320K shorts (LoRA weights)
    // xw/xa/xg bf16 live in the pk region (pk written later by lora2f)
    unsigned short* xw16 = (unsigned short*)pk;
    unsigned short* xa16 = xw16 + NE;
    unsigned short* xg16 = xw16 + 2 * NE;
    // yB aliases xr16/xk16 (consumed by gemms before vscan writes it)
    float* yB = (float*)xr16;

    wcvtall<<<4384, 256, 0, stream>>>(Wr, Wk, Wv, Wo, w1, a1, v1, g1,
                                      Wr16, lw16);
    xcvt<<<T_LEN, 256, 0, stream>>>(x, x_prev, x_r, x_k, x_v, x_w, x_a, x_g,
                                    xr16, xk16, xv16, xw16, xa16, xg16);

    gemm_bf16_3<<<dim3(16, 16, 3), 256, 0, stream>>>(
        xr16, xk16, xv16, Wr16, Wk16, Wv16, rB, kB, vB);

    lora1m<<<dim3(2, 16, 4), 256, 0, stream>>>(
        xw16, xa16, xv16, xg16, lw16, hwB, haB, hvB, hgB);

    lora2f<<<dim3(4, 128), 256, 0, stream>>>(
        hwB, haB, hvB, hgB, w2, a2, v2, g2, w0, a0, v0,
        k_k, k_a, v_first, rB, kB, vB, gB, pk);

    vscan<<<256, 64, 0, stream>>>(pk, init_st, yB);
    gn_bonus<<<T_LEN, 256, 0, stream>>>(yB, rB, kB, vB, gB, r_k, ln_w, ln_b, yg16);
    gemm_bf16<<<dim3(16, 16), 256, 0, stream>>>(yg16, Wo16, out);
}